// Round 1
// baseline (2858.858 us; speedup 1.0000x reference)
//
#include <hip/hip_runtime.h>
#include <math.h>

#define EMB 32
#define HID 64
#define PAT 8

// ---------------- degree ----------------
__global__ void deg_init_kernel(float* deg, int n) {
    int i = blockIdx.x * blockDim.x + threadIdx.x;
    if (i < n) deg[i] = 1.0f;  // self-loop contribution
}

__global__ void deg_accum_kernel(const int* __restrict__ dst, float* deg, int e) {
    int i = blockIdx.x * blockDim.x + threadIdx.x;
    if (i < e) atomicAdd(&deg[dst[i]], 1.0f);
}

__global__ void dinv_kernel(float* deg, int n) {
    int i = blockIdx.x * blockDim.x + threadIdx.x;
    if (i < n) deg[i] = 1.0f / sqrtf(deg[i]);   // deg >= 1 always (self-loop)
}

// ---------------- layer-1 matmul: h1 = emb @ W1 ; acc1 = h1 * dinv^2 (self-loop) ----------------
__global__ __launch_bounds__(256) void mm1_kernel(
    const float* __restrict__ emb, const float* __restrict__ W1,
    const float* __restrict__ dinv,
    float* __restrict__ h1, float* __restrict__ acc1, int n) {
    __shared__ float w[EMB * HID];  // 8 KB
    int t = threadIdx.x;
    for (int k = t; k < EMB * HID; k += 256) w[k] = W1[k];
    __syncthreads();
    int wave = t >> 6, lane = t & 63;
    int i = blockIdx.x * 4 + wave;
    if (i >= n) return;
    float e = (lane < EMB) ? emb[i * EMB + lane] : 0.0f;
    float acc = 0.0f;
#pragma unroll
    for (int k = 0; k < EMB; ++k) {
        float ek = __shfl(e, k, 64);
        acc += ek * w[k * HID + lane];
    }
    h1[i * HID + lane] = acc;
    float dv = dinv[i];
    acc1[i * HID + lane] = acc * dv * dv;
}

// ---------------- edge aggregation: acc[dst] += h[src] * dinv[src]*dinv[dst] ----------------
__global__ __launch_bounds__(256) void agg_kernel(
    const int* __restrict__ ei,   // [2*E]: row0 = src, row1 = dst
    const float* __restrict__ dinv,
    const float* __restrict__ h, float* acc, int e) {
    long long idx = (long long)blockIdx.x * blockDim.x + threadIdx.x;
    int edge = (int)(idx >> 6);
    if (edge >= e) return;
    int c = threadIdx.x & 63;
    int s = ei[edge];
    int d = ei[e + edge];
    float norm = dinv[s] * dinv[d];
    atomicAdd(&acc[d * HID + c], h[s * HID + c] * norm);
}

// ---------------- layer-2 matmul: x1 = relu(acc1+b1); h2 = x1 @ W2 ; acc2 = h2 * dinv^2 ----------------
__global__ __launch_bounds__(256) void mm2_kernel(
    const float* __restrict__ acc1, const float* __restrict__ W2,
    const float* __restrict__ b1, const float* __restrict__ dinv,
    float* __restrict__ h2, float* __restrict__ acc2, int n) {
    __shared__ float w[HID * HID];  // 16 KB
    __shared__ float bs[HID];
    int t = threadIdx.x;
    for (int k = t; k < HID * HID; k += 256) w[k] = W2[k];
    if (t < HID) bs[t] = b1[t];
    __syncthreads();
    int wave = t >> 6, lane = t & 63;
    int i = blockIdx.x * 4 + wave;
    if (i >= n) return;
    float x = fmaxf(acc1[i * HID + lane] + bs[lane], 0.0f);
    float acc = 0.0f;
#pragma unroll
    for (int k = 0; k < HID; ++k) {
        acc += __shfl(x, k, 64) * w[k * HID + lane];
    }
    h2[i * HID + lane] = acc;           // h2 may alias old h1 buffer (h1 dead)
    float dv = dinv[i];
    acc2[i * HID + lane] = acc * dv * dv;  // acc2 aliases acc1: row read above, safe
}

// ---------------- pair MLP head ----------------
__global__ __launch_bounds__(256) void final_kernel(
    const int* __restrict__ pairs, const float* __restrict__ pf,
    const float* __restrict__ x2, const float* __restrict__ b2,
    const float* __restrict__ Wf1, const float* __restrict__ bf1,
    const float* __restrict__ Wf2, const float* __restrict__ bf2,
    float* __restrict__ out, int p) {
    __shared__ float w1[(HID + PAT) * 64];  // 18 KB
    __shared__ float w2[64];
    __shared__ float b1s[64];
    __shared__ float b2s[HID];
    int t = threadIdx.x;
    for (int k = t; k < (HID + PAT) * 64; k += 256) w1[k] = Wf1[k];
    if (t < 64) { w2[t] = Wf2[t]; b1s[t] = bf1[t]; b2s[t] = b2[t]; }
    __syncthreads();
    int wave = t >> 6, lane = t & 63;
    int pi = blockIdx.x * 4 + wave;
    if (pi >= p) return;
    int dn = pairs[pi * 2];
    int an = pairs[pi * 2 + 1];
    float xd = x2[dn * HID + lane] + b2s[lane];
    float xa = x2[an * HID + lane] + b2s[lane];
    float v = xd * xa;
    float pfv = (lane < PAT) ? pf[pi * PAT + lane] : 0.0f;
    float acc = b1s[lane];
#pragma unroll
    for (int k = 0; k < HID; ++k)
        acc += __shfl(v, k, 64) * w1[k * 64 + lane];
#pragma unroll
    for (int k = 0; k < PAT; ++k)
        acc += __shfl(pfv, k, 64) * w1[(HID + k) * 64 + lane];
    float hh = fmaxf(acc, 0.0f);
    float r = hh * w2[lane];
#pragma unroll
    for (int off = 32; off > 0; off >>= 1)
        r += __shfl_xor(r, off, 64);
    if (lane == 0) {
        float z = r + bf2[0];
        out[pi] = 1.0f / (1.0f + expf(-z));
    }
}

extern "C" void kernel_launch(void* const* d_in, const int* in_sizes, int n_in,
                              void* d_out, int out_size, void* d_ws, size_t ws_size,
                              hipStream_t stream) {
    const int*   edge_index = (const int*)d_in[0];
    const int*   edge_pairs = (const int*)d_in[1];
    const float* pf         = (const float*)d_in[2];
    const float* emb        = (const float*)d_in[3];
    const float* W1         = (const float*)d_in[4];
    const float* b1         = (const float*)d_in[5];
    const float* W2         = (const float*)d_in[6];
    const float* b2         = (const float*)d_in[7];
    const float* Wf1        = (const float*)d_in[8];
    const float* bf1        = (const float*)d_in[9];
    const float* Wf2        = (const float*)d_in[10];
    const float* bf2        = (const float*)d_in[11];
    float*       out        = (float*)d_out;

    const int E = in_sizes[0] / 2;
    const int P = in_sizes[1] / 2;
    const int N = in_sizes[3] / EMB;

    char* ws = (char*)d_ws;
    size_t off = 0;
    float* dinv = (float*)(ws + off); off += ((size_t)N * 4 + 255) & ~255ULL;
    float* bufH = (float*)(ws + off); off += ((size_t)N * HID * 4 + 255) & ~255ULL;
    float* bufA = (float*)(ws + off); off += ((size_t)N * HID * 4 + 255) & ~255ULL;
    (void)ws_size;

    // 1. degree (init to 1 for self-loop), accumulate over dst, invert-sqrt
    deg_init_kernel<<<(N + 255) / 256, 256, 0, stream>>>(dinv, N);
    deg_accum_kernel<<<(E + 255) / 256, 256, 0, stream>>>(edge_index + E, dinv, E);
    dinv_kernel<<<(N + 255) / 256, 256, 0, stream>>>(dinv, N);

    // 2. layer 1: h1 = emb@W1 ; acc1 = self-loop
    mm1_kernel<<<(N + 3) / 4, 256, 0, stream>>>(emb, W1, dinv, bufH, bufA, N);

    // 3. edge aggregation layer 1
    long long tot = (long long)E * 64;
    agg_kernel<<<(unsigned)((tot + 255) / 256), 256, 0, stream>>>(edge_index, dinv, bufH, bufA, E);

    // 4. layer 2: x1 = relu(acc1+b1); h2 = x1@W2 ; acc2 = self-loop
    mm2_kernel<<<(N + 3) / 4, 256, 0, stream>>>(bufA, W2, b1, dinv, bufH, bufA, N);

    // 5. edge aggregation layer 2
    agg_kernel<<<(unsigned)((tot + 255) / 256), 256, 0, stream>>>(edge_index, dinv, bufH, bufA, E);

    // 6. pair MLP head (adds b2 on the fly)
    final_kernel<<<(P + 3) / 4, 256, 0, stream>>>(edge_pairs, pf, bufA, b2,
                                                  Wf1, bf1, Wf2, bf2, out, P);
}

// Round 3
// 2137.523 us; speedup vs baseline: 1.3375x; 1.3375x over previous
//
#include <hip/hip_runtime.h>
#include <math.h>

#define EMB 32
#define HID 64
#define PAT 8

__device__ __forceinline__ float readlane_f(float v, int l) {
    // bit-cast: __builtin_amdgcn_readlane is integer-typed; passing a float
    // directly would NUMERICALLY convert (truncate) it.
    return __int_as_float(__builtin_amdgcn_readlane(__float_as_int(v), l));
}

// ---------------- degree ----------------
__global__ void deg_init_kernel(float* deg, int n) {
    int i = blockIdx.x * blockDim.x + threadIdx.x;
    if (i < n) deg[i] = 1.0f;  // self-loop contribution
}

__global__ void deg_accum_kernel(const int* __restrict__ dst, float* deg, int e) {
    int i = blockIdx.x * blockDim.x + threadIdx.x;
    if (i < e) atomicAdd(&deg[dst[i]], 1.0f);
}

__global__ void dinv_kernel(float* deg, int n) {
    int i = blockIdx.x * blockDim.x + threadIdx.x;
    if (i < n) deg[i] = 1.0f / sqrtf(deg[i]);   // deg >= 1 always (self-loop)
}

// ---------------- layer-1 matmul: h1 = emb @ W1 ; acc1 = h1 * dinv^2 (self-loop) ----------------
__global__ __launch_bounds__(256) void mm1_kernel(
    const float* __restrict__ emb, const float* __restrict__ W1,
    const float* __restrict__ dinv,
    float* __restrict__ h1, float* __restrict__ acc1, int n) {
    __shared__ float w[EMB * HID];  // 8 KB
    int t = threadIdx.x;
    for (int k = t; k < EMB * HID; k += 256) w[k] = W1[k];
    __syncthreads();
    int wave = t >> 6, lane = t & 63;
    int i = blockIdx.x * 4 + wave;
    if (i >= n) return;
    float e = (lane < EMB) ? emb[i * EMB + lane] : 0.0f;
    float acc = 0.0f;
#pragma unroll
    for (int k = 0; k < EMB; ++k) {
        float ek = __shfl(e, k, 64);
        acc += ek * w[k * HID + lane];
    }
    h1[i * HID + lane] = acc;
    float dv = dinv[i];
    acc1[i * HID + lane] = acc * dv * dv;
}

// ---------------- edge aggregation: acc[dst] += h[src] * dinv[src]*dinv[dst] ----------------
__global__ __launch_bounds__(256) void agg_kernel(
    const int* __restrict__ ei,   // [2*E]: row0 = src, row1 = dst
    const float* __restrict__ dinv,
    const float* __restrict__ h, float* acc, int e) {
    long long idx = (long long)blockIdx.x * blockDim.x + threadIdx.x;
    int edge = (int)(idx >> 6);
    if (edge >= e) return;
    int c = threadIdx.x & 63;
    int s = ei[edge];
    int d = ei[e + edge];
    float norm = dinv[s] * dinv[d];
    atomicAdd(&acc[d * HID + c], h[s * HID + c] * norm);
}

// ---------------- layer-2 matmul: x1 = relu(acc1+b1); h2 = x1 @ W2 ; acc2 = h2 * dinv^2 ----------------
__global__ __launch_bounds__(256) void mm2_kernel(
    const float* __restrict__ acc1, const float* __restrict__ W2,
    const float* __restrict__ b1, const float* __restrict__ dinv,
    float* __restrict__ h2, float* __restrict__ acc2, int n) {
    __shared__ float w[HID * HID];  // 16 KB
    __shared__ float bs[HID];
    int t = threadIdx.x;
    for (int k = t; k < HID * HID; k += 256) w[k] = W2[k];
    if (t < HID) bs[t] = b1[t];
    __syncthreads();
    int wave = t >> 6, lane = t & 63;
    int i = blockIdx.x * 4 + wave;
    if (i >= n) return;
    float x = fmaxf(acc1[i * HID + lane] + bs[lane], 0.0f);
    float acc = 0.0f;
#pragma unroll
    for (int k = 0; k < HID; ++k) {
        acc += __shfl(x, k, 64) * w[k * HID + lane];
    }
    h2[i * HID + lane] = acc;
    float dv = dinv[i];
    acc2[i * HID + lane] = acc * dv * dv;  // acc2 aliases acc1: row read above, safe
}

// ---------------- pair MLP head: VGPR weights + readlane broadcast (no LDS pipe) ----------------
__global__ __launch_bounds__(256) void final_kernel(
    const int* __restrict__ pairs, const float* __restrict__ pf,
    const float* __restrict__ x2, const float* __restrict__ b2,
    const float* __restrict__ Wf1, const float* __restrict__ bf1,
    const float* __restrict__ Wf2, const float* __restrict__ bf2,
    float* __restrict__ out, int p) {
    int lane = threadIdx.x & 63;
    int wid  = threadIdx.x >> 6;

    // Per-lane persistent weights: lane = output channel c of the hidden layer.
    float w1r[HID + PAT];
#pragma unroll
    for (int k = 0; k < HID + PAT; ++k) w1r[k] = Wf1[k * 64 + lane];
    float b2r  = b2[lane];
    float bf1r = bf1[lane];
    float w2r  = Wf2[lane];
    float bf2r = bf2[0];

    int nw = gridDim.x * 4;           // total waves
    int pi = blockIdx.x * 4 + wid;    // this wave's first pair

    for (; pi < p; pi += nw) {
        int2 pr = ((const int2*)pairs)[pi];          // broadcast load (same addr all lanes)
        float xd = x2[(size_t)pr.x * HID + lane] + b2r;   // coalesced 256B row
        float xa = x2[(size_t)pr.y * HID + lane] + b2r;
        float v  = xd * xa;
        float pfv = (lane < PAT) ? pf[(size_t)pi * PAT + lane] : 0.0f;

        // acc_c = bf1[c] + sum_k comb[k] * Wf1[k][c], broadcast via readlane (scalar path)
        float a0 = bf1r, a1 = 0.0f, a2 = 0.0f, a3 = 0.0f;
#pragma unroll
        for (int k = 0; k < HID; k += 4) {
            a0 = fmaf(readlane_f(v, k + 0), w1r[k + 0], a0);
            a1 = fmaf(readlane_f(v, k + 1), w1r[k + 1], a1);
            a2 = fmaf(readlane_f(v, k + 2), w1r[k + 2], a2);
            a3 = fmaf(readlane_f(v, k + 3), w1r[k + 3], a3);
        }
#pragma unroll
        for (int k = 0; k < PAT; k += 4) {
            a0 = fmaf(readlane_f(pfv, k + 0), w1r[HID + k + 0], a0);
            a1 = fmaf(readlane_f(pfv, k + 1), w1r[HID + k + 1], a1);
            a2 = fmaf(readlane_f(pfv, k + 2), w1r[HID + k + 2], a2);
            a3 = fmaf(readlane_f(pfv, k + 3), w1r[HID + k + 3], a3);
        }
        float acc = (a0 + a1) + (a2 + a3);
        float r = fmaxf(acc, 0.0f) * w2r;
#pragma unroll
        for (int off = 32; off > 0; off >>= 1)
            r += __shfl_xor(r, off, 64);
        if (lane == 0)
            out[pi] = 1.0f / (1.0f + expf(-(r + bf2r)));
    }
}

extern "C" void kernel_launch(void* const* d_in, const int* in_sizes, int n_in,
                              void* d_out, int out_size, void* d_ws, size_t ws_size,
                              hipStream_t stream) {
    const int*   edge_index = (const int*)d_in[0];
    const int*   edge_pairs = (const int*)d_in[1];
    const float* pf         = (const float*)d_in[2];
    const float* emb        = (const float*)d_in[3];
    const float* W1         = (const float*)d_in[4];
    const float* b1         = (const float*)d_in[5];
    const float* W2         = (const float*)d_in[6];
    const float* b2         = (const float*)d_in[7];
    const float* Wf1        = (const float*)d_in[8];
    const float* bf1        = (const float*)d_in[9];
    const float* Wf2        = (const float*)d_in[10];
    const float* bf2        = (const float*)d_in[11];
    float*       out        = (float*)d_out;

    const int E = in_sizes[0] / 2;
    const int P = in_sizes[1] / 2;
    const int N = in_sizes[3] / EMB;

    char* ws = (char*)d_ws;
    size_t off = 0;
    float* dinv = (float*)(ws + off); off += ((size_t)N * 4 + 255) & ~255ULL;
    float* bufH = (float*)(ws + off); off += ((size_t)N * HID * 4 + 255) & ~255ULL;
    float* bufA = (float*)(ws + off); off += ((size_t)N * HID * 4 + 255) & ~255ULL;
    (void)ws_size;

    // 1. degree (init to 1 for self-loop), accumulate over dst, invert-sqrt
    deg_init_kernel<<<(N + 255) / 256, 256, 0, stream>>>(dinv, N);
    deg_accum_kernel<<<(E + 255) / 256, 256, 0, stream>>>(edge_index + E, dinv, E);
    dinv_kernel<<<(N + 255) / 256, 256, 0, stream>>>(dinv, N);

    // 2. layer 1: h1 = emb@W1 ; acc1 = self-loop
    mm1_kernel<<<(N + 3) / 4, 256, 0, stream>>>(emb, W1, dinv, bufH, bufA, N);

    // 3. edge aggregation layer 1
    long long tot = (long long)E * 64;
    agg_kernel<<<(unsigned)((tot + 255) / 256), 256, 0, stream>>>(edge_index, dinv, bufH, bufA, E);

    // 4. layer 2: x1 = relu(acc1+b1); h2 = x1@W2 ; acc2 = self-loop
    mm2_kernel<<<(N + 3) / 4, 256, 0, stream>>>(bufA, W2, b1, dinv, bufH, bufA, N);

    // 5. edge aggregation layer 2
    agg_kernel<<<(unsigned)((tot + 255) / 256), 256, 0, stream>>>(edge_index, dinv, bufH, bufA, E);

    // 6. pair MLP head (adds b2 on the fly), grid-stride over pairs
    final_kernel<<<2048, 256, 0, stream>>>(edge_pairs, pf, bufA, b2,
                                           Wf1, bf1, Wf2, bf2, out, P);
}

// Round 4
// 1313.034 us; speedup vs baseline: 2.1773x; 1.6279x over previous
//
#include <hip/hip_runtime.h>
#include <math.h>

#define EMB 32
#define HID 64
#define PAT 8

__device__ __forceinline__ float readlane_f(float v, int l) {
    return __int_as_float(__builtin_amdgcn_readlane(__float_as_int(v), l));
}

// ---------------- CSR build ----------------
__global__ void hist_kernel(const int* __restrict__ dst, int* __restrict__ count, int e) {
    int i = blockIdx.x * blockDim.x + threadIdx.x;
    if (i < e) atomicAdd(&count[dst[i]], 1);
}

// per-256-block sums of count
__global__ void block_sum_kernel(const int* __restrict__ count, int* __restrict__ bsum, int n) {
    __shared__ int s[256];
    int t = threadIdx.x, i = blockIdx.x * 256 + t;
    s[t] = (i < n) ? count[i] : 0;
    __syncthreads();
    for (int off = 128; off > 0; off >>= 1) {
        if (t < off) s[t] += s[t + off];
        __syncthreads();
    }
    if (t == 0) bsum[blockIdx.x] = s[0];
}

// single-block exclusive scan of block sums (nb <= 1024)
__global__ void scan_partials_kernel(const int* __restrict__ bsum, int* __restrict__ boff, int nb) {
    __shared__ int s[1024];
    int t = threadIdx.x;
    int v = (t < nb) ? bsum[t] : 0;
    s[t] = v;
    __syncthreads();
    for (int off = 1; off < 1024; off <<= 1) {
        int u = (t >= off) ? s[t - off] : 0;
        __syncthreads();
        s[t] += u;
        __syncthreads();
    }
    if (t < nb) boff[t] = s[t] - v;  // exclusive
}

// per-block exclusive scan + global offset -> row_ptr, cursor; dinv = rsqrt(1+deg)
__global__ void scan_final_kernel(const int* __restrict__ count, const int* __restrict__ boff,
                                  int* __restrict__ row_ptr, int* __restrict__ cursor,
                                  float* __restrict__ dinv, int n) {
    __shared__ int s[256];
    int t = threadIdx.x, i = blockIdx.x * 256 + t;
    int c = (i < n) ? count[i] : 0;
    s[t] = c;
    __syncthreads();
    for (int off = 1; off < 256; off <<= 1) {
        int u = (t >= off) ? s[t - off] : 0;
        __syncthreads();
        s[t] += u;
        __syncthreads();
    }
    if (i < n) {
        int rp = s[t] - c + boff[blockIdx.x];
        row_ptr[i] = rp;
        cursor[i]  = rp;
        dinv[i]    = rsqrtf(1.0f + (float)c);  // +1 self-loop
    }
}

__global__ void scatter_kernel(const int* __restrict__ ei, int* __restrict__ cursor,
                               int* __restrict__ csr_src, int e) {
    int i = blockIdx.x * blockDim.x + threadIdx.x;
    if (i >= e) return;
    int s = ei[i];
    int d = ei[e + i];
    int pos = atomicAdd(&cursor[d], 1);
    csr_src[pos] = s;
}

// ---------------- layer-1 matmul: h1 = emb @ W1 ; acc1 = h1 * dinv^2 (self-loop) ----------------
__global__ __launch_bounds__(256) void mm1_kernel(
    const float* __restrict__ emb, const float* __restrict__ W1,
    const float* __restrict__ dinv,
    float* __restrict__ h1, float* __restrict__ acc1, int n) {
    __shared__ float w[EMB * HID];  // 8 KB
    int t = threadIdx.x;
    for (int k = t; k < EMB * HID; k += 256) w[k] = W1[k];
    __syncthreads();
    int wave = t >> 6, lane = t & 63;
    int i = blockIdx.x * 4 + wave;
    if (i >= n) return;
    float e = (lane < EMB) ? emb[i * EMB + lane] : 0.0f;
    float acc = 0.0f;
#pragma unroll
    for (int k = 0; k < EMB; ++k) {
        float ek = __shfl(e, k, 64);
        acc += ek * w[k * HID + lane];
    }
    h1[i * HID + lane] = acc;
    float dv = dinv[i];
    acc1[i * HID + lane] = acc * dv * dv;
}

// ---------------- CSR gather: acc[i] += sum_{e in CSR[i]} h[src_e]*dinv[src_e]*dinv[i] ----------------
__global__ __launch_bounds__(256) void gather_kernel(
    const int* __restrict__ row_ptr, const int* __restrict__ row_end,
    const int* __restrict__ csr_src, const float* __restrict__ dinv,
    const float* __restrict__ h, float* __restrict__ acc, int n) {
    int lane = threadIdx.x & 63;
    int i = blockIdx.x * 4 + (threadIdx.x >> 6);
    if (i >= n) return;
    int beg = row_ptr[i];
    int end = row_end[i];      // cursor after scatter == row end
    float dv = dinv[i];
    float sum = acc[(size_t)i * HID + lane];  // self-loop term from mm kernel
    int e = beg;
    for (; e + 2 <= end; e += 2) {
        int s0 = csr_src[e], s1 = csr_src[e + 1];
        float n0 = dinv[s0] * dv, n1 = dinv[s1] * dv;
        float h0 = h[(size_t)s0 * HID + lane];
        float h1v = h[(size_t)s1 * HID + lane];
        sum = fmaf(h0, n0, sum);
        sum = fmaf(h1v, n1, sum);
    }
    if (e < end) {
        int s0 = csr_src[e];
        sum = fmaf(h[(size_t)s0 * HID + lane], dinv[s0] * dv, sum);
    }
    acc[(size_t)i * HID + lane] = sum;
}

// ---------------- layer-2 matmul: x1 = relu(acc1+b1); h2 = x1 @ W2 ; acc2 = h2 * dinv^2 ----------------
__global__ __launch_bounds__(256) void mm2_kernel(
    const float* __restrict__ acc1, const float* __restrict__ W2,
    const float* __restrict__ b1, const float* __restrict__ dinv,
    float* __restrict__ h2, float* __restrict__ acc2, int n) {
    __shared__ float w[HID * HID];  // 16 KB
    __shared__ float bs[HID];
    int t = threadIdx.x;
    for (int k = t; k < HID * HID; k += 256) w[k] = W2[k];
    if (t < HID) bs[t] = b1[t];
    __syncthreads();
    int wave = t >> 6, lane = t & 63;
    int i = blockIdx.x * 4 + wave;
    if (i >= n) return;
    float x = fmaxf(acc1[i * HID + lane] + bs[lane], 0.0f);
    float acc = 0.0f;
#pragma unroll
    for (int k = 0; k < HID; ++k) {
        acc += __shfl(x, k, 64) * w[k * HID + lane];
    }
    h2[i * HID + lane] = acc;
    float dv = dinv[i];
    acc2[i * HID + lane] = acc * dv * dv;  // acc2 aliases acc1: row read above, safe
}

// ---------------- pair MLP head: VGPR weights + readlane broadcast ----------------
__global__ __launch_bounds__(256) void final_kernel(
    const int* __restrict__ pairs, const float* __restrict__ pf,
    const float* __restrict__ x2, const float* __restrict__ b2,
    const float* __restrict__ Wf1, const float* __restrict__ bf1,
    const float* __restrict__ Wf2, const float* __restrict__ bf2,
    float* __restrict__ out, int p) {
    int lane = threadIdx.x & 63;
    int wid  = threadIdx.x >> 6;

    float w1r[HID + PAT];
#pragma unroll
    for (int k = 0; k < HID + PAT; ++k) w1r[k] = Wf1[k * 64 + lane];
    float b2r  = b2[lane];
    float bf1r = bf1[lane];
    float w2r  = Wf2[lane];
    float bf2r = bf2[0];

    int nw = gridDim.x * 4;
    int pi = blockIdx.x * 4 + wid;

    for (; pi < p; pi += nw) {
        int2 pr = ((const int2*)pairs)[pi];
        float xd = x2[(size_t)pr.x * HID + lane] + b2r;
        float xa = x2[(size_t)pr.y * HID + lane] + b2r;
        float v  = xd * xa;
        float pfv = (lane < PAT) ? pf[(size_t)pi * PAT + lane] : 0.0f;

        float a0 = bf1r, a1 = 0.0f, a2 = 0.0f, a3 = 0.0f;
#pragma unroll
        for (int k = 0; k < HID; k += 4) {
            a0 = fmaf(readlane_f(v, k + 0), w1r[k + 0], a0);
            a1 = fmaf(readlane_f(v, k + 1), w1r[k + 1], a1);
            a2 = fmaf(readlane_f(v, k + 2), w1r[k + 2], a2);
            a3 = fmaf(readlane_f(v, k + 3), w1r[k + 3], a3);
        }
#pragma unroll
        for (int k = 0; k < PAT; k += 4) {
            a0 = fmaf(readlane_f(pfv, k + 0), w1r[HID + k + 0], a0);
            a1 = fmaf(readlane_f(pfv, k + 1), w1r[HID + k + 1], a1);
            a2 = fmaf(readlane_f(pfv, k + 2), w1r[HID + k + 2], a2);
            a3 = fmaf(readlane_f(pfv, k + 3), w1r[HID + k + 3], a3);
        }
        float acc = (a0 + a1) + (a2 + a3);
        float r = fmaxf(acc, 0.0f) * w2r;
#pragma unroll
        for (int off = 32; off > 0; off >>= 1)
            r += __shfl_xor(r, off, 64);
        if (lane == 0)
            out[pi] = 1.0f / (1.0f + expf(-(r + bf2r)));
    }
}

extern "C" void kernel_launch(void* const* d_in, const int* in_sizes, int n_in,
                              void* d_out, int out_size, void* d_ws, size_t ws_size,
                              hipStream_t stream) {
    const int*   edge_index = (const int*)d_in[0];
    const int*   edge_pairs = (const int*)d_in[1];
    const float* pf         = (const float*)d_in[2];
    const float* emb        = (const float*)d_in[3];
    const float* W1         = (const float*)d_in[4];
    const float* b1         = (const float*)d_in[5];
    const float* W2         = (const float*)d_in[6];
    const float* b2         = (const float*)d_in[7];
    const float* Wf1        = (const float*)d_in[8];
    const float* bf1        = (const float*)d_in[9];
    const float* Wf2        = (const float*)d_in[10];
    const float* bf2        = (const float*)d_in[11];
    float*       out        = (float*)d_out;

    const int E = in_sizes[0] / 2;
    const int P = in_sizes[1] / 2;
    const int N = in_sizes[3] / EMB;
    const int NB = (N + 255) / 256;   // 391 for N=100k (scan_partials supports <=1024)

    char* ws = (char*)d_ws;
    size_t off = 0;
    float* dinv    = (float*)(ws + off); off += ((size_t)N * 4 + 255) & ~255ULL;
    float* bufH    = (float*)(ws + off); off += ((size_t)N * HID * 4 + 255) & ~255ULL;
    float* bufA    = (float*)(ws + off); off += ((size_t)N * HID * 4 + 255) & ~255ULL;
    int*   count   = (int*)(ws + off);   off += ((size_t)N * 4 + 255) & ~255ULL;
    int*   row_ptr = (int*)(ws + off);   off += ((size_t)N * 4 + 255) & ~255ULL;
    int*   cursor  = (int*)(ws + off);   off += ((size_t)N * 4 + 255) & ~255ULL;
    int*   bsum    = (int*)(ws + off);   off += ((size_t)NB * 4 + 255) & ~255ULL;
    int*   boff    = (int*)(ws + off);   off += ((size_t)NB * 4 + 255) & ~255ULL;
    int*   csr_src = (int*)(ws + off);   off += ((size_t)E * 4 + 255) & ~255ULL;
    (void)ws_size;

    // ---- CSR build (also produces dinv) ----
    hipMemsetAsync(count, 0, (size_t)N * 4, stream);
    hist_kernel<<<(E + 255) / 256, 256, 0, stream>>>(edge_index + E, count, E);
    block_sum_kernel<<<NB, 256, 0, stream>>>(count, bsum, N);
    scan_partials_kernel<<<1, 1024, 0, stream>>>(bsum, boff, NB);
    scan_final_kernel<<<NB, 256, 0, stream>>>(count, boff, row_ptr, cursor, dinv, N);
    scatter_kernel<<<(E + 255) / 256, 256, 0, stream>>>(edge_index, cursor, csr_src, E);

    // ---- layer 1 ----
    mm1_kernel<<<(N + 3) / 4, 256, 0, stream>>>(emb, W1, dinv, bufH, bufA, N);
    gather_kernel<<<(N + 3) / 4, 256, 0, stream>>>(row_ptr, cursor, csr_src, dinv, bufH, bufA, N);

    // ---- layer 2 ----
    mm2_kernel<<<(N + 3) / 4, 256, 0, stream>>>(bufA, W2, b1, dinv, bufH, bufA, N);
    gather_kernel<<<(N + 3) / 4, 256, 0, stream>>>(row_ptr, cursor, csr_src, dinv, bufH, bufA, N);

    // ---- pair MLP head ----
    final_kernel<<<2048, 256, 0, stream>>>(edge_pairs, pf, bufA, b2,
                                           Wf1, bf1, Wf2, bf2, out, P);
}

// Round 5
// 1197.776 us; speedup vs baseline: 2.3868x; 1.0962x over previous
//
#include <hip/hip_runtime.h>
#include <hip/hip_bf16.h>
#include <math.h>

#define EMB 32
#define HID 64
#define PAT 8

__device__ __forceinline__ float readlane_f(float v, int l) {
    return __int_as_float(__builtin_amdgcn_readlane(__float_as_int(v), l));
}

// ---------------- CSR build ----------------
__global__ void hist_kernel(const int* __restrict__ dst, int* __restrict__ count, int e) {
    int i = blockIdx.x * blockDim.x + threadIdx.x;
    if (i < e) atomicAdd(&count[dst[i]], 1);
}

__global__ void block_sum_kernel(const int* __restrict__ count, int* __restrict__ bsum, int n) {
    __shared__ int s[256];
    int t = threadIdx.x, i = blockIdx.x * 256 + t;
    s[t] = (i < n) ? count[i] : 0;
    __syncthreads();
    for (int off = 128; off > 0; off >>= 1) {
        if (t < off) s[t] += s[t + off];
        __syncthreads();
    }
    if (t == 0) bsum[blockIdx.x] = s[0];
}

__global__ void scan_partials_kernel(const int* __restrict__ bsum, int* __restrict__ boff, int nb) {
    __shared__ int s[1024];
    int t = threadIdx.x;
    int v = (t < nb) ? bsum[t] : 0;
    s[t] = v;
    __syncthreads();
    for (int off = 1; off < 1024; off <<= 1) {
        int u = (t >= off) ? s[t - off] : 0;
        __syncthreads();
        s[t] += u;
        __syncthreads();
    }
    if (t < nb) boff[t] = s[t] - v;  // exclusive
}

__global__ void scan_final_kernel(const int* __restrict__ count, const int* __restrict__ boff,
                                  int* __restrict__ row_ptr, int* __restrict__ cursor,
                                  float* __restrict__ dinv, int n) {
    __shared__ int s[256];
    int t = threadIdx.x, i = blockIdx.x * 256 + t;
    int c = (i < n) ? count[i] : 0;
    s[t] = c;
    __syncthreads();
    for (int off = 1; off < 256; off <<= 1) {
        int u = (t >= off) ? s[t - off] : 0;
        __syncthreads();
        s[t] += u;
        __syncthreads();
    }
    if (i < n) {
        int rp = s[t] - c + boff[blockIdx.x];
        row_ptr[i] = rp;
        cursor[i]  = rp;
        dinv[i]    = rsqrtf(1.0f + (float)c);  // +1 self-loop
    }
}

__global__ void scatter_kernel(const int* __restrict__ ei, int* __restrict__ cursor,
                               int* __restrict__ csr_src, int e) {
    int i = blockIdx.x * blockDim.x + threadIdx.x;
    if (i >= e) return;
    int s = ei[i];
    int d = ei[e + i];
    int pos = atomicAdd(&cursor[d], 1);
    csr_src[pos] = s;
}

// ---------------- layer-1 matmul: hb = bf16(emb @ W1) ; acc = h * dinv^2 (self-loop) ----------------
__global__ __launch_bounds__(256) void mm1_kernel(
    const float* __restrict__ emb, const float* __restrict__ W1,
    const float* __restrict__ dinv,
    __hip_bfloat16* __restrict__ hb, float* __restrict__ acc1, int n) {
    __shared__ float w[EMB * HID];  // 8 KB
    int t = threadIdx.x;
    for (int k = t; k < EMB * HID; k += 256) w[k] = W1[k];
    __syncthreads();
    int wave = t >> 6, lane = t & 63;
    int i = blockIdx.x * 4 + wave;
    if (i >= n) return;
    float e = (lane < EMB) ? emb[i * EMB + lane] : 0.0f;
    float acc = 0.0f;
#pragma unroll
    for (int k = 0; k < EMB; ++k) {
        float ek = __shfl(e, k, 64);
        acc += ek * w[k * HID + lane];
    }
    hb[(size_t)i * HID + lane] = __float2bfloat16(acc);
    float dv = dinv[i];
    acc1[(size_t)i * HID + lane] = acc * dv * dv;
}

// ---------------- CSR gather: sum = acc[i] + sum_e h[src]*dinv[src]*dinv[i] ----------------
// layer1: xb==null -> write f32 acc.  layer2: write xb = bf16(sum + b2) only.
__global__ __launch_bounds__(256) void gather_kernel(
    const int* __restrict__ row_ptr, const int* __restrict__ row_end,
    const int* __restrict__ csr_src, const float* __restrict__ dinv,
    const __hip_bfloat16* __restrict__ hb, float* __restrict__ acc,
    __hip_bfloat16* __restrict__ xb, const float* __restrict__ b2, int n) {
    int lane = threadIdx.x & 63;
    int i = blockIdx.x * 4 + (threadIdx.x >> 6);
    if (i >= n) return;
    int e   = row_ptr[i];
    int end = row_end[i];      // cursor after scatter == row end
    float dv = dinv[i];
    float sum = acc[(size_t)i * HID + lane];  // self-loop term from mm kernel
    for (; e + 4 <= end; e += 4) {
        int s0 = csr_src[e], s1 = csr_src[e + 1], s2 = csr_src[e + 2], s3 = csr_src[e + 3];
        float h0 = __bfloat162float(hb[(size_t)s0 * HID + lane]);
        float h1 = __bfloat162float(hb[(size_t)s1 * HID + lane]);
        float h2 = __bfloat162float(hb[(size_t)s2 * HID + lane]);
        float h3 = __bfloat162float(hb[(size_t)s3 * HID + lane]);
        sum = fmaf(h0, dinv[s0] * dv, sum);
        sum = fmaf(h1, dinv[s1] * dv, sum);
        sum = fmaf(h2, dinv[s2] * dv, sum);
        sum = fmaf(h3, dinv[s3] * dv, sum);
    }
    for (; e < end; ++e) {
        int s0 = csr_src[e];
        sum = fmaf(__bfloat162float(hb[(size_t)s0 * HID + lane]), dinv[s0] * dv, sum);
    }
    if (xb) xb[(size_t)i * HID + lane] = __float2bfloat16(sum + b2[lane]);
    else    acc[(size_t)i * HID + lane] = sum;
}

// ---------------- layer-2 matmul: x1 = relu(acc1+b1); hb = bf16(x1 @ W2) ; acc = h*dinv^2 ----------------
__global__ __launch_bounds__(256) void mm2_kernel(
    const float* __restrict__ acc1, const float* __restrict__ W2,
    const float* __restrict__ b1, const float* __restrict__ dinv,
    __hip_bfloat16* __restrict__ hb, float* __restrict__ acc2, int n) {
    __shared__ float w[HID * HID];  // 16 KB
    __shared__ float bs[HID];
    int t = threadIdx.x;
    for (int k = t; k < HID * HID; k += 256) w[k] = W2[k];
    if (t < HID) bs[t] = b1[t];
    __syncthreads();
    int wave = t >> 6, lane = t & 63;
    int i = blockIdx.x * 4 + wave;
    if (i >= n) return;
    float x = fmaxf(acc1[(size_t)i * HID + lane] + bs[lane], 0.0f);
    float acc = 0.0f;
#pragma unroll
    for (int k = 0; k < HID; ++k) {
        acc += __shfl(x, k, 64) * w[k * HID + lane];
    }
    hb[(size_t)i * HID + lane] = __float2bfloat16(acc);
    float dv = dinv[i];
    acc2[(size_t)i * HID + lane] = acc * dv * dv;  // aliases acc1: row read above, safe
}

// ---------------- pair MLP head: VGPR weights + readlane broadcast ----------------
__global__ __launch_bounds__(256, 1) void final_kernel(
    const int* __restrict__ pairs, const float* __restrict__ pf,
    const __hip_bfloat16* __restrict__ xb,
    const float* __restrict__ Wf1, const float* __restrict__ bf1,
    const float* __restrict__ Wf2, const float* __restrict__ bf2,
    float* __restrict__ out, int p) {
    int lane = threadIdx.x & 63;
    int wid  = threadIdx.x >> 6;

    // Per-lane persistent weights: lane = hidden channel. (256,1) bounds keep these in VGPRs.
    float w1r[HID];
#pragma unroll
    for (int k = 0; k < HID; ++k) w1r[k] = Wf1[k * 64 + lane];
    float wpf[PAT];
#pragma unroll
    for (int k = 0; k < PAT; ++k) wpf[k] = Wf1[(HID + k) * 64 + lane];
    float bf1r = bf1[lane];
    float w2r  = Wf2[lane];
    float bf2r = bf2[0];

    int nw = gridDim.x * 4;
    for (int pi = blockIdx.x * 4 + wid; pi < p; pi += nw) {
        int2 pr = ((const int2*)pairs)[pi];
        float xd = __bfloat162float(xb[(size_t)pr.x * HID + lane]);  // b2 already folded in
        float xa = __bfloat162float(xb[(size_t)pr.y * HID + lane]);
        float v  = xd * xa;
        float pfv = (lane < PAT) ? pf[(size_t)pi * PAT + lane] : 0.0f;

        float a0 = bf1r, a1 = 0.0f, a2 = 0.0f, a3 = 0.0f;
#pragma unroll
        for (int k = 0; k < HID; k += 4) {
            a0 = fmaf(readlane_f(v, k + 0), w1r[k + 0], a0);
            a1 = fmaf(readlane_f(v, k + 1), w1r[k + 1], a1);
            a2 = fmaf(readlane_f(v, k + 2), w1r[k + 2], a2);
            a3 = fmaf(readlane_f(v, k + 3), w1r[k + 3], a3);
        }
#pragma unroll
        for (int k = 0; k < PAT; k += 4) {
            a0 = fmaf(readlane_f(pfv, k + 0), wpf[k + 0], a0);
            a1 = fmaf(readlane_f(pfv, k + 1), wpf[k + 1], a1);
            a2 = fmaf(readlane_f(pfv, k + 2), wpf[k + 2], a2);
            a3 = fmaf(readlane_f(pfv, k + 3), wpf[k + 3], a3);
        }
        float acc = (a0 + a1) + (a2 + a3);
        float r = fmaxf(acc, 0.0f) * w2r;
#pragma unroll
        for (int off = 32; off > 0; off >>= 1)
            r += __shfl_xor(r, off, 64);
        if (lane == 0)
            out[pi] = 1.0f / (1.0f + expf(-(r + bf2r)));
    }
}

extern "C" void kernel_launch(void* const* d_in, const int* in_sizes, int n_in,
                              void* d_out, int out_size, void* d_ws, size_t ws_size,
                              hipStream_t stream) {
    const int*   edge_index = (const int*)d_in[0];
    const int*   edge_pairs = (const int*)d_in[1];
    const float* pf         = (const float*)d_in[2];
    const float* emb        = (const float*)d_in[3];
    const float* W1         = (const float*)d_in[4];
    const float* b1         = (const float*)d_in[5];
    const float* W2         = (const float*)d_in[6];
    const float* b2         = (const float*)d_in[7];
    const float* Wf1        = (const float*)d_in[8];
    const float* bf1        = (const float*)d_in[9];
    const float* Wf2        = (const float*)d_in[10];
    const float* bf2        = (const float*)d_in[11];
    float*       out        = (float*)d_out;

    const int E = in_sizes[0] / 2;
    const int P = in_sizes[1] / 2;
    const int N = in_sizes[3] / EMB;
    const int NB = (N + 255) / 256;   // <=1024 for scan_partials

    char* ws = (char*)d_ws;
    size_t off = 0;
    float*          dinv    = (float*)(ws + off);          off += ((size_t)N * 4 + 255) & ~255ULL;
    __hip_bfloat16* bufHb   = (__hip_bfloat16*)(ws + off); off += ((size_t)N * HID * 2 + 255) & ~255ULL;
    float*          bufA    = (float*)(ws + off);          off += ((size_t)N * HID * 4 + 255) & ~255ULL;
    __hip_bfloat16* xb      = (__hip_bfloat16*)(ws + off); off += ((size_t)N * HID * 2 + 255) & ~255ULL;
    int*            count   = (int*)(ws + off);            off += ((size_t)N * 4 + 255) & ~255ULL;
    int*            row_ptr = (int*)(ws + off);            off += ((size_t)N * 4 + 255) & ~255ULL;
    int*            cursor  = (int*)(ws + off);            off += ((size_t)N * 4 + 255) & ~255ULL;
    int*            bsum    = (int*)(ws + off);            off += ((size_t)NB * 4 + 255) & ~255ULL;
    int*            boff    = (int*)(ws + off);            off += ((size_t)NB * 4 + 255) & ~255ULL;
    int*            csr_src = (int*)(ws + off);            off += ((size_t)E * 4 + 255) & ~255ULL;
    (void)ws_size;

    // ---- CSR build (also produces dinv) ----
    hipMemsetAsync(count, 0, (size_t)N * 4, stream);
    hist_kernel<<<(E + 255) / 256, 256, 0, stream>>>(edge_index + E, count, E);
    block_sum_kernel<<<NB, 256, 0, stream>>>(count, bsum, N);
    scan_partials_kernel<<<1, 1024, 0, stream>>>(bsum, boff, NB);
    scan_final_kernel<<<NB, 256, 0, stream>>>(count, boff, row_ptr, cursor, dinv, N);
    scatter_kernel<<<(E + 255) / 256, 256, 0, stream>>>(edge_index, cursor, csr_src, E);

    // ---- layer 1 ----
    mm1_kernel<<<(N + 3) / 4, 256, 0, stream>>>(emb, W1, dinv, bufHb, bufA, N);
    gather_kernel<<<(N + 3) / 4, 256, 0, stream>>>(row_ptr, cursor, csr_src, dinv,
                                                   bufHb, bufA, (__hip_bfloat16*)nullptr, nullptr, N);

    // ---- layer 2 ----
    mm2_kernel<<<(N + 3) / 4, 256, 0, stream>>>(bufA, W2, b1, dinv, bufHb, bufA, N);
    gather_kernel<<<(N + 3) / 4, 256, 0, stream>>>(row_ptr, cursor, csr_src, dinv,
                                                   bufHb, bufA, xb, b2, N);

    // ---- pair MLP head ----
    final_kernel<<<2048, 256, 0, stream>>>(edge_pairs, pf, xb,
                                           Wf1, bf1, Wf2, bf2, out, P);
}

// Round 6
// 1183.767 us; speedup vs baseline: 2.4151x; 1.0118x over previous
//
#include <hip/hip_runtime.h>
#include <hip/hip_bf16.h>
#include <math.h>

#define EMB 32
#define HID 64
#define PAT 8

__device__ __forceinline__ float readlane_f(float v, int l) {
    return __int_as_float(__builtin_amdgcn_readlane(__float_as_int(v), l));
}

// ---------------- CSR build ----------------
__global__ void hist_kernel(const int* __restrict__ dst, int* __restrict__ count, int e) {
    int i = blockIdx.x * blockDim.x + threadIdx.x;
    if (i < e) atomicAdd(&count[dst[i]], 1);
}

__global__ void block_sum_kernel(const int* __restrict__ count, int* __restrict__ bsum, int n) {
    __shared__ int s[256];
    int t = threadIdx.x, i = blockIdx.x * 256 + t;
    s[t] = (i < n) ? count[i] : 0;
    __syncthreads();
    for (int off = 128; off > 0; off >>= 1) {
        if (t < off) s[t] += s[t + off];
        __syncthreads();
    }
    if (t == 0) bsum[blockIdx.x] = s[0];
}

__global__ void scan_partials_kernel(const int* __restrict__ bsum, int* __restrict__ boff, int nb) {
    __shared__ int s[1024];
    int t = threadIdx.x;
    int v = (t < nb) ? bsum[t] : 0;
    s[t] = v;
    __syncthreads();
    for (int off = 1; off < 1024; off <<= 1) {
        int u = (t >= off) ? s[t - off] : 0;
        __syncthreads();
        s[t] += u;
        __syncthreads();
    }
    if (t < nb) boff[t] = s[t] - v;  // exclusive
}

__global__ void scan_final_kernel(const int* __restrict__ count, const int* __restrict__ boff,
                                  int* __restrict__ row_ptr, int* __restrict__ cursor,
                                  float* __restrict__ dinv, int n) {
    __shared__ int s[256];
    int t = threadIdx.x, i = blockIdx.x * 256 + t;
    int c = (i < n) ? count[i] : 0;
    s[t] = c;
    __syncthreads();
    for (int off = 1; off < 256; off <<= 1) {
        int u = (t >= off) ? s[t - off] : 0;
        __syncthreads();
        s[t] += u;
        __syncthreads();
    }
    if (i < n) {
        int rp = s[t] - c + boff[blockIdx.x];
        row_ptr[i] = rp;
        cursor[i]  = rp;
        dinv[i]    = rsqrtf(1.0f + (float)c);  // +1 self-loop
    }
}

__global__ void scatter_kernel(const int* __restrict__ ei, int* __restrict__ cursor,
                               int* __restrict__ csr_src, int e) {
    int i = blockIdx.x * blockDim.x + threadIdx.x;
    if (i >= e) return;
    int s = ei[i];
    int d = ei[e + i];
    int pos = atomicAdd(&cursor[d], 1);
    csr_src[pos] = s;
}

// ---------------- layer-1 matmul: hb = bf16(emb @ W1) ; acc = h * dinv^2 (self-loop) ----------------
__global__ __launch_bounds__(256) void mm1_kernel(
    const float* __restrict__ emb, const float* __restrict__ W1,
    const float* __restrict__ dinv,
    __hip_bfloat16* __restrict__ hb, float* __restrict__ acc1, int n) {
    __shared__ float w[EMB * HID];  // 8 KB
    int t = threadIdx.x;
    for (int k = t; k < EMB * HID; k += 256) w[k] = W1[k];
    __syncthreads();
    int wave = t >> 6, lane = t & 63;
    int i = blockIdx.x * 4 + wave;
    if (i >= n) return;
    float e = (lane < EMB) ? emb[i * EMB + lane] : 0.0f;
    float acc = 0.0f;
#pragma unroll
    for (int k = 0; k < EMB; ++k) {
        float ek = __shfl(e, k, 64);
        acc += ek * w[k * HID + lane];
    }
    hb[(size_t)i * HID + lane] = __float2bfloat16(acc);
    float dv = dinv[i];
    acc1[(size_t)i * HID + lane] = acc * dv * dv;
}

// ---------------- CSR gather: sum = acc[i] + sum_e h[src]*dinv[src]*dinv[i] ----------------
__global__ __launch_bounds__(256) void gather_kernel(
    const int* __restrict__ row_ptr, const int* __restrict__ row_end,
    const int* __restrict__ csr_src, const float* __restrict__ dinv,
    const __hip_bfloat16* __restrict__ hb, float* __restrict__ acc,
    __hip_bfloat16* __restrict__ xb, const float* __restrict__ b2, int n) {
    int lane = threadIdx.x & 63;
    int i = blockIdx.x * 4 + (threadIdx.x >> 6);
    if (i >= n) return;
    int e   = row_ptr[i];
    int end = row_end[i];      // cursor after scatter == row end
    float dv = dinv[i];
    float sum = acc[(size_t)i * HID + lane];  // self-loop term from mm kernel
    for (; e + 4 <= end; e += 4) {
        int s0 = csr_src[e], s1 = csr_src[e + 1], s2 = csr_src[e + 2], s3 = csr_src[e + 3];
        float h0 = __bfloat162float(hb[(size_t)s0 * HID + lane]);
        float h1 = __bfloat162float(hb[(size_t)s1 * HID + lane]);
        float h2 = __bfloat162float(hb[(size_t)s2 * HID + lane]);
        float h3 = __bfloat162float(hb[(size_t)s3 * HID + lane]);
        sum = fmaf(h0, dinv[s0] * dv, sum);
        sum = fmaf(h1, dinv[s1] * dv, sum);
        sum = fmaf(h2, dinv[s2] * dv, sum);
        sum = fmaf(h3, dinv[s3] * dv, sum);
    }
    for (; e < end; ++e) {
        int s0 = csr_src[e];
        sum = fmaf(__bfloat162float(hb[(size_t)s0 * HID + lane]), dinv[s0] * dv, sum);
    }
    if (xb) xb[(size_t)i * HID + lane] = __float2bfloat16(sum + b2[lane]);
    else    acc[(size_t)i * HID + lane] = sum;
}

// ---------------- layer-2 matmul ----------------
__global__ __launch_bounds__(256) void mm2_kernel(
    const float* __restrict__ acc1, const float* __restrict__ W2,
    const float* __restrict__ b1, const float* __restrict__ dinv,
    __hip_bfloat16* __restrict__ hb, float* __restrict__ acc2, int n) {
    __shared__ float w[HID * HID];  // 16 KB
    __shared__ float bs[HID];
    int t = threadIdx.x;
    for (int k = t; k < HID * HID; k += 256) w[k] = W2[k];
    if (t < HID) bs[t] = b1[t];
    __syncthreads();
    int wave = t >> 6, lane = t & 63;
    int i = blockIdx.x * 4 + wave;
    if (i >= n) return;
    float x = fmaxf(acc1[(size_t)i * HID + lane] + bs[lane], 0.0f);
    float acc = 0.0f;
#pragma unroll
    for (int k = 0; k < HID; ++k) {
        acc += __shfl(x, k, 64) * w[k * HID + lane];
    }
    hb[(size_t)i * HID + lane] = __float2bfloat16(acc);
    float dv = dinv[i];
    acc2[(size_t)i * HID + lane] = acc * dv * dv;  // aliases acc1: row read above, safe
}

// ---------------- pair MLP head: weights as 18 named float4 SSA values (no array -> no scratch) ----------------
__global__ __launch_bounds__(256, 1) void final_kernel(
    const int* __restrict__ pairs, const float* __restrict__ pf,
    const __hip_bfloat16* __restrict__ xb,
    const float* __restrict__ Wf1, const float* __restrict__ bf1,
    const float* __restrict__ Wf2, const float* __restrict__ bf2,
    float* __restrict__ out, int p) {
    int lane = threadIdx.x & 63;
    int wid  = threadIdx.x >> 6;

    // Wf1 is [72][64]; this lane owns hidden channel `lane`. 18 named float4s =
    // pure SSA values: nothing the compiler can lower to scratch (rule #20).
#define LDW(j) const float4 w##j = make_float4( \
        Wf1[(4*(j)+0)*64 + lane], Wf1[(4*(j)+1)*64 + lane], \
        Wf1[(4*(j)+2)*64 + lane], Wf1[(4*(j)+3)*64 + lane]);
    LDW(0)  LDW(1)  LDW(2)  LDW(3)  LDW(4)  LDW(5)  LDW(6)  LDW(7)
    LDW(8)  LDW(9)  LDW(10) LDW(11) LDW(12) LDW(13) LDW(14) LDW(15)
    LDW(16) LDW(17)
#undef LDW
    float bf1r = bf1[lane];
    float w2r  = Wf2[lane];
    float bf2r = bf2[0];
    __builtin_amdgcn_sched_barrier(0);   // keep weight loads hoisted above the loop

    int nw = gridDim.x * 4;
    for (int pi = blockIdx.x * 4 + wid; pi < p; pi += nw) {
        int2 pr = ((const int2*)pairs)[pi];
        float xd = __bfloat162float(xb[(size_t)pr.x * HID + lane]);  // b2 folded in
        float xa = __bfloat162float(xb[(size_t)pr.y * HID + lane]);
        float v  = xd * xa;
        float pfv = (lane < PAT) ? pf[(size_t)pi * PAT + lane] : 0.0f;

        float a0 = bf1r, a1 = 0.0f, a2 = 0.0f, a3 = 0.0f;
#define STEP(j, src, o) \
        a0 = fmaf(readlane_f(src, (o)+0), w##j.x, a0); \
        a1 = fmaf(readlane_f(src, (o)+1), w##j.y, a1); \
        a2 = fmaf(readlane_f(src, (o)+2), w##j.z, a2); \
        a3 = fmaf(readlane_f(src, (o)+3), w##j.w, a3);
        STEP(0,  v, 0)   STEP(1,  v, 4)   STEP(2,  v, 8)   STEP(3,  v, 12)
        STEP(4,  v, 16)  STEP(5,  v, 20)  STEP(6,  v, 24)  STEP(7,  v, 28)
        STEP(8,  v, 32)  STEP(9,  v, 36)  STEP(10, v, 40)  STEP(11, v, 44)
        STEP(12, v, 48)  STEP(13, v, 52)  STEP(14, v, 56)  STEP(15, v, 60)
        STEP(16, pfv, 0) STEP(17, pfv, 4)
#undef STEP
        float acc = (a0 + a1) + (a2 + a3);
        float r = fmaxf(acc, 0.0f) * w2r;
#pragma unroll
        for (int off = 32; off > 0; off >>= 1)
            r += __shfl_xor(r, off, 64);
        if (lane == 0)
            out[pi] = 1.0f / (1.0f + expf(-(r + bf2r)));
    }
}

extern "C" void kernel_launch(void* const* d_in, const int* in_sizes, int n_in,
                              void* d_out, int out_size, void* d_ws, size_t ws_size,
                              hipStream_t stream) {
    const int*   edge_index = (const int*)d_in[0];
    const int*   edge_pairs = (const int*)d_in[1];
    const float* pf         = (const float*)d_in[2];
    const float* emb        = (const float*)d_in[3];
    const float* W1         = (const float*)d_in[4];
    const float* b1         = (const float*)d_in[5];
    const float* W2         = (const float*)d_in[6];
    const float* b2         = (const float*)d_in[7];
    const float* Wf1        = (const float*)d_in[8];
    const float* bf1        = (const float*)d_in[9];
    const float* Wf2        = (const float*)d_in[10];
    const float* bf2        = (const float*)d_in[11];
    float*       out        = (float*)d_out;

    const int E = in_sizes[0] / 2;
    const int P = in_sizes[1] / 2;
    const int N = in_sizes[3] / EMB;
    const int NB = (N + 255) / 256;   // <=1024 for scan_partials

    char* ws = (char*)d_ws;
    size_t off = 0;
    float*          dinv    = (float*)(ws + off);          off += ((size_t)N * 4 + 255) & ~255ULL;
    __hip_bfloat16* bufHb   = (__hip_bfloat16*)(ws + off); off += ((size_t)N * HID * 2 + 255) & ~255ULL;
    float*          bufA    = (float*)(ws + off);          off += ((size_t)N * HID * 4 + 255) & ~255ULL;
    __hip_bfloat16* xb      = (__hip_bfloat16*)(ws + off); off += ((size_t)N * HID * 2 + 255) & ~255ULL;
    int*            count   = (int*)(ws + off);            off += ((size_t)N * 4 + 255) & ~255ULL;
    int*            row_ptr = (int*)(ws + off);            off += ((size_t)N * 4 + 255) & ~255ULL;
    int*            cursor  = (int*)(ws + off);            off += ((size_t)N * 4 + 255) & ~255ULL;
    int*            bsum    = (int*)(ws + off);            off += ((size_t)NB * 4 + 255) & ~255ULL;
    int*            boff    = (int*)(ws + off);            off += ((size_t)NB * 4 + 255) & ~255ULL;
    int*            csr_src = (int*)(ws + off);            off += ((size_t)E * 4 + 255) & ~255ULL;
    (void)ws_size;

    // ---- CSR build (also produces dinv) ----
    hipMemsetAsync(count, 0, (size_t)N * 4, stream);
    hist_kernel<<<(E + 255) / 256, 256, 0, stream>>>(edge_index + E, count, E);
    block_sum_kernel<<<NB, 256, 0, stream>>>(count, bsum, N);
    scan_partials_kernel<<<1, 1024, 0, stream>>>(bsum, boff, NB);
    scan_final_kernel<<<NB, 256, 0, stream>>>(count, boff, row_ptr, cursor, dinv, N);
    scatter_kernel<<<(E + 255) / 256, 256, 0, stream>>>(edge_index, cursor, csr_src, E);

    // ---- layer 1 ----
    mm1_kernel<<<(N + 3) / 4, 256, 0, stream>>>(emb, W1, dinv, bufHb, bufA, N);
    gather_kernel<<<(N + 3) / 4, 256, 0, stream>>>(row_ptr, cursor, csr_src, dinv,
                                                   bufHb, bufA, (__hip_bfloat16*)nullptr, nullptr, N);

    // ---- layer 2 ----
    mm2_kernel<<<(N + 3) / 4, 256, 0, stream>>>(bufA, W2, b1, dinv, bufHb, bufA, N);
    gather_kernel<<<(N + 3) / 4, 256, 0, stream>>>(row_ptr, cursor, csr_src, dinv,
                                                   bufHb, bufA, xb, b2, N);

    // ---- pair MLP head ----
    final_kernel<<<2048, 256, 0, stream>>>(edge_pairs, pf, xb,
                                           Wf1, bf1, Wf2, bf2, out, P);
}

// Round 7
// 1183.403 us; speedup vs baseline: 2.4158x; 1.0003x over previous
//
#include <hip/hip_runtime.h>
#include <hip/hip_bf16.h>
#include <math.h>

#define EMB 32
#define HID 64
#define PAT 8

__device__ __forceinline__ float readlane_f(float v, int l) {
    return __int_as_float(__builtin_amdgcn_readlane(__float_as_int(v), l));
}

// ---------------- CSR build ----------------
__global__ void hist_kernel(const int* __restrict__ dst, int* __restrict__ count, int e) {
    int i = blockIdx.x * blockDim.x + threadIdx.x;
    if (i < e) atomicAdd(&count[dst[i]], 1);
}

__global__ void block_sum_kernel(const int* __restrict__ count, int* __restrict__ bsum, int n) {
    __shared__ int s[256];
    int t = threadIdx.x, i = blockIdx.x * 256 + t;
    s[t] = (i < n) ? count[i] : 0;
    __syncthreads();
    for (int off = 128; off > 0; off >>= 1) {
        if (t < off) s[t] += s[t + off];
        __syncthreads();
    }
    if (t == 0) bsum[blockIdx.x] = s[0];
}

__global__ void scan_partials_kernel(const int* __restrict__ bsum, int* __restrict__ boff, int nb) {
    __shared__ int s[1024];
    int t = threadIdx.x;
    int v = (t < nb) ? bsum[t] : 0;
    s[t] = v;
    __syncthreads();
    for (int off = 1; off < 1024; off <<= 1) {
        int u = (t >= off) ? s[t - off] : 0;
        __syncthreads();
        s[t] += u;
        __syncthreads();
    }
    if (t < nb) boff[t] = s[t] - v;  // exclusive
}

__global__ void scan_final_kernel(const int* __restrict__ count, const int* __restrict__ boff,
                                  int* __restrict__ row_ptr, int* __restrict__ cursor,
                                  float* __restrict__ dinv, int n) {
    __shared__ int s[256];
    int t = threadIdx.x, i = blockIdx.x * 256 + t;
    int c = (i < n) ? count[i] : 0;
    s[t] = c;
    __syncthreads();
    for (int off = 1; off < 256; off <<= 1) {
        int u = (t >= off) ? s[t - off] : 0;
        __syncthreads();
        s[t] += u;
        __syncthreads();
    }
    if (i < n) {
        int rp = s[t] - c + boff[blockIdx.x];
        row_ptr[i] = rp;
        cursor[i]  = rp;
        dinv[i]    = rsqrtf(1.0f + (float)c);  // +1 self-loop
    }
}

__global__ void scatter_kernel(const int* __restrict__ ei, int* __restrict__ cursor,
                               int* __restrict__ csr_src, int e) {
    int i = blockIdx.x * blockDim.x + threadIdx.x;
    if (i >= e) return;
    int s = ei[i];
    int d = ei[e + i];
    int pos = atomicAdd(&cursor[d], 1);
    csr_src[pos] = s;
}

// ---------------- layer-1 matmul: hb = bf16(emb @ W1) ; acc = h * dinv^2 (self-loop) ----------------
__global__ __launch_bounds__(256) void mm1_kernel(
    const float* __restrict__ emb, const float* __restrict__ W1,
    const float* __restrict__ dinv,
    __hip_bfloat16* __restrict__ hb, float* __restrict__ acc1, int n) {
    __shared__ float w[EMB * HID];  // 8 KB
    int t = threadIdx.x;
    for (int k = t; k < EMB * HID; k += 256) w[k] = W1[k];
    __syncthreads();
    int wave = t >> 6, lane = t & 63;
    int i = blockIdx.x * 4 + wave;
    if (i >= n) return;
    float e = (lane < EMB) ? emb[i * EMB + lane] : 0.0f;
    float acc = 0.0f;
#pragma unroll
    for (int k = 0; k < EMB; ++k) {
        float ek = __shfl(e, k, 64);
        acc += ek * w[k * HID + lane];
    }
    hb[(size_t)i * HID + lane] = __float2bfloat16(acc);
    float dv = dinv[i];
    acc1[(size_t)i * HID + lane] = acc * dv * dv;
}

// ---------------- CSR gather: sum = acc[i] + sum_e h[src]*dinv[src]*dinv[i] ----------------
__global__ __launch_bounds__(256) void gather_kernel(
    const int* __restrict__ row_ptr, const int* __restrict__ row_end,
    const int* __restrict__ csr_src, const float* __restrict__ dinv,
    const __hip_bfloat16* __restrict__ hb, float* __restrict__ acc,
    __hip_bfloat16* __restrict__ xb, const float* __restrict__ b2, int n) {
    int lane = threadIdx.x & 63;
    int i = blockIdx.x * 4 + (threadIdx.x >> 6);
    if (i >= n) return;
    int e   = row_ptr[i];
    int end = row_end[i];      // cursor after scatter == row end
    float dv = dinv[i];
    float sum = acc[(size_t)i * HID + lane];  // self-loop term from mm kernel
    for (; e + 4 <= end; e += 4) {
        int s0 = csr_src[e], s1 = csr_src[e + 1], s2 = csr_src[e + 2], s3 = csr_src[e + 3];
        float h0 = __bfloat162float(hb[(size_t)s0 * HID + lane]);
        float h1 = __bfloat162float(hb[(size_t)s1 * HID + lane]);
        float h2 = __bfloat162float(hb[(size_t)s2 * HID + lane]);
        float h3 = __bfloat162float(hb[(size_t)s3 * HID + lane]);
        sum = fmaf(h0, dinv[s0] * dv, sum);
        sum = fmaf(h1, dinv[s1] * dv, sum);
        sum = fmaf(h2, dinv[s2] * dv, sum);
        sum = fmaf(h3, dinv[s3] * dv, sum);
    }
    for (; e < end; ++e) {
        int s0 = csr_src[e];
        sum = fmaf(__bfloat162float(hb[(size_t)s0 * HID + lane]), dinv[s0] * dv, sum);
    }
    if (xb) xb[(size_t)i * HID + lane] = __float2bfloat16(sum + b2[lane]);
    else    acc[(size_t)i * HID + lane] = sum;
}

// ---------------- layer-2 matmul ----------------
__global__ __launch_bounds__(256) void mm2_kernel(
    const float* __restrict__ acc1, const float* __restrict__ W2,
    const float* __restrict__ b1, const float* __restrict__ dinv,
    __hip_bfloat16* __restrict__ hb, float* __restrict__ acc2, int n) {
    __shared__ float w[HID * HID];  // 16 KB
    __shared__ float bs[HID];
    int t = threadIdx.x;
    for (int k = t; k < HID * HID; k += 256) w[k] = W2[k];
    if (t < HID) bs[t] = b1[t];
    __syncthreads();
    int wave = t >> 6, lane = t & 63;
    int i = blockIdx.x * 4 + wave;
    if (i >= n) return;
    float x = fmaxf(acc1[(size_t)i * HID + lane] + bs[lane], 0.0f);
    float acc = 0.0f;
#pragma unroll
    for (int k = 0; k < HID; ++k) {
        acc += __shfl(x, k, 64) * w[k * HID + lane];
    }
    hb[(size_t)i * HID + lane] = __float2bfloat16(acc);
    float dv = dinv[i];
    acc2[(size_t)i * HID + lane] = acc * dv * dv;  // aliases acc1: row read above, safe
}

// ---------------- pair MLP head ----------------
// Weights laundered through asm so the compiler CANNOT rematerialize the loads
// inside the loop (VGPR_Count=52 across r4-r6 proved it was re-loading all 72
// weights from L1 every pair-iteration instead of keeping them resident).
__global__ __launch_bounds__(256, 1) void final_kernel(
    const int* __restrict__ pairs, const float* __restrict__ pf,
    const __hip_bfloat16* __restrict__ xb,
    const float* __restrict__ Wf1, const float* __restrict__ bf1,
    const float* __restrict__ Wf2, const float* __restrict__ bf2,
    float* __restrict__ out, int p) {
    int lane = threadIdx.x & 63;
    int wid  = threadIdx.x >> 6;

#define KEEP(x) asm("" : "+v"(x))
#define LDW(j) float4 w##j = make_float4( \
        Wf1[(4*(j)+0)*64 + lane], Wf1[(4*(j)+1)*64 + lane], \
        Wf1[(4*(j)+2)*64 + lane], Wf1[(4*(j)+3)*64 + lane]); \
        KEEP(w##j.x); KEEP(w##j.y); KEEP(w##j.z); KEEP(w##j.w);
    LDW(0)  LDW(1)  LDW(2)  LDW(3)  LDW(4)  LDW(5)  LDW(6)  LDW(7)
    LDW(8)  LDW(9)  LDW(10) LDW(11) LDW(12) LDW(13) LDW(14) LDW(15)
    LDW(16) LDW(17)
#undef LDW
    float bf1r = bf1[lane];  KEEP(bf1r);
    float w2r  = Wf2[lane];  KEEP(w2r);
    float bf2r = bf2[0];     KEEP(bf2r);
#undef KEEP

    int nw = gridDim.x * 4;
    for (int pi = blockIdx.x * 4 + wid; pi < p; pi += nw) {
        int2 pr = ((const int2*)pairs)[pi];
        float xd = __bfloat162float(xb[(size_t)pr.x * HID + lane]);  // b2 folded in
        float xa = __bfloat162float(xb[(size_t)pr.y * HID + lane]);
        float v  = xd * xa;
        float pfv = (lane < PAT) ? pf[(size_t)pi * PAT + lane] : 0.0f;

        float a0 = bf1r, a1 = 0.0f, a2 = 0.0f, a3 = 0.0f;
#define STEP(j, src, o) \
        a0 = fmaf(readlane_f(src, (o)+0), w##j.x, a0); \
        a1 = fmaf(readlane_f(src, (o)+1), w##j.y, a1); \
        a2 = fmaf(readlane_f(src, (o)+2), w##j.z, a2); \
        a3 = fmaf(readlane_f(src, (o)+3), w##j.w, a3);
        STEP(0,  v, 0)   STEP(1,  v, 4)   STEP(2,  v, 8)   STEP(3,  v, 12)
        STEP(4,  v, 16)  STEP(5,  v, 20)  STEP(6,  v, 24)  STEP(7,  v, 28)
        STEP(8,  v, 32)  STEP(9,  v, 36)  STEP(10, v, 40)  STEP(11, v, 44)
        STEP(12, v, 48)  STEP(13, v, 52)  STEP(14, v, 56)  STEP(15, v, 60)
        STEP(16, pfv, 0) STEP(17, pfv, 4)
#undef STEP
        float acc = (a0 + a1) + (a2 + a3);
        float r = fmaxf(acc, 0.0f) * w2r;
#pragma unroll
        for (int off = 32; off > 0; off >>= 1)
            r += __shfl_xor(r, off, 64);
        if (lane == 0)
            out[pi] = 1.0f / (1.0f + expf(-(r + bf2r)));
    }
}

extern "C" void kernel_launch(void* const* d_in, const int* in_sizes, int n_in,
                              void* d_out, int out_size, void* d_ws, size_t ws_size,
                              hipStream_t stream) {
    const int*   edge_index = (const int*)d_in[0];
    const int*   edge_pairs = (const int*)d_in[1];
    const float* pf         = (const float*)d_in[2];
    const float* emb        = (const float*)d_in[3];
    const float* W1         = (const float*)d_in[4];
    const float* b1         = (const float*)d_in[5];
    const float* W2         = (const float*)d_in[6];
    const float* b2         = (const float*)d_in[7];
    const float* Wf1        = (const float*)d_in[8];
    const float* bf1        = (const float*)d_in[9];
    const float* Wf2        = (const float*)d_in[10];
    const float* bf2        = (const float*)d_in[11];
    float*       out        = (float*)d_out;

    const int E = in_sizes[0] / 2;
    const int P = in_sizes[1] / 2;
    const int N = in_sizes[3] / EMB;
    const int NB = (N + 255) / 256;   // <=1024 for scan_partials

    char* ws = (char*)d_ws;
    size_t off = 0;
    float*          dinv    = (float*)(ws + off);          off += ((size_t)N * 4 + 255) & ~255ULL;
    __hip_bfloat16* bufHb   = (__hip_bfloat16*)(ws + off); off += ((size_t)N * HID * 2 + 255) & ~255ULL;
    float*          bufA    = (float*)(ws + off);          off += ((size_t)N * HID * 4 + 255) & ~255ULL;
    __hip_bfloat16* xb      = (__hip_bfloat16*)(ws + off); off += ((size_t)N * HID * 2 + 255) & ~255ULL;
    int*            count   = (int*)(ws + off);            off += ((size_t)N * 4 + 255) & ~255ULL;
    int*            row_ptr = (int*)(ws + off);            off += ((size_t)N * 4 + 255) & ~255ULL;
    int*            cursor  = (int*)(ws + off);            off += ((size_t)N * 4 + 255) & ~255ULL;
    int*            bsum    = (int*)(ws + off);            off += ((size_t)NB * 4 + 255) & ~255ULL;
    int*            boff    = (int*)(ws + off);            off += ((size_t)NB * 4 + 255) & ~255ULL;
    int*            csr_src = (int*)(ws + off);            off += ((size_t)E * 4 + 255) & ~255ULL;
    (void)ws_size;

    // ---- CSR build (also produces dinv) ----
    hipMemsetAsync(count, 0, (size_t)N * 4, stream);
    hist_kernel<<<(E + 255) / 256, 256, 0, stream>>>(edge_index + E, count, E);
    block_sum_kernel<<<NB, 256, 0, stream>>>(count, bsum, N);
    scan_partials_kernel<<<1, 1024, 0, stream>>>(bsum, boff, NB);
    scan_final_kernel<<<NB, 256, 0, stream>>>(count, boff, row_ptr, cursor, dinv, N);
    scatter_kernel<<<(E + 255) / 256, 256, 0, stream>>>(edge_index, cursor, csr_src, E);

    // ---- layer 1 ----
    mm1_kernel<<<(N + 3) / 4, 256, 0, stream>>>(emb, W1, dinv, bufHb, bufA, N);
    gather_kernel<<<(N + 3) / 4, 256, 0, stream>>>(row_ptr, cursor, csr_src, dinv,
                                                   bufHb, bufA, (__hip_bfloat16*)nullptr, nullptr, N);

    // ---- layer 2 ----
    mm2_kernel<<<(N + 3) / 4, 256, 0, stream>>>(bufA, W2, b1, dinv, bufHb, bufA, N);
    gather_kernel<<<(N + 3) / 4, 256, 0, stream>>>(row_ptr, cursor, csr_src, dinv,
                                                   bufHb, bufA, xb, b2, N);

    // ---- pair MLP head ----
    final_kernel<<<2048, 256, 0, stream>>>(edge_pairs, pf, xb,
                                           Wf1, bf1, Wf2, bf2, out, P);
}

// Round 8
// 845.801 us; speedup vs baseline: 3.3801x; 1.3992x over previous
//
#include <hip/hip_runtime.h>
#include <hip/hip_bf16.h>
#include <math.h>

#define EMB 32
#define HID 64
#define PAT 8

typedef __attribute__((ext_vector_type(8))) short short8v;   // 8 bf16 = 4 VGPRs
typedef __attribute__((ext_vector_type(16))) float f32x16;   // MFMA 32x32 accumulator

union Frag {
    short8v s8;
    uint4 u4;
    __hip_bfloat162 h2[4];
    __hip_bfloat16 h[8];
    unsigned short us[8];
};

// ---------------- CSR build ----------------
__global__ void hist_kernel(const int* __restrict__ dst, int* __restrict__ count, int e) {
    int i = blockIdx.x * blockDim.x + threadIdx.x;
    if (i < e) atomicAdd(&count[dst[i]], 1);
}

__global__ void block_sum_kernel(const int* __restrict__ count, int* __restrict__ bsum, int n) {
    __shared__ int s[256];
    int t = threadIdx.x, i = blockIdx.x * 256 + t;
    s[t] = (i < n) ? count[i] : 0;
    __syncthreads();
    for (int off = 128; off > 0; off >>= 1) {
        if (t < off) s[t] += s[t + off];
        __syncthreads();
    }
    if (t == 0) bsum[blockIdx.x] = s[0];
}

__global__ void scan_partials_kernel(const int* __restrict__ bsum, int* __restrict__ boff, int nb) {
    __shared__ int s[1024];
    int t = threadIdx.x;
    int v = (t < nb) ? bsum[t] : 0;
    s[t] = v;
    __syncthreads();
    for (int off = 1; off < 1024; off <<= 1) {
        int u = (t >= off) ? s[t - off] : 0;
        __syncthreads();
        s[t] += u;
        __syncthreads();
    }
    if (t < nb) boff[t] = s[t] - v;  // exclusive
}

__global__ void scan_final_kernel(const int* __restrict__ count, const int* __restrict__ boff,
                                  int* __restrict__ row_ptr, int* __restrict__ cursor,
                                  float* __restrict__ dinv, int n) {
    __shared__ int s[256];
    int t = threadIdx.x, i = blockIdx.x * 256 + t;
    int c = (i < n) ? count[i] : 0;
    s[t] = c;
    __syncthreads();
    for (int off = 1; off < 256; off <<= 1) {
        int u = (t >= off) ? s[t - off] : 0;
        __syncthreads();
        s[t] += u;
        __syncthreads();
    }
    if (i < n) {
        int rp = s[t] - c + boff[blockIdx.x];
        row_ptr[i] = rp;
        cursor[i]  = rp;
        dinv[i]    = rsqrtf(1.0f + (float)c);  // +1 self-loop
    }
}

__global__ void scatter_kernel(const int* __restrict__ ei, int* __restrict__ cursor,
                               int* __restrict__ csr_src, int e) {
    int i = blockIdx.x * blockDim.x + threadIdx.x;
    if (i >= e) return;
    int s = ei[i];
    int d = ei[e + i];
    int pos = atomicAdd(&cursor[d], 1);
    csr_src[pos] = s;
}

// ---------------- pack Wf1 into MFMA B-fragment order (bf16) ----------------
// frag f = c*2+t (k-chunk c 0..4, n-tile t 0..1); lane l; elem e:
//   k = c*16 + (l>>5)*8 + e  (zero-pad k>=72), n = (l&31) + 32*t
// stored at wfrag[f*512 + l*8 + e]
__global__ void prep_wf1_kernel(const float* __restrict__ Wf1, __hip_bfloat16* __restrict__ wfrag) {
    int gid = blockIdx.x * blockDim.x + threadIdx.x;
    if (gid >= 10 * 512) return;
    int f = gid >> 9;
    int rem = gid & 511;
    int l = rem >> 3;
    int e = rem & 7;
    int c = f >> 1;
    int t = f & 1;
    int k = c * 16 + ((l >> 5) << 3) + e;
    int n = (l & 31) + (t << 5);
    float v = (k < HID + PAT) ? Wf1[k * 64 + n] : 0.0f;
    wfrag[gid] = __float2bfloat16(v);
}

// ---------------- layer-1 matmul: hb = bf16(emb @ W1) ; acc = h * dinv^2 (self-loop) ----------------
__global__ __launch_bounds__(256) void mm1_kernel(
    const float* __restrict__ emb, const float* __restrict__ W1,
    const float* __restrict__ dinv,
    __hip_bfloat16* __restrict__ hb, float* __restrict__ acc1, int n) {
    __shared__ float w[EMB * HID];  // 8 KB
    int t = threadIdx.x;
    for (int k = t; k < EMB * HID; k += 256) w[k] = W1[k];
    __syncthreads();
    int wave = t >> 6, lane = t & 63;
    int i = blockIdx.x * 4 + wave;
    if (i >= n) return;
    float e = (lane < EMB) ? emb[i * EMB + lane] : 0.0f;
    float acc = 0.0f;
#pragma unroll
    for (int k = 0; k < EMB; ++k) {
        float ek = __shfl(e, k, 64);
        acc += ek * w[k * HID + lane];
    }
    hb[(size_t)i * HID + lane] = __float2bfloat16(acc);
    float dv = dinv[i];
    acc1[(size_t)i * HID + lane] = acc * dv * dv;
}

// ---------------- CSR gather: sum = acc[i] + sum_e h[src]*dinv[src]*dinv[i] ----------------
__global__ __launch_bounds__(256) void gather_kernel(
    const int* __restrict__ row_ptr, const int* __restrict__ row_end,
    const int* __restrict__ csr_src, const float* __restrict__ dinv,
    const __hip_bfloat16* __restrict__ hb, float* __restrict__ acc,
    __hip_bfloat16* __restrict__ xb, const float* __restrict__ b2, int n) {
    int lane = threadIdx.x & 63;
    int i = blockIdx.x * 4 + (threadIdx.x >> 6);
    if (i >= n) return;
    int e   = row_ptr[i];
    int end = row_end[i];      // cursor after scatter == row end
    float dv = dinv[i];
    float sum = acc[(size_t)i * HID + lane];  // self-loop term from mm kernel
    for (; e + 4 <= end; e += 4) {
        int s0 = csr_src[e], s1 = csr_src[e + 1], s2 = csr_src[e + 2], s3 = csr_src[e + 3];
        float h0 = __bfloat162float(hb[(size_t)s0 * HID + lane]);
        float h1 = __bfloat162float(hb[(size_t)s1 * HID + lane]);
        float h2 = __bfloat162float(hb[(size_t)s2 * HID + lane]);
        float h3 = __bfloat162float(hb[(size_t)s3 * HID + lane]);
        sum = fmaf(h0, dinv[s0] * dv, sum);
        sum = fmaf(h1, dinv[s1] * dv, sum);
        sum = fmaf(h2, dinv[s2] * dv, sum);
        sum = fmaf(h3, dinv[s3] * dv, sum);
    }
    for (; e < end; ++e) {
        int s0 = csr_src[e];
        sum = fmaf(__bfloat162float(hb[(size_t)s0 * HID + lane]), dinv[s0] * dv, sum);
    }
    if (xb) xb[(size_t)i * HID + lane] = __float2bfloat16(sum + b2[lane]);
    else    acc[(size_t)i * HID + lane] = sum;
}

// ---------------- layer-2 matmul ----------------
__global__ __launch_bounds__(256) void mm2_kernel(
    const float* __restrict__ acc1, const float* __restrict__ W2,
    const float* __restrict__ b1, const float* __restrict__ dinv,
    __hip_bfloat16* __restrict__ hb, float* __restrict__ acc2, int n) {
    __shared__ float w[HID * HID];  // 16 KB
    __shared__ float bs[HID];
    int t = threadIdx.x;
    for (int k = t; k < HID * HID; k += 256) w[k] = W2[k];
    if (t < HID) bs[t] = b1[t];
    __syncthreads();
    int wave = t >> 6, lane = t & 63;
    int i = blockIdx.x * 4 + wave;
    if (i >= n) return;
    float x = fmaxf(acc1[(size_t)i * HID + lane] + bs[lane], 0.0f);
    float acc = 0.0f;
#pragma unroll
    for (int k = 0; k < HID; ++k) {
        acc += __shfl(x, k, 64) * w[k * HID + lane];
    }
    hb[(size_t)i * HID + lane] = __float2bfloat16(acc);
    float dv = dinv[i];
    acc2[(size_t)i * HID + lane] = acc * dv * dv;  // aliases acc1: row read above, safe
}

// ---------------- pair MLP head via MFMA ----------------
// Per wave-iteration: 32 pairs. D[pair][channel] = combined[32x80] @ Wf1[80x64]
// (K padded 72->80, 5 chunks of 16; N=64 as 2 tiles of 32) -> 10 mfma_32x32x16_bf16.
// A-frag lane l: row = l&31 (pair), k-slice = chunk*16 + (l>>5)*8; built as
// __hmul2(drug_slice, adr_slice). B-frags pre-packed by prep_wf1_kernel.
// C/D layout (HW-verified): col = lane&31, row = (reg&3)+8*(reg>>2)+4*(lane>>5).
__global__ __launch_bounds__(256) void final_mfma_kernel(
    const int* __restrict__ pairs, const float* __restrict__ pf,
    const __hip_bfloat16* __restrict__ xb, const __hip_bfloat16* __restrict__ wfrag,
    const float* __restrict__ bf1, const float* __restrict__ Wf2,
    const float* __restrict__ bf2, float* __restrict__ out, int p) {
    int lane = threadIdx.x & 63;
    int wid  = threadIdx.x >> 6;
    int half = lane >> 5;
    int lp   = lane & 31;

    float bf1a = bf1[lp];
    float bf1b = bf1[32 + lp];
    float w2a  = Wf2[lp];
    float w2b  = Wf2[32 + lp];
    float bf2r = bf2[0];

    const uint4* wf = (const uint4*)wfrag;   // frag f at wf[f*64 + lane]

    int ngroups = (p + 31) >> 5;
    int nw = gridDim.x * 4;
    for (int g = blockIdx.x * 4 + wid; g < ngroups; g += nw) {
        int p32 = g << 5;
        int pi = p32 + lp; if (pi >= p) pi = p - 1;
        int2 pr = ((const int2*)pairs)[pi];
        const uint4* drow = (const uint4*)(xb + (size_t)pr.x * HID);
        const uint4* arow = (const uint4*)(xb + (size_t)pr.y * HID);

        f32x16 acc0, acc1;
#pragma unroll
        for (int r = 0; r < 16; ++r) { acc0[r] = 0.0f; acc1[r] = 0.0f; }

#pragma unroll
        for (int c = 0; c < 4; ++c) {
            Frag fd, fx, fa, fb0, fb1;
            fd.u4 = drow[c * 2 + half];
            fx.u4 = arow[c * 2 + half];
#pragma unroll
            for (int q = 0; q < 4; ++q) fa.h2[q] = __hmul2(fd.h2[q], fx.h2[q]);
            fb0.u4 = wf[(c * 2 + 0) * 64 + lane];
            fb1.u4 = wf[(c * 2 + 1) * 64 + lane];
            acc0 = __builtin_amdgcn_mfma_f32_32x32x16_bf16(fa.s8, fb0.s8, acc0, 0, 0, 0);
            acc1 = __builtin_amdgcn_mfma_f32_32x32x16_bf16(fa.s8, fb1.s8, acc1, 0, 0, 0);
        }
        {   // chunk 4: patient features (k=64..71 real, 72..79 zero-pad)
            Frag fa, fb0, fb1;
            if (half == 0) {
                float4 lo = ((const float4*)pf)[pi * 2];
                float4 hi = ((const float4*)pf)[pi * 2 + 1];
                fa.h[0] = __float2bfloat16(lo.x); fa.h[1] = __float2bfloat16(lo.y);
                fa.h[2] = __float2bfloat16(lo.z); fa.h[3] = __float2bfloat16(lo.w);
                fa.h[4] = __float2bfloat16(hi.x); fa.h[5] = __float2bfloat16(hi.y);
                fa.h[6] = __float2bfloat16(hi.z); fa.h[7] = __float2bfloat16(hi.w);
            } else {
#pragma unroll
                for (int e = 0; e < 8; ++e) fa.us[e] = 0;
            }
            fb0.u4 = wf[8 * 64 + lane];
            fb1.u4 = wf[9 * 64 + lane];
            acc0 = __builtin_amdgcn_mfma_f32_32x32x16_bf16(fa.s8, fb0.s8, acc0, 0, 0, 0);
            acc1 = __builtin_amdgcn_mfma_f32_32x32x16_bf16(fa.s8, fb1.s8, acc1, 0, 0, 0);
        }

        // per-lane second layer: contrib over this lane's 2 channels (lp, lp+32)
        float t[16];
#pragma unroll
        for (int r = 0; r < 16; ++r)
            t[r] = fmaxf(acc0[r] + bf1a, 0.0f) * w2a + fmaxf(acc1[r] + bf1b, 0.0f) * w2b;

        // reduce over the 32 channels-lanes of each half (rows identical within a half)
#pragma unroll
        for (int off = 1; off < 32; off <<= 1) {
#pragma unroll
            for (int r = 0; r < 16; ++r) t[r] += __shfl_xor(t[r], off, 64);
        }

        // lanes lp<16 of each half: select t[lp] (static cndmask tree), write row m
        if (lp < 16) {
            int j = lp;
            float u[8];
#pragma unroll
            for (int r = 0; r < 8; ++r) u[r] = (j & 1) ? t[2 * r + 1] : t[2 * r];
            float v4[4];
#pragma unroll
            for (int r = 0; r < 4; ++r) v4[r] = (j & 2) ? u[2 * r + 1] : u[2 * r];
            float w2v[2];
#pragma unroll
            for (int r = 0; r < 2; ++r) w2v[r] = (j & 4) ? v4[2 * r + 1] : v4[2 * r];
            float z = (j & 8) ? w2v[1] : w2v[0];
            int m = (j & 3) + ((j >> 2) << 3) + (half << 2);
            int po = p32 + m;
            if (po < p) out[po] = 1.0f / (1.0f + expf(-(z + bf2r)));
        }
    }
}

extern "C" void kernel_launch(void* const* d_in, const int* in_sizes, int n_in,
                              void* d_out, int out_size, void* d_ws, size_t ws_size,
                              hipStream_t stream) {
    const int*   edge_index = (const int*)d_in[0];
    const int*   edge_pairs = (const int*)d_in[1];
    const float* pf         = (const float*)d_in[2];
    const float* emb        = (const float*)d_in[3];
    const float* W1         = (const float*)d_in[4];
    const float* b1         = (const float*)d_in[5];
    const float* W2         = (const float*)d_in[6];
    const float* b2         = (const float*)d_in[7];
    const float* Wf1        = (const float*)d_in[8];
    const float* bf1        = (const float*)d_in[9];
    const float* Wf2        = (const float*)d_in[10];
    const float* bf2        = (const float*)d_in[11];
    float*       out        = (float*)d_out;

    const int E = in_sizes[0] / 2;
    const int P = in_sizes[1] / 2;
    const int N = in_sizes[3] / EMB;
    const int NB = (N + 255) / 256;   // <=1024 for scan_partials

    char* ws = (char*)d_ws;
    size_t off = 0;
    float*          dinv    = (float*)(ws + off);          off += ((size_t)N * 4 + 255) & ~255ULL;
    __hip_bfloat16* bufHb   = (__hip_bfloat16*)(ws + off); off += ((size_t)N * HID * 2 + 255) & ~255ULL;
    float*          bufA    = (float*)(ws + off);          off += ((size_t)N * HID * 4 + 255) & ~255ULL;
    __hip_bfloat16* xb      = (__hip_bfloat16*)(ws + off); off += ((size_t)N * HID * 2 + 255) & ~255ULL;
    __hip_bfloat16* wfrag   = (__hip_bfloat16*)(ws + off); off += ((size_t)10 * 512 * 2 + 255) & ~255ULL;
    int*            count   = (int*)(ws + off);            off += ((size_t)N * 4 + 255) & ~255ULL;
    int*            row_ptr = (int*)(ws + off);            off += ((size_t)N * 4 + 255) & ~255ULL;
    int*            cursor  = (int*)(ws + off);            off += ((size_t)N * 4 + 255) & ~255ULL;
    int*            bsum    = (int*)(ws + off);            off += ((size_t)NB * 4 + 255) & ~255ULL;
    int*            boff    = (int*)(ws + off);            off += ((size_t)NB * 4 + 255) & ~255ULL;
    int*            csr_src = (int*)(ws + off);            off += ((size_t)E * 4 + 255) & ~255ULL;
    (void)ws_size;

    // ---- CSR build (also produces dinv) + Wf1 fragment pack ----
    hipMemsetAsync(count, 0, (size_t)N * 4, stream);
    hist_kernel<<<(E + 255) / 256, 256, 0, stream>>>(edge_index + E, count, E);
    prep_wf1_kernel<<<20, 256, 0, stream>>>(Wf1, wfrag);
    block_sum_kernel<<<NB, 256, 0, stream>>>(count, bsum, N);
    scan_partials_kernel<<<1, 1024, 0, stream>>>(bsum, boff, NB);
    scan_final_kernel<<<NB, 256, 0, stream>>>(count, boff, row_ptr, cursor, dinv, N);
    scatter_kernel<<<(E + 255) / 256, 256, 0, stream>>>(edge_index, cursor, csr_src, E);

    // ---- layer 1 ----
    mm1_kernel<<<(N + 3) / 4, 256, 0, stream>>>(emb, W1, dinv, bufHb, bufA, N);
    gather_kernel<<<(N + 3) / 4, 256, 0, stream>>>(row_ptr, cursor, csr_src, dinv,
                                                   bufHb, bufA, (__hip_bfloat16*)nullptr, nullptr, N);

    // ---- layer 2 ----
    mm2_kernel<<<(N + 3) / 4, 256, 0, stream>>>(bufA, W2, b1, dinv, bufHb, bufA, N);
    gather_kernel<<<(N + 3) / 4, 256, 0, stream>>>(row_ptr, cursor, csr_src, dinv,
                                                   bufHb, bufA, xb, b2, N);

    // ---- pair MLP head (MFMA) ----
    final_mfma_kernel<<<2048, 256, 0, stream>>>(edge_pairs, pf, xb, wfrag,
                                                bf1, Wf2, bf2, out, P);
}

// Round 9
// 645.273 us; speedup vs baseline: 4.4305x; 1.3108x over previous
//
#include <hip/hip_runtime.h>
#include <hip/hip_bf16.h>
#include <math.h>

#define EMB 32
#define HID 64
#define PAT 8

#define BSH   9                 // nodes per bucket = 512
#define NBMAX 256               // max buckets supported (N <= 131072)
#define CHUNK 4096              // edges per partition block

typedef __attribute__((ext_vector_type(8))) short short8v;   // 8 bf16 = 4 VGPRs
typedef __attribute__((ext_vector_type(16))) float f32x16;   // MFMA 32x32 accumulator

union Frag {
    short8v s8;
    uint4 u4;
    __hip_bfloat162 h2[4];
    __hip_bfloat16 h[8];
    unsigned short us[8];
};

// ---------------- degree histogram ----------------
__global__ void hist_kernel(const int* __restrict__ dst, int* __restrict__ count, int e) {
    int i = blockIdx.x * blockDim.x + threadIdx.x;
    if (i < e) atomicAdd(&count[dst[i]], 1);
}

__global__ void block_sum_kernel(const int* __restrict__ count, int* __restrict__ bsum, int n) {
    __shared__ int s[256];
    int t = threadIdx.x, i = blockIdx.x * 256 + t;
    s[t] = (i < n) ? count[i] : 0;
    __syncthreads();
    for (int off = 128; off > 0; off >>= 1) {
        if (t < off) s[t] += s[t + off];
        __syncthreads();
    }
    if (t == 0) bsum[blockIdx.x] = s[0];
}

__global__ void scan_partials_kernel(const int* __restrict__ bsum, int* __restrict__ boff, int nb) {
    __shared__ int s[1024];
    int t = threadIdx.x;
    int v = (t < nb) ? bsum[t] : 0;
    s[t] = v;
    __syncthreads();
    for (int off = 1; off < 1024; off <<= 1) {
        int u = (t >= off) ? s[t - off] : 0;
        __syncthreads();
        s[t] += u;
        __syncthreads();
    }
    if (t < nb) boff[t] = s[t] - v;  // exclusive
}

// row_ptr / rend / dinv from counts
__global__ void scan_final_kernel(const int* __restrict__ count, const int* __restrict__ boff,
                                  int* __restrict__ row_ptr, int* __restrict__ rend,
                                  float* __restrict__ dinv, int n) {
    __shared__ int s[256];
    int t = threadIdx.x, i = blockIdx.x * 256 + t;
    int c = (i < n) ? count[i] : 0;
    s[t] = c;
    __syncthreads();
    for (int off = 1; off < 256; off <<= 1) {
        int u = (t >= off) ? s[t - off] : 0;
        __syncthreads();
        s[t] += u;
        __syncthreads();
    }
    if (i < n) {
        int rp = s[t] - c + boff[blockIdx.x];
        row_ptr[i] = rp;
        rend[i]    = rp + c;
        dinv[i]    = rsqrtf(1.0f + (float)c);  // +1 self-loop
    }
}

// bucket cursor init: bucket b's pair-region base = row_ptr[b<<BSH]
__global__ void cursor_init_kernel(const int* __restrict__ row_ptr, int* __restrict__ bcur,
                                   int n, int nbuck) {
    int b = blockIdx.x * blockDim.x + threadIdx.x;
    if (b < nbuck) bcur[b] = row_ptr[b << BSH];
}

// ---------------- pass A: LDS-staged partition of (src,dst) by dst bucket ----------------
__global__ __launch_bounds__(256) void partition_kernel(
    const int* __restrict__ ei, int* __restrict__ bcur,
    int2* __restrict__ pairs, int e) {
    __shared__ int cnt[NBMAX];
    __shared__ int scn[NBMAX];   // pristine exclusive scan
    __shared__ int loff[NBMAX];  // mutable copy for distribution
    __shared__ int base[NBMAX];  // global base per bucket for this block
    __shared__ int2 stg[CHUNK];
    int t = threadIdx.x;
    int e0 = blockIdx.x * CHUNK;
    int ecnt = min(CHUNK, e - e0);

    for (int k = t; k < NBMAX; k += 256) cnt[k] = 0;
    __syncthreads();
    for (int k = t; k < ecnt; k += 256)
        atomicAdd(&cnt[ei[e + e0 + k] >> BSH], 1);
    __syncthreads();
    // exclusive scan over 256 buckets (blockDim == 256)
    int c = cnt[t];
    scn[t] = c;
    __syncthreads();
    for (int off = 1; off < 256; off <<= 1) {
        int u = (t >= off) ? scn[t - off] : 0;
        __syncthreads();
        scn[t] += u;
        __syncthreads();
    }
    int ex = scn[t] - c;
    __syncthreads();
    scn[t] = ex;
    loff[t] = ex;
    base[t] = c ? atomicAdd(&bcur[t], c) : 0;
    __syncthreads();
    // distribute into LDS staging, bucket-grouped
    for (int k = t; k < ecnt; k += 256) {
        int s = ei[e0 + k];
        int d = ei[e + e0 + k];
        int pos = atomicAdd(&loff[d >> BSH], 1);
        stg[pos] = make_int2(s, d);
    }
    __syncthreads();
    // coalesced flush: staging index k -> pairs[base[b] + (k - scn[b])]
    for (int k = t; k < ecnt; k += 256) {
        int2 pr = stg[k];
        int b = pr.y >> BSH;
        pairs[base[b] + (k - scn[b])] = pr;
    }
}

// ---------------- pass B: per-bucket scatter into exact CSR rows (L2-local) ----------------
__global__ __launch_bounds__(256) void bucket_scatter_kernel(
    const int* __restrict__ row_ptr, const int2* __restrict__ pairs,
    int* __restrict__ csr_src, int n, int e) {
    __shared__ int cur[1 << BSH];
    int b = blockIdx.x;
    int n0 = b << BSH;
    int n1 = min(n0 + (1 << BSH), n);
    int t = threadIdx.x;
    for (int k = n0 + t; k < n1; k += 256) cur[k - n0] = row_ptr[k];
    __syncthreads();
    int p0 = row_ptr[n0];
    int p1 = (n1 < n) ? row_ptr[n1] : e;
    for (int k = p0 + t; k < p1; k += 256) {
        int2 pr = pairs[k];
        int pos = atomicAdd(&cur[pr.y - n0], 1);
        csr_src[pos] = pr.x;
    }
}

// ---------------- pack Wf1 into MFMA B-fragment order (bf16) ----------------
__global__ void prep_wf1_kernel(const float* __restrict__ Wf1, __hip_bfloat16* __restrict__ wfrag) {
    int gid = blockIdx.x * blockDim.x + threadIdx.x;
    if (gid >= 10 * 512) return;
    int f = gid >> 9;
    int rem = gid & 511;
    int l = rem >> 3;
    int e = rem & 7;
    int c = f >> 1;
    int t = f & 1;
    int k = c * 16 + ((l >> 5) << 3) + e;
    int n = (l & 31) + (t << 5);
    float v = (k < HID + PAT) ? Wf1[k * 64 + n] : 0.0f;
    wfrag[gid] = __float2bfloat16(v);
}

// ---------------- layer-1 matmul: hb = bf16(emb @ W1) ; acc = h * dinv^2 (self-loop) ----------------
__global__ __launch_bounds__(256) void mm1_kernel(
    const float* __restrict__ emb, const float* __restrict__ W1,
    const float* __restrict__ dinv,
    __hip_bfloat16* __restrict__ hb, float* __restrict__ acc1, int n) {
    __shared__ float w[EMB * HID];  // 8 KB
    int t = threadIdx.x;
    for (int k = t; k < EMB * HID; k += 256) w[k] = W1[k];
    __syncthreads();
    int wave = t >> 6, lane = t & 63;
    int i = blockIdx.x * 4 + wave;
    if (i >= n) return;
    float e = (lane < EMB) ? emb[i * EMB + lane] : 0.0f;
    float acc = 0.0f;
#pragma unroll
    for (int k = 0; k < EMB; ++k) {
        float ek = __shfl(e, k, 64);
        acc += ek * w[k * HID + lane];
    }
    hb[(size_t)i * HID + lane] = __float2bfloat16(acc);
    float dv = dinv[i];
    acc1[(size_t)i * HID + lane] = acc * dv * dv;
}

// ---------------- CSR gather: sum = acc[i] + sum_e h[src]*dinv[src]*dinv[i] ----------------
__global__ __launch_bounds__(256) void gather_kernel(
    const int* __restrict__ row_ptr, const int* __restrict__ row_end,
    const int* __restrict__ csr_src, const float* __restrict__ dinv,
    const __hip_bfloat16* __restrict__ hb, float* __restrict__ acc,
    __hip_bfloat16* __restrict__ xb, const float* __restrict__ b2, int n) {
    int lane = threadIdx.x & 63;
    int i = blockIdx.x * 4 + (threadIdx.x >> 6);
    if (i >= n) return;
    int e   = row_ptr[i];
    int end = row_end[i];
    float dv = dinv[i];
    float sum = acc[(size_t)i * HID + lane];  // self-loop term from mm kernel
    for (; e + 4 <= end; e += 4) {
        int s0 = csr_src[e], s1 = csr_src[e + 1], s2 = csr_src[e + 2], s3 = csr_src[e + 3];
        float h0 = __bfloat162float(hb[(size_t)s0 * HID + lane]);
        float h1 = __bfloat162float(hb[(size_t)s1 * HID + lane]);
        float h2 = __bfloat162float(hb[(size_t)s2 * HID + lane]);
        float h3 = __bfloat162float(hb[(size_t)s3 * HID + lane]);
        sum = fmaf(h0, dinv[s0] * dv, sum);
        sum = fmaf(h1, dinv[s1] * dv, sum);
        sum = fmaf(h2, dinv[s2] * dv, sum);
        sum = fmaf(h3, dinv[s3] * dv, sum);
    }
    for (; e < end; ++e) {
        int s0 = csr_src[e];
        sum = fmaf(__bfloat162float(hb[(size_t)s0 * HID + lane]), dinv[s0] * dv, sum);
    }
    if (xb) xb[(size_t)i * HID + lane] = __float2bfloat16(sum + b2[lane]);
    else    acc[(size_t)i * HID + lane] = sum;
}

// ---------------- layer-2 matmul ----------------
__global__ __launch_bounds__(256) void mm2_kernel(
    const float* __restrict__ acc1, const float* __restrict__ W2,
    const float* __restrict__ b1, const float* __restrict__ dinv,
    __hip_bfloat16* __restrict__ hb, float* __restrict__ acc2, int n) {
    __shared__ float w[HID * HID];  // 16 KB
    __shared__ float bs[HID];
    int t = threadIdx.x;
    for (int k = t; k < HID * HID; k += 256) w[k] = W2[k];
    if (t < HID) bs[t] = b1[t];
    __syncthreads();
    int wave = t >> 6, lane = t & 63;
    int i = blockIdx.x * 4 + wave;
    if (i >= n) return;
    float x = fmaxf(acc1[(size_t)i * HID + lane] + bs[lane], 0.0f);
    float acc = 0.0f;
#pragma unroll
    for (int k = 0; k < HID; ++k) {
        acc += __shfl(x, k, 64) * w[k * HID + lane];
    }
    hb[(size_t)i * HID + lane] = __float2bfloat16(acc);
    float dv = dinv[i];
    acc2[(size_t)i * HID + lane] = acc * dv * dv;  // aliases acc1: row read above, safe
}

// ---------------- pair MLP head via MFMA (see r8 notes; C/D layout HW-verified) ----------------
__global__ __launch_bounds__(256) void final_mfma_kernel(
    const int* __restrict__ pairs, const float* __restrict__ pf,
    const __hip_bfloat16* __restrict__ xb, const __hip_bfloat16* __restrict__ wfrag,
    const float* __restrict__ bf1, const float* __restrict__ Wf2,
    const float* __restrict__ bf2, float* __restrict__ out, int p) {
    int lane = threadIdx.x & 63;
    int wid  = threadIdx.x >> 6;
    int half = lane >> 5;
    int lp   = lane & 31;

    float bf1a = bf1[lp];
    float bf1b = bf1[32 + lp];
    float w2a  = Wf2[lp];
    float w2b  = Wf2[32 + lp];
    float bf2r = bf2[0];

    const uint4* wf = (const uint4*)wfrag;   // frag f at wf[f*64 + lane]

    int ngroups = (p + 31) >> 5;
    int nw = gridDim.x * 4;
    for (int g = blockIdx.x * 4 + wid; g < ngroups; g += nw) {
        int p32 = g << 5;
        int pi = p32 + lp; if (pi >= p) pi = p - 1;
        int2 pr = ((const int2*)pairs)[pi];
        const uint4* drow = (const uint4*)(xb + (size_t)pr.x * HID);
        const uint4* arow = (const uint4*)(xb + (size_t)pr.y * HID);

        f32x16 acc0, acc1;
#pragma unroll
        for (int r = 0; r < 16; ++r) { acc0[r] = 0.0f; acc1[r] = 0.0f; }

#pragma unroll
        for (int c = 0; c < 4; ++c) {
            Frag fd, fx, fa, fb0, fb1;
            fd.u4 = drow[c * 2 + half];
            fx.u4 = arow[c * 2 + half];
#pragma unroll
            for (int q = 0; q < 4; ++q) fa.h2[q] = __hmul2(fd.h2[q], fx.h2[q]);
            fb0.u4 = wf[(c * 2 + 0) * 64 + lane];
            fb1.u4 = wf[(c * 2 + 1) * 64 + lane];
            acc0 = __builtin_amdgcn_mfma_f32_32x32x16_bf16(fa.s8, fb0.s8, acc0, 0, 0, 0);
            acc1 = __builtin_amdgcn_mfma_f32_32x32x16_bf16(fa.s8, fb1.s8, acc1, 0, 0, 0);
        }
        {   // chunk 4: patient features (k=64..71 real, 72..79 zero-pad)
            Frag fa, fb0, fb1;
            if (half == 0) {
                float4 lo = ((const float4*)pf)[pi * 2];
                float4 hi = ((const float4*)pf)[pi * 2 + 1];
                fa.h[0] = __float2bfloat16(lo.x); fa.h[1] = __float2bfloat16(lo.y);
                fa.h[2] = __float2bfloat16(lo.z); fa.h[3] = __float2bfloat16(lo.w);
                fa.h[4] = __float2bfloat16(hi.x); fa.h[5] = __float2bfloat16(hi.y);
                fa.h[6] = __float2bfloat16(hi.z); fa.h[7] = __float2bfloat16(hi.w);
            } else {
#pragma unroll
                for (int e = 0; e < 8; ++e) fa.us[e] = 0;
            }
            fb0.u4 = wf[8 * 64 + lane];
            fb1.u4 = wf[9 * 64 + lane];
            acc0 = __builtin_amdgcn_mfma_f32_32x32x16_bf16(fa.s8, fb0.s8, acc0, 0, 0, 0);
            acc1 = __builtin_amdgcn_mfma_f32_32x32x16_bf16(fa.s8, fb1.s8, acc1, 0, 0, 0);
        }

        float t[16];
#pragma unroll
        for (int r = 0; r < 16; ++r)
            t[r] = fmaxf(acc0[r] + bf1a, 0.0f) * w2a + fmaxf(acc1[r] + bf1b, 0.0f) * w2b;

#pragma unroll
        for (int off = 1; off < 32; off <<= 1) {
#pragma unroll
            for (int r = 0; r < 16; ++r) t[r] += __shfl_xor(t[r], off, 64);
        }

        if (lp < 16) {
            int j = lp;
            float u[8];
#pragma unroll
            for (int r = 0; r < 8; ++r) u[r] = (j & 1) ? t[2 * r + 1] : t[2 * r];
            float v4[4];
#pragma unroll
            for (int r = 0; r < 4; ++r) v4[r] = (j & 2) ? u[2 * r + 1] : u[2 * r];
            float w2v[2];
#pragma unroll
            for (int r = 0; r < 2; ++r) w2v[r] = (j & 4) ? v4[2 * r + 1] : v4[2 * r];
            float z = (j & 8) ? w2v[1] : w2v[0];
            int m = (j & 3) + ((j >> 2) << 3) + (half << 2);
            int po = p32 + m;
            if (po < p) out[po] = 1.0f / (1.0f + expf(-(z + bf2r)));
        }
    }
}

extern "C" void kernel_launch(void* const* d_in, const int* in_sizes, int n_in,
                              void* d_out, int out_size, void* d_ws, size_t ws_size,
                              hipStream_t stream) {
    const int*   edge_index = (const int*)d_in[0];
    const int*   edge_pairs = (const int*)d_in[1];
    const float* pf         = (const float*)d_in[2];
    const float* emb        = (const float*)d_in[3];
    const float* W1         = (const float*)d_in[4];
    const float* b1         = (const float*)d_in[5];
    const float* W2         = (const float*)d_in[6];
    const float* b2         = (const float*)d_in[7];
    const float* Wf1        = (const float*)d_in[8];
    const float* bf1        = (const float*)d_in[9];
    const float* Wf2        = (const float*)d_in[10];
    const float* bf2        = (const float*)d_in[11];
    float*       out        = (float*)d_out;

    const int E = in_sizes[0] / 2;
    const int P = in_sizes[1] / 2;
    const int N = in_sizes[3] / EMB;
    const int NB = (N + 255) / 256;          // <=1024 for scan_partials
    const int NBUCK = (N + (1 << BSH) - 1) >> BSH;   // 196 for N=100k (<=NBMAX)

    char* ws = (char*)d_ws;
    size_t off = 0;
    float*          dinv    = (float*)(ws + off);          off += ((size_t)N * 4 + 255) & ~255ULL;
    __hip_bfloat16* bufHb   = (__hip_bfloat16*)(ws + off); off += ((size_t)N * HID * 2 + 255) & ~255ULL;
    float*          bufA    = (float*)(ws + off);          off += ((size_t)N * HID * 4 + 255) & ~255ULL;
    __hip_bfloat16* xb      = (__hip_bfloat16*)(ws + off); off += ((size_t)N * HID * 2 + 255) & ~255ULL;
    __hip_bfloat16* wfrag   = (__hip_bfloat16*)(ws + off); off += ((size_t)10 * 512 * 2 + 255) & ~255ULL;
    int*            count   = (int*)(ws + off);            off += ((size_t)N * 4 + 255) & ~255ULL;
    int*            row_ptr = (int*)(ws + off);            off += ((size_t)N * 4 + 255) & ~255ULL;
    int*            rend    = (int*)(ws + off);            off += ((size_t)N * 4 + 255) & ~255ULL;
    int*            bsum    = (int*)(ws + off);            off += ((size_t)NB * 4 + 255) & ~255ULL;
    int*            boff    = (int*)(ws + off);            off += ((size_t)NB * 4 + 255) & ~255ULL;
    int*            bcur    = (int*)(ws + off);            off += ((size_t)NBMAX * 4 + 255) & ~255ULL;
    int*            csr_src = (int*)(ws + off);            off += ((size_t)E * 4 + 255) & ~255ULL;
    int2*           pairs2  = (int2*)(ws + off);           off += ((size_t)E * 8 + 255) & ~255ULL;
    (void)ws_size;

    // ---- CSR build (two-level binned scatter) + Wf1 fragment pack ----
    hipMemsetAsync(count, 0, (size_t)N * 4, stream);
    hist_kernel<<<(E + 255) / 256, 256, 0, stream>>>(edge_index + E, count, E);
    prep_wf1_kernel<<<20, 256, 0, stream>>>(Wf1, wfrag);
    block_sum_kernel<<<NB, 256, 0, stream>>>(count, bsum, N);
    scan_partials_kernel<<<1, 1024, 0, stream>>>(bsum, boff, NB);
    scan_final_kernel<<<NB, 256, 0, stream>>>(count, boff, row_ptr, rend, dinv, N);
    cursor_init_kernel<<<1, 256, 0, stream>>>(row_ptr, bcur, N, NBUCK);
    partition_kernel<<<(E + CHUNK - 1) / CHUNK, 256, 0, stream>>>(edge_index, bcur, pairs2, E);
    bucket_scatter_kernel<<<NBUCK, 256, 0, stream>>>(row_ptr, pairs2, csr_src, N, E);

    // ---- layer 1 ----
    mm1_kernel<<<(N + 3) / 4, 256, 0, stream>>>(emb, W1, dinv, bufHb, bufA, N);
    gather_kernel<<<(N + 3) / 4, 256, 0, stream>>>(row_ptr, rend, csr_src, dinv,
                                                   bufHb, bufA, (__hip_bfloat16*)nullptr, nullptr, N);

    // ---- layer 2 ----
    mm2_kernel<<<(N + 3) / 4, 256, 0, stream>>>(bufA, W2, b1, dinv, bufHb, bufA, N);
    gather_kernel<<<(N + 3) / 4, 256, 0, stream>>>(row_ptr, rend, csr_src, dinv,
                                                   bufHb, bufA, xb, b2, N);

    // ---- pair MLP head (MFMA) ----
    final_mfma_kernel<<<2048, 256, 0, stream>>>(edge_pairs, pf, xb, wfrag,
                                                bf1, Wf2, bf2, out, P);
}

// Round 10
// 543.188 us; speedup vs baseline: 5.2631x; 1.1879x over previous
//
#include <hip/hip_runtime.h>
#include <hip/hip_bf16.h>
#include <math.h>

#define EMB 32
#define HID 64
#define PAT 8

#define BSH   9                 // nodes per bucket = 512
#define NBMAX 256               // max buckets supported (N <= 131072)
#define CHUNK 4096              // edges per partition block

typedef __attribute__((ext_vector_type(8))) short short8v;   // 8 bf16 = 4 VGPRs
typedef __attribute__((ext_vector_type(16))) float f32x16;   // MFMA 32x32 accumulator

union Frag {
    short8v s8;
    uint4 u4;
    __hip_bfloat162 h2[4];
    __hip_bfloat16 h[8];
    unsigned short us[8];
};

// ---------------- pass 0: per-block LDS bucket histogram (replaces per-node global hist) ----------------
__global__ __launch_bounds__(256) void bucket_hist_kernel(
    const int* __restrict__ dst, int* __restrict__ btot, int e) {
    __shared__ int cnt[NBMAX];
    int t = threadIdx.x;
    for (int k = t; k < NBMAX; k += 256) cnt[k] = 0;
    __syncthreads();
    int e0 = blockIdx.x * CHUNK;
    int ec = min(CHUNK, e - e0);
    for (int k = t; k < ec; k += 256)
        atomicAdd(&cnt[dst[e0 + k] >> BSH], 1);
    __syncthreads();
    for (int k = t; k < NBMAX; k += 256)
        if (cnt[k]) atomicAdd(&btot[k], cnt[k]);
}

// one block: exclusive scan of bucket totals -> bbase (197 entries), bcur
__global__ void scan_buckets_kernel(const int* __restrict__ btot, int* __restrict__ bbase,
                                    int* __restrict__ bcur, int nbuck, int e) {
    __shared__ int s[256];
    int t = threadIdx.x;
    int v = (t < nbuck) ? btot[t] : 0;
    s[t] = v;
    __syncthreads();
    for (int off = 1; off < 256; off <<= 1) {
        int u = (t >= off) ? s[t - off] : 0;
        __syncthreads();
        s[t] += u;
        __syncthreads();
    }
    if (t < nbuck) {
        int ex = s[t] - v;
        bbase[t] = ex;
        bcur[t]  = ex;
    }
    if (t == 0) bbase[nbuck] = e;
}

// ---------------- pass A: LDS-staged partition of (src,dst) by dst bucket ----------------
__global__ __launch_bounds__(256) void partition_kernel(
    const int* __restrict__ ei, int* __restrict__ bcur,
    int2* __restrict__ pairs, int e) {
    __shared__ int cnt[NBMAX];
    __shared__ int scn[NBMAX];   // pristine exclusive scan
    __shared__ int loff[NBMAX];  // mutable copy for distribution
    __shared__ int base[NBMAX];  // global base per bucket for this block
    __shared__ int2 stg[CHUNK];
    int t = threadIdx.x;
    int e0 = blockIdx.x * CHUNK;
    int ecnt = min(CHUNK, e - e0);

    for (int k = t; k < NBMAX; k += 256) cnt[k] = 0;
    __syncthreads();
    for (int k = t; k < ecnt; k += 256)
        atomicAdd(&cnt[ei[e + e0 + k] >> BSH], 1);
    __syncthreads();
    int c = cnt[t];
    scn[t] = c;
    __syncthreads();
    for (int off = 1; off < 256; off <<= 1) {
        int u = (t >= off) ? scn[t - off] : 0;
        __syncthreads();
        scn[t] += u;
        __syncthreads();
    }
    int ex = scn[t] - c;
    __syncthreads();
    scn[t] = ex;
    loff[t] = ex;
    base[t] = c ? atomicAdd(&bcur[t], c) : 0;
    __syncthreads();
    for (int k = t; k < ecnt; k += 256) {
        int s = ei[e0 + k];
        int d = ei[e + e0 + k];
        int pos = atomicAdd(&loff[d >> BSH], 1);
        stg[pos] = make_int2(s, d);
    }
    __syncthreads();
    for (int k = t; k < ecnt; k += 256) {
        int2 pr = stg[k];
        int b = pr.y >> BSH;
        pairs[base[b] + (k - scn[b])] = pr;
    }
}

// ---------------- pass B: per-bucket count+scan+scatter; emits row_ptr/rend/dinv/csr_src ----------------
__global__ __launch_bounds__(256) void bucket_scatter_kernel(
    const int* __restrict__ bbase, const int2* __restrict__ pairs,
    int* __restrict__ csr_src, int* __restrict__ row_ptr, int* __restrict__ rend,
    float* __restrict__ dinv, int n) {
    __shared__ int cnt[1 << BSH];
    __shared__ int scn[256];
    __shared__ int cur[1 << BSH];
    int b = blockIdx.x;
    int n0 = b << BSH;
    int nn = min(1 << BSH, n - n0);
    int t = threadIdx.x;
    cnt[t] = 0; cnt[t + 256] = 0;
    __syncthreads();
    int p0 = bbase[b], p1 = bbase[b + 1];
    // count per node (LDS atomics, avg ~32 hits/counter)
    for (int k = p0 + t; k < p1; k += 256)
        atomicAdd(&cnt[pairs[k].y - n0], 1);
    __syncthreads();
    // scan 512 via pairwise sums + 256 Hillis-Steele
    int ca = cnt[2 * t], cb = cnt[2 * t + 1];
    int c2 = ca + cb;
    scn[t] = c2;
    __syncthreads();
    for (int off = 1; off < 256; off <<= 1) {
        int u = (t >= off) ? scn[t - off] : 0;
        __syncthreads();
        scn[t] += u;
        __syncthreads();
    }
    int ex2 = scn[t] - c2;
    int ea = p0 + ex2;          // row base for node 2t
    int eb = ea + ca;           // row base for node 2t+1
    if (2 * t < nn) {
        row_ptr[n0 + 2 * t] = ea;
        rend[n0 + 2 * t]    = ea + ca;
        dinv[n0 + 2 * t]    = rsqrtf(1.0f + (float)ca);
        cur[2 * t] = ea;
    }
    if (2 * t + 1 < nn) {
        row_ptr[n0 + 2 * t + 1] = eb;
        rend[n0 + 2 * t + 1]    = eb + cb;
        dinv[n0 + 2 * t + 1]    = rsqrtf(1.0f + (float)cb);
        cur[2 * t + 1] = eb;
    }
    __syncthreads();
    // scatter into exact CSR rows (64KB-local region -> lines fully written)
    for (int k = p0 + t; k < p1; k += 256) {
        int2 pr = pairs[k];
        int pos = atomicAdd(&cur[pr.y - n0], 1);
        csr_src[pos] = pr.x;
    }
}

// ---------------- pack Wf1 into MFMA B-fragment order (bf16) ----------------
__global__ void prep_wf1_kernel(const float* __restrict__ Wf1, __hip_bfloat16* __restrict__ wfrag) {
    int gid = blockIdx.x * blockDim.x + threadIdx.x;
    if (gid >= 10 * 512) return;
    int f = gid >> 9;
    int rem = gid & 511;
    int l = rem >> 3;
    int e = rem & 7;
    int c = f >> 1;
    int t = f & 1;
    int k = c * 16 + ((l >> 5) << 3) + e;
    int n = (l & 31) + (t << 5);
    float v = (k < HID + PAT) ? Wf1[k * 64 + n] : 0.0f;
    wfrag[gid] = __float2bfloat16(v);
}

// ---------------- layer-1 matmul: hb = bf16(emb @ W1) ; acc = h * dinv^2 (self-loop) ----------------
__global__ __launch_bounds__(256) void mm1_kernel(
    const float* __restrict__ emb, const float* __restrict__ W1,
    const float* __restrict__ dinv,
    __hip_bfloat16* __restrict__ hb, float* __restrict__ acc1, int n) {
    __shared__ float w[EMB * HID];  // 8 KB
    int t = threadIdx.x;
    for (int k = t; k < EMB * HID; k += 256) w[k] = W1[k];
    __syncthreads();
    int wave = t >> 6, lane = t & 63;
    int i = blockIdx.x * 4 + wave;
    if (i >= n) return;
    float e = (lane < EMB) ? emb[i * EMB + lane] : 0.0f;
    float acc = 0.0f;
#pragma unroll
    for (int k = 0; k < EMB; ++k) {
        float ek = __shfl(e, k, 64);
        acc += ek * w[k * HID + lane];
    }
    hb[(size_t)i * HID + lane] = __float2bfloat16(acc);
    float dv = dinv[i];
    acc1[(size_t)i * HID + lane] = acc * dv * dv;
}

// ---------------- CSR gather: sum = acc[i] + sum_e h[src]*dinv[src]*dinv[i] ----------------
__global__ __launch_bounds__(256) void gather_kernel(
    const int* __restrict__ row_ptr, const int* __restrict__ row_end,
    const int* __restrict__ csr_src, const float* __restrict__ dinv,
    const __hip_bfloat16* __restrict__ hb, float* __restrict__ acc,
    __hip_bfloat16* __restrict__ xb, const float* __restrict__ b2, int n) {
    int lane = threadIdx.x & 63;
    int i = blockIdx.x * 4 + (threadIdx.x >> 6);
    if (i >= n) return;
    int e   = row_ptr[i];
    int end = row_end[i];
    float dv = dinv[i];
    float sum = acc[(size_t)i * HID + lane];  // self-loop term from mm kernel
    for (; e + 4 <= end; e += 4) {
        int s0 = csr_src[e], s1 = csr_src[e + 1], s2 = csr_src[e + 2], s3 = csr_src[e + 3];
        float h0 = __bfloat162float(hb[(size_t)s0 * HID + lane]);
        float h1 = __bfloat162float(hb[(size_t)s1 * HID + lane]);
        float h2 = __bfloat162float(hb[(size_t)s2 * HID + lane]);
        float h3 = __bfloat162float(hb[(size_t)s3 * HID + lane]);
        sum = fmaf(h0, dinv[s0] * dv, sum);
        sum = fmaf(h1, dinv[s1] * dv, sum);
        sum = fmaf(h2, dinv[s2] * dv, sum);
        sum = fmaf(h3, dinv[s3] * dv, sum);
    }
    for (; e < end; ++e) {
        int s0 = csr_src[e];
        sum = fmaf(__bfloat162float(hb[(size_t)s0 * HID + lane]), dinv[s0] * dv, sum);
    }
    if (xb) xb[(size_t)i * HID + lane] = __float2bfloat16(sum + b2[lane]);
    else    acc[(size_t)i * HID + lane] = sum;
}

// ---------------- layer-2 matmul ----------------
__global__ __launch_bounds__(256) void mm2_kernel(
    const float* __restrict__ acc1, const float* __restrict__ W2,
    const float* __restrict__ b1, const float* __restrict__ dinv,
    __hip_bfloat16* __restrict__ hb, float* __restrict__ acc2, int n) {
    __shared__ float w[HID * HID];  // 16 KB
    __shared__ float bs[HID];
    int t = threadIdx.x;
    for (int k = t; k < HID * HID; k += 256) w[k] = W2[k];
    if (t < HID) bs[t] = b1[t];
    __syncthreads();
    int wave = t >> 6, lane = t & 63;
    int i = blockIdx.x * 4 + wave;
    if (i >= n) return;
    float x = fmaxf(acc1[(size_t)i * HID + lane] + bs[lane], 0.0f);
    float acc = 0.0f;
#pragma unroll
    for (int k = 0; k < HID; ++k) {
        acc += __shfl(x, k, 64) * w[k * HID + lane];
    }
    hb[(size_t)i * HID + lane] = __float2bfloat16(acc);
    float dv = dinv[i];
    acc2[(size_t)i * HID + lane] = acc * dv * dv;  // aliases acc1: row read above, safe
}

// ---------------- pair MLP head via MFMA (C/D layout HW-verified) ----------------
__global__ __launch_bounds__(256) void final_mfma_kernel(
    const int* __restrict__ pairs, const float* __restrict__ pf,
    const __hip_bfloat16* __restrict__ xb, const __hip_bfloat16* __restrict__ wfrag,
    const float* __restrict__ bf1, const float* __restrict__ Wf2,
    const float* __restrict__ bf2, float* __restrict__ out, int p) {
    int lane = threadIdx.x & 63;
    int wid  = threadIdx.x >> 6;
    int half = lane >> 5;
    int lp   = lane & 31;

    float bf1a = bf1[lp];
    float bf1b = bf1[32 + lp];
    float w2a  = Wf2[lp];
    float w2b  = Wf2[32 + lp];
    float bf2r = bf2[0];

    const uint4* wf = (const uint4*)wfrag;   // frag f at wf[f*64 + lane]

    int ngroups = (p + 31) >> 5;
    int nw = gridDim.x * 4;
    for (int g = blockIdx.x * 4 + wid; g < ngroups; g += nw) {
        int p32 = g << 5;
        int pi = p32 + lp; if (pi >= p) pi = p - 1;
        int2 pr = ((const int2*)pairs)[pi];
        const uint4* drow = (const uint4*)(xb + (size_t)pr.x * HID);
        const uint4* arow = (const uint4*)(xb + (size_t)pr.y * HID);

        f32x16 acc0, acc1;
#pragma unroll
        for (int r = 0; r < 16; ++r) { acc0[r] = 0.0f; acc1[r] = 0.0f; }

#pragma unroll
        for (int c = 0; c < 4; ++c) {
            Frag fd, fx, fa, fb0, fb1;
            fd.u4 = drow[c * 2 + half];
            fx.u4 = arow[c * 2 + half];
#pragma unroll
            for (int q = 0; q < 4; ++q) fa.h2[q] = __hmul2(fd.h2[q], fx.h2[q]);
            fb0.u4 = wf[(c * 2 + 0) * 64 + lane];
            fb1.u4 = wf[(c * 2 + 1) * 64 + lane];
            acc0 = __builtin_amdgcn_mfma_f32_32x32x16_bf16(fa.s8, fb0.s8, acc0, 0, 0, 0);
            acc1 = __builtin_amdgcn_mfma_f32_32x32x16_bf16(fa.s8, fb1.s8, acc1, 0, 0, 0);
        }
        {   // chunk 4: patient features (k=64..71 real, 72..79 zero-pad)
            Frag fa, fb0, fb1;
            if (half == 0) {
                float4 lo = ((const float4*)pf)[pi * 2];
                float4 hi = ((const float4*)pf)[pi * 2 + 1];
                fa.h[0] = __float2bfloat16(lo.x); fa.h[1] = __float2bfloat16(lo.y);
                fa.h[2] = __float2bfloat16(lo.z); fa.h[3] = __float2bfloat16(lo.w);
                fa.h[4] = __float2bfloat16(hi.x); fa.h[5] = __float2bfloat16(hi.y);
                fa.h[6] = __float2bfloat16(hi.z); fa.h[7] = __float2bfloat16(hi.w);
            } else {
#pragma unroll
                for (int e = 0; e < 8; ++e) fa.us[e] = 0;
            }
            fb0.u4 = wf[8 * 64 + lane];
            fb1.u4 = wf[9 * 64 + lane];
            acc0 = __builtin_amdgcn_mfma_f32_32x32x16_bf16(fa.s8, fb0.s8, acc0, 0, 0, 0);
            acc1 = __builtin_amdgcn_mfma_f32_32x32x16_bf16(fa.s8, fb1.s8, acc1, 0, 0, 0);
        }

        float t[16];
#pragma unroll
        for (int r = 0; r < 16; ++r)
            t[r] = fmaxf(acc0[r] + bf1a, 0.0f) * w2a + fmaxf(acc1[r] + bf1b, 0.0f) * w2b;

#pragma unroll
        for (int off = 1; off < 32; off <<= 1) {
#pragma unroll
            for (int r = 0; r < 16; ++r) t[r] += __shfl_xor(t[r], off, 64);
        }

        if (lp < 16) {
            int j = lp;
            float u[8];
#pragma unroll
            for (int r = 0; r < 8; ++r) u[r] = (j & 1) ? t[2 * r + 1] : t[2 * r];
            float v4[4];
#pragma unroll
            for (int r = 0; r < 4; ++r) v4[r] = (j & 2) ? u[2 * r + 1] : u[2 * r];
            float w2v[2];
#pragma unroll
            for (int r = 0; r < 2; ++r) w2v[r] = (j & 4) ? v4[2 * r + 1] : v4[2 * r];
            float z = (j & 8) ? w2v[1] : w2v[0];
            int m = (j & 3) + ((j >> 2) << 3) + (half << 2);
            int po = p32 + m;
            if (po < p) out[po] = 1.0f / (1.0f + expf(-(z + bf2r)));
        }
    }
}

extern "C" void kernel_launch(void* const* d_in, const int* in_sizes, int n_in,
                              void* d_out, int out_size, void* d_ws, size_t ws_size,
                              hipStream_t stream) {
    const int*   edge_index = (const int*)d_in[0];
    const int*   edge_pairs = (const int*)d_in[1];
    const float* pf         = (const float*)d_in[2];
    const float* emb        = (const float*)d_in[3];
    const float* W1         = (const float*)d_in[4];
    const float* b1         = (const float*)d_in[5];
    const float* W2         = (const float*)d_in[6];
    const float* b2         = (const float*)d_in[7];
    const float* Wf1        = (const float*)d_in[8];
    const float* bf1        = (const float*)d_in[9];
    const float* Wf2        = (const float*)d_in[10];
    const float* bf2        = (const float*)d_in[11];
    float*       out        = (float*)d_out;

    const int E = in_sizes[0] / 2;
    const int P = in_sizes[1] / 2;
    const int N = in_sizes[3] / EMB;
    const int NBUCK = (N + (1 << BSH) - 1) >> BSH;   // 196 for N=100k (<=NBMAX)

    char* ws = (char*)d_ws;
    size_t off = 0;
    float*          dinv    = (float*)(ws + off);          off += ((size_t)N * 4 + 255) & ~255ULL;
    __hip_bfloat16* bufHb   = (__hip_bfloat16*)(ws + off); off += ((size_t)N * HID * 2 + 255) & ~255ULL;
    float*          bufA    = (float*)(ws + off);          off += ((size_t)N * HID * 4 + 255) & ~255ULL;
    __hip_bfloat16* xb      = (__hip_bfloat16*)(ws + off); off += ((size_t)N * HID * 2 + 255) & ~255ULL;
    __hip_bfloat16* wfrag   = (__hip_bfloat16*)(ws + off); off += ((size_t)10 * 512 * 2 + 255) & ~255ULL;
    int*            row_ptr = (int*)(ws + off);            off += ((size_t)N * 4 + 255) & ~255ULL;
    int*            rend    = (int*)(ws + off);            off += ((size_t)N * 4 + 255) & ~255ULL;
    int*            btot    = (int*)(ws + off);            off += ((size_t)NBMAX * 4 + 255) & ~255ULL;
    int*            bbase   = (int*)(ws + off);            off += ((size_t)(NBMAX + 1) * 4 + 255) & ~255ULL;
    int*            bcur    = (int*)(ws + off);            off += ((size_t)NBMAX * 4 + 255) & ~255ULL;
    int*            csr_src = (int*)(ws + off);            off += ((size_t)E * 4 + 255) & ~255ULL;
    int2*           pairs2  = (int2*)(ws + off);           off += ((size_t)E * 8 + 255) & ~255ULL;
    (void)ws_size;

    const int EBLK = (E + CHUNK - 1) / CHUNK;

    // ---- CSR build (bucket hist -> scan -> partition -> bucket scatter) ----
    hipMemsetAsync(btot, 0, (size_t)NBMAX * 4, stream);
    bucket_hist_kernel<<<EBLK, 256, 0, stream>>>(edge_index + E, btot, E);
    prep_wf1_kernel<<<20, 256, 0, stream>>>(Wf1, wfrag);
    scan_buckets_kernel<<<1, 256, 0, stream>>>(btot, bbase, bcur, NBUCK, E);
    partition_kernel<<<EBLK, 256, 0, stream>>>(edge_index, bcur, pairs2, E);
    bucket_scatter_kernel<<<NBUCK, 256, 0, stream>>>(bbase, pairs2, csr_src,
                                                     row_ptr, rend, dinv, N);

    // ---- layer 1 ----
    mm1_kernel<<<(N + 3) / 4, 256, 0, stream>>>(emb, W1, dinv, bufHb, bufA, N);
    gather_kernel<<<(N + 3) / 4, 256, 0, stream>>>(row_ptr, rend, csr_src, dinv,
                                                   bufHb, bufA, (__hip_bfloat16*)nullptr, nullptr, N);

    // ---- layer 2 ----
    mm2_kernel<<<(N + 3) / 4, 256, 0, stream>>>(bufA, W2, b1, dinv, bufHb, bufA, N);
    gather_kernel<<<(N + 3) / 4, 256, 0, stream>>>(row_ptr, rend, csr_src, dinv,
                                                   bufHb, bufA, xb, b2, N);

    // ---- pair MLP head (MFMA) ----
    final_mfma_kernel<<<2048, 256, 0, stream>>>(edge_pairs, pf, xb, wfrag,
                                                bf1, Wf2, bf2, out, P);
}

// Round 11
// 482.188 us; speedup vs baseline: 5.9289x; 1.1265x over previous
//
#include <hip/hip_runtime.h>
#include <hip/hip_bf16.h>
#include <math.h>

#define EMB 32
#define HID 64
#define PAT 8

#define BSH   9                 // nodes per bucket = 512
#define NBMAX 256               // max buckets supported (N <= 131072)
#define CHUNK 4096              // edges per partition block

typedef __attribute__((ext_vector_type(8))) short short8v;   // 8 bf16 = 4 VGPRs
typedef __attribute__((ext_vector_type(16))) float f32x16;   // MFMA 32x32 accumulator

union Frag {
    short8v s8;
    uint4 u4;
    __hip_bfloat162 h2[4];
    __hip_bfloat16 h[8];
    unsigned short us[8];
};

// ---------------- pass 0: per-block LDS bucket histogram ----------------
__global__ __launch_bounds__(256) void bucket_hist_kernel(
    const int* __restrict__ dst, int* __restrict__ btot, int e) {
    __shared__ int cnt[NBMAX];
    int t = threadIdx.x;
    for (int k = t; k < NBMAX; k += 256) cnt[k] = 0;
    __syncthreads();
    int e0 = blockIdx.x * CHUNK;
    int ec = min(CHUNK, e - e0);
    for (int k = t; k < ec; k += 256)
        atomicAdd(&cnt[dst[e0 + k] >> BSH], 1);
    __syncthreads();
    for (int k = t; k < NBMAX; k += 256)
        if (cnt[k]) atomicAdd(&btot[k], cnt[k]);
}

// one block: exclusive scan of bucket totals -> bbase (197 entries), bcur
__global__ void scan_buckets_kernel(const int* __restrict__ btot, int* __restrict__ bbase,
                                    int* __restrict__ bcur, int nbuck, int e) {
    __shared__ int s[256];
    int t = threadIdx.x;
    int v = (t < nbuck) ? btot[t] : 0;
    s[t] = v;
    __syncthreads();
    for (int off = 1; off < 256; off <<= 1) {
        int u = (t >= off) ? s[t - off] : 0;
        __syncthreads();
        s[t] += u;
        __syncthreads();
    }
    if (t < nbuck) {
        int ex = s[t] - v;
        bbase[t] = ex;
        bcur[t]  = ex;
    }
    if (t == 0) bbase[nbuck] = e;
}

// ---------------- pass A: LDS-staged partition of (src,dst) by dst bucket ----------------
__global__ __launch_bounds__(256) void partition_kernel(
    const int* __restrict__ ei, int* __restrict__ bcur,
    int2* __restrict__ pairs, int e) {
    __shared__ int cnt[NBMAX];
    __shared__ int scn[NBMAX];
    __shared__ int loff[NBMAX];
    __shared__ int base[NBMAX];
    __shared__ int2 stg[CHUNK];
    int t = threadIdx.x;
    int e0 = blockIdx.x * CHUNK;
    int ecnt = min(CHUNK, e - e0);

    for (int k = t; k < NBMAX; k += 256) cnt[k] = 0;
    __syncthreads();
    for (int k = t; k < ecnt; k += 256)
        atomicAdd(&cnt[ei[e + e0 + k] >> BSH], 1);
    __syncthreads();
    int c = cnt[t];
    scn[t] = c;
    __syncthreads();
    for (int off = 1; off < 256; off <<= 1) {
        int u = (t >= off) ? scn[t - off] : 0;
        __syncthreads();
        scn[t] += u;
        __syncthreads();
    }
    int ex = scn[t] - c;
    __syncthreads();
    scn[t] = ex;
    loff[t] = ex;
    base[t] = c ? atomicAdd(&bcur[t], c) : 0;
    __syncthreads();
    for (int k = t; k < ecnt; k += 256) {
        int s = ei[e0 + k];
        int d = ei[e + e0 + k];
        int pos = atomicAdd(&loff[d >> BSH], 1);
        stg[pos] = make_int2(s, d);
    }
    __syncthreads();
    for (int k = t; k < ecnt; k += 256) {
        int2 pr = stg[k];
        int b = pr.y >> BSH;
        pairs[base[b] + (k - scn[b])] = pr;
    }
}

// ---------------- pass B: per-bucket count+scan+scatter; emits row_ptr/rend/dinv/csr_src ----------------
__global__ __launch_bounds__(256) void bucket_scatter_kernel(
    const int* __restrict__ bbase, const int2* __restrict__ pairs,
    int* __restrict__ csr_src, int* __restrict__ row_ptr, int* __restrict__ rend,
    float* __restrict__ dinv, int n) {
    __shared__ int cnt[1 << BSH];
    __shared__ int scn[256];
    __shared__ int cur[1 << BSH];
    int b = blockIdx.x;
    int n0 = b << BSH;
    int nn = min(1 << BSH, n - n0);
    int t = threadIdx.x;
    cnt[t] = 0; cnt[t + 256] = 0;
    __syncthreads();
    int p0 = bbase[b], p1 = bbase[b + 1];
    for (int k = p0 + t; k < p1; k += 256)
        atomicAdd(&cnt[pairs[k].y - n0], 1);
    __syncthreads();
    int ca = cnt[2 * t], cb = cnt[2 * t + 1];
    int c2 = ca + cb;
    scn[t] = c2;
    __syncthreads();
    for (int off = 1; off < 256; off <<= 1) {
        int u = (t >= off) ? scn[t - off] : 0;
        __syncthreads();
        scn[t] += u;
        __syncthreads();
    }
    int ex2 = scn[t] - c2;
    int ea = p0 + ex2;
    int eb = ea + ca;
    if (2 * t < nn) {
        row_ptr[n0 + 2 * t] = ea;
        rend[n0 + 2 * t]    = ea + ca;
        dinv[n0 + 2 * t]    = rsqrtf(1.0f + (float)ca);
        cur[2 * t] = ea;
    }
    if (2 * t + 1 < nn) {
        row_ptr[n0 + 2 * t + 1] = eb;
        rend[n0 + 2 * t + 1]    = eb + cb;
        dinv[n0 + 2 * t + 1]    = rsqrtf(1.0f + (float)cb);
        cur[2 * t + 1] = eb;
    }
    __syncthreads();
    for (int k = p0 + t; k < p1; k += 256) {
        int2 pr = pairs[k];
        int pos = atomicAdd(&cur[pr.y - n0], 1);
        csr_src[pos] = pr.x;
    }
}

// ---------------- pack Wf1 into MFMA B-fragment order (bf16) ----------------
__global__ void prep_wf1_kernel(const float* __restrict__ Wf1, __hip_bfloat16* __restrict__ wfrag) {
    int gid = blockIdx.x * blockDim.x + threadIdx.x;
    if (gid >= 10 * 512) return;
    int f = gid >> 9;
    int rem = gid & 511;
    int l = rem >> 3;
    int e = rem & 7;
    int c = f >> 1;
    int t = f & 1;
    int k = c * 16 + ((l >> 5) << 3) + e;
    int n = (l & 31) + (t << 5);
    float v = (k < HID + PAT) ? Wf1[k * 64 + n] : 0.0f;
    wfrag[gid] = __float2bfloat16(v);
}

// ---------------- layer-1 matmul: hbs1 = bf16((emb @ W1) * dinv) ----------------
// dinv folded into the stored row: edge term becomes just hbs[src]; self-loop = hbs[i].
__global__ __launch_bounds__(256) void mm1_kernel(
    const float* __restrict__ emb, const float* __restrict__ W1,
    const float* __restrict__ dinv,
    __hip_bfloat16* __restrict__ hbs, int n) {
    __shared__ float w[EMB * HID];  // 8 KB
    int t = threadIdx.x;
    for (int k = t; k < EMB * HID; k += 256) w[k] = W1[k];
    __syncthreads();
    int wave = t >> 6, lane = t & 63;
    int i = blockIdx.x * 4 + wave;
    if (i >= n) return;
    float e = (lane < EMB) ? emb[i * EMB + lane] : 0.0f;
    float acc = 0.0f;
#pragma unroll
    for (int k = 0; k < EMB; ++k) {
        float ek = __shfl(e, k, 64);
        acc += ek * w[k * HID + lane];
    }
    hbs[(size_t)i * HID + lane] = __float2bfloat16(acc * dinv[i]);
}

// ---------------- fused gather(layer1) + mm2: hbs2 = bf16((relu(dv*sum+b1) @ W2) * dv) ----------------
__global__ __launch_bounds__(256) void gather_mm2_kernel(
    const int* __restrict__ row_ptr, const int* __restrict__ rend,
    const int* __restrict__ csr_src, const float* __restrict__ dinv,
    const __hip_bfloat16* __restrict__ hbs1, const float* __restrict__ W2,
    const float* __restrict__ b1, __hip_bfloat16* __restrict__ hbs2, int n) {
    __shared__ float w[HID * HID];  // 16 KB
    __shared__ float bs[HID];
    int t = threadIdx.x;
    for (int k = t; k < HID * HID; k += 256) w[k] = W2[k];
    if (t < HID) bs[t] = b1[t];
    __syncthreads();
    int lane = t & 63;
    int i = blockIdx.x * 4 + (t >> 6);
    if (i >= n) return;
    int e   = row_ptr[i];
    int end = rend[i];
    float sum = __bfloat162float(hbs1[(size_t)i * HID + lane]);  // self-loop
    for (; e + 8 <= end; e += 8) {
        int s0 = csr_src[e],     s1 = csr_src[e + 1], s2 = csr_src[e + 2], s3 = csr_src[e + 3];
        int s4 = csr_src[e + 4], s5 = csr_src[e + 5], s6 = csr_src[e + 6], s7 = csr_src[e + 7];
        float h0 = __bfloat162float(hbs1[(size_t)s0 * HID + lane]);
        float h1 = __bfloat162float(hbs1[(size_t)s1 * HID + lane]);
        float h2 = __bfloat162float(hbs1[(size_t)s2 * HID + lane]);
        float h3 = __bfloat162float(hbs1[(size_t)s3 * HID + lane]);
        float h4 = __bfloat162float(hbs1[(size_t)s4 * HID + lane]);
        float h5 = __bfloat162float(hbs1[(size_t)s5 * HID + lane]);
        float h6 = __bfloat162float(hbs1[(size_t)s6 * HID + lane]);
        float h7 = __bfloat162float(hbs1[(size_t)s7 * HID + lane]);
        sum += ((h0 + h1) + (h2 + h3)) + ((h4 + h5) + (h6 + h7));
    }
    for (; e < end; ++e)
        sum += __bfloat162float(hbs1[(size_t)csr_src[e] * HID + lane]);
    float dv = dinv[i];
    float x = fmaxf(fmaf(dv, sum, bs[lane]), 0.0f);
    float acc = 0.0f;
#pragma unroll
    for (int k = 0; k < HID; ++k)
        acc += __shfl(x, k, 64) * w[k * HID + lane];
    hbs2[(size_t)i * HID + lane] = __float2bfloat16(acc * dv);
}

// ---------------- gather(layer2): xb = bf16(dv*sum + b2) ----------------
__global__ __launch_bounds__(256) void gather_out_kernel(
    const int* __restrict__ row_ptr, const int* __restrict__ rend,
    const int* __restrict__ csr_src, const float* __restrict__ dinv,
    const __hip_bfloat16* __restrict__ hbs2, const float* __restrict__ b2,
    __hip_bfloat16* __restrict__ xb, int n) {
    int t = threadIdx.x;
    int lane = t & 63;
    int i = blockIdx.x * 4 + (t >> 6);
    if (i >= n) return;
    int e   = row_ptr[i];
    int end = rend[i];
    float sum = __bfloat162float(hbs2[(size_t)i * HID + lane]);  // self-loop
    for (; e + 8 <= end; e += 8) {
        int s0 = csr_src[e],     s1 = csr_src[e + 1], s2 = csr_src[e + 2], s3 = csr_src[e + 3];
        int s4 = csr_src[e + 4], s5 = csr_src[e + 5], s6 = csr_src[e + 6], s7 = csr_src[e + 7];
        float h0 = __bfloat162float(hbs2[(size_t)s0 * HID + lane]);
        float h1 = __bfloat162float(hbs2[(size_t)s1 * HID + lane]);
        float h2 = __bfloat162float(hbs2[(size_t)s2 * HID + lane]);
        float h3 = __bfloat162float(hbs2[(size_t)s3 * HID + lane]);
        float h4 = __bfloat162float(hbs2[(size_t)s4 * HID + lane]);
        float h5 = __bfloat162float(hbs2[(size_t)s5 * HID + lane]);
        float h6 = __bfloat162float(hbs2[(size_t)s6 * HID + lane]);
        float h7 = __bfloat162float(hbs2[(size_t)s7 * HID + lane]);
        sum += ((h0 + h1) + (h2 + h3)) + ((h4 + h5) + (h6 + h7));
    }
    for (; e < end; ++e)
        sum += __bfloat162float(hbs2[(size_t)csr_src[e] * HID + lane]);
    xb[(size_t)i * HID + lane] = __float2bfloat16(fmaf(dinv[i], sum, b2[lane]));
}

// ---------------- pair MLP head via MFMA (C/D layout HW-verified) ----------------
__global__ __launch_bounds__(256) void final_mfma_kernel(
    const int* __restrict__ pairs, const float* __restrict__ pf,
    const __hip_bfloat16* __restrict__ xb, const __hip_bfloat16* __restrict__ wfrag,
    const float* __restrict__ bf1, const float* __restrict__ Wf2,
    const float* __restrict__ bf2, float* __restrict__ out, int p) {
    int lane = threadIdx.x & 63;
    int wid  = threadIdx.x >> 6;
    int half = lane >> 5;
    int lp   = lane & 31;

    float bf1a = bf1[lp];
    float bf1b = bf1[32 + lp];
    float w2a  = Wf2[lp];
    float w2b  = Wf2[32 + lp];
    float bf2r = bf2[0];

    const uint4* wf = (const uint4*)wfrag;

    int ngroups = (p + 31) >> 5;
    int nw = gridDim.x * 4;
    for (int g = blockIdx.x * 4 + wid; g < ngroups; g += nw) {
        int p32 = g << 5;
        int pi = p32 + lp; if (pi >= p) pi = p - 1;
        int2 pr = ((const int2*)pairs)[pi];
        const uint4* drow = (const uint4*)(xb + (size_t)pr.x * HID);
        const uint4* arow = (const uint4*)(xb + (size_t)pr.y * HID);

        f32x16 acc0, acc1;
#pragma unroll
        for (int r = 0; r < 16; ++r) { acc0[r] = 0.0f; acc1[r] = 0.0f; }

#pragma unroll
        for (int c = 0; c < 4; ++c) {
            Frag fd, fx, fa, fb0, fb1;
            fd.u4 = drow[c * 2 + half];
            fx.u4 = arow[c * 2 + half];
#pragma unroll
            for (int q = 0; q < 4; ++q) fa.h2[q] = __hmul2(fd.h2[q], fx.h2[q]);
            fb0.u4 = wf[(c * 2 + 0) * 64 + lane];
            fb1.u4 = wf[(c * 2 + 1) * 64 + lane];
            acc0 = __builtin_amdgcn_mfma_f32_32x32x16_bf16(fa.s8, fb0.s8, acc0, 0, 0, 0);
            acc1 = __builtin_amdgcn_mfma_f32_32x32x16_bf16(fa.s8, fb1.s8, acc1, 0, 0, 0);
        }
        {   // chunk 4: patient features (k=64..71 real, 72..79 zero-pad)
            Frag fa, fb0, fb1;
            if (half == 0) {
                float4 lo = ((const float4*)pf)[pi * 2];
                float4 hi = ((const float4*)pf)[pi * 2 + 1];
                fa.h[0] = __float2bfloat16(lo.x); fa.h[1] = __float2bfloat16(lo.y);
                fa.h[2] = __float2bfloat16(lo.z); fa.h[3] = __float2bfloat16(lo.w);
                fa.h[4] = __float2bfloat16(hi.x); fa.h[5] = __float2bfloat16(hi.y);
                fa.h[6] = __float2bfloat16(hi.z); fa.h[7] = __float2bfloat16(hi.w);
            } else {
#pragma unroll
                for (int e = 0; e < 8; ++e) fa.us[e] = 0;
            }
            fb0.u4 = wf[8 * 64 + lane];
            fb1.u4 = wf[9 * 64 + lane];
            acc0 = __builtin_amdgcn_mfma_f32_32x32x16_bf16(fa.s8, fb0.s8, acc0, 0, 0, 0);
            acc1 = __builtin_amdgcn_mfma_f32_32x32x16_bf16(fa.s8, fb1.s8, acc1, 0, 0, 0);
        }

        float t[16];
#pragma unroll
        for (int r = 0; r < 16; ++r)
            t[r] = fmaxf(acc0[r] + bf1a, 0.0f) * w2a + fmaxf(acc1[r] + bf1b, 0.0f) * w2b;

#pragma unroll
        for (int off = 1; off < 32; off <<= 1) {
#pragma unroll
            for (int r = 0; r < 16; ++r) t[r] += __shfl_xor(t[r], off, 64);
        }

        if (lp < 16) {
            int j = lp;
            float u[8];
#pragma unroll
            for (int r = 0; r < 8; ++r) u[r] = (j & 1) ? t[2 * r + 1] : t[2 * r];
            float v4[4];
#pragma unroll
            for (int r = 0; r < 4; ++r) v4[r] = (j & 2) ? u[2 * r + 1] : u[2 * r];
            float w2v[2];
#pragma unroll
            for (int r = 0; r < 2; ++r) w2v[r] = (j & 4) ? v4[2 * r + 1] : v4[2 * r];
            float z = (j & 8) ? w2v[1] : w2v[0];
            int m = (j & 3) + ((j >> 2) << 3) + (half << 2);
            int po = p32 + m;
            if (po < p) out[po] = 1.0f / (1.0f + expf(-(z + bf2r)));
        }
    }
}

extern "C" void kernel_launch(void* const* d_in, const int* in_sizes, int n_in,
                              void* d_out, int out_size, void* d_ws, size_t ws_size,
                              hipStream_t stream) {
    const int*   edge_index = (const int*)d_in[0];
    const int*   edge_pairs = (const int*)d_in[1];
    const float* pf         = (const float*)d_in[2];
    const float* emb        = (const float*)d_in[3];
    const float* W1         = (const float*)d_in[4];
    const float* b1         = (const float*)d_in[5];
    const float* W2         = (const float*)d_in[6];
    const float* b2         = (const float*)d_in[7];
    const float* Wf1        = (const float*)d_in[8];
    const float* bf1        = (const float*)d_in[9];
    const float* Wf2        = (const float*)d_in[10];
    const float* bf2        = (const float*)d_in[11];
    float*       out        = (float*)d_out;

    const int E = in_sizes[0] / 2;
    const int P = in_sizes[1] / 2;
    const int N = in_sizes[3] / EMB;
    const int NBUCK = (N + (1 << BSH) - 1) >> BSH;   // 196 for N=100k (<=NBMAX)

    char* ws = (char*)d_ws;
    size_t off = 0;
    float*          dinv    = (float*)(ws + off);          off += ((size_t)N * 4 + 255) & ~255ULL;
    __hip_bfloat16* hbs1    = (__hip_bfloat16*)(ws + off); off += ((size_t)N * HID * 2 + 255) & ~255ULL;
    __hip_bfloat16* hbs2    = (__hip_bfloat16*)(ws + off); off += ((size_t)N * HID * 2 + 255) & ~255ULL;
    __hip_bfloat16* xb      = (__hip_bfloat16*)(ws + off); off += ((size_t)N * HID * 2 + 255) & ~255ULL;
    __hip_bfloat16* wfrag   = (__hip_bfloat16*)(ws + off); off += ((size_t)10 * 512 * 2 + 255) & ~255ULL;
    int*            row_ptr = (int*)(ws + off);            off += ((size_t)N * 4 + 255) & ~255ULL;
    int*            rend    = (int*)(ws + off);            off += ((size_t)N * 4 + 255) & ~255ULL;
    int*            btot    = (int*)(ws + off);            off += ((size_t)NBMAX * 4 + 255) & ~255ULL;
    int*            bbase   = (int*)(ws + off);            off += ((size_t)(NBMAX + 1) * 4 + 255) & ~255ULL;
    int*            bcur    = (int*)(ws + off);            off += ((size_t)NBMAX * 4 + 255) & ~255ULL;
    int*            csr_src = (int*)(ws + off);            off += ((size_t)E * 4 + 255) & ~255ULL;
    int2*           pairs2  = (int2*)(ws + off);           off += ((size_t)E * 8 + 255) & ~255ULL;
    (void)ws_size;

    const int EBLK = (E + CHUNK - 1) / CHUNK;

    // ---- CSR build (bucket hist -> scan -> partition -> bucket scatter) ----
    hipMemsetAsync(btot, 0, (size_t)NBMAX * 4, stream);
    bucket_hist_kernel<<<EBLK, 256, 0, stream>>>(edge_index + E, btot, E);
    prep_wf1_kernel<<<20, 256, 0, stream>>>(Wf1, wfrag);
    scan_buckets_kernel<<<1, 256, 0, stream>>>(btot, bbase, bcur, NBUCK, E);
    partition_kernel<<<EBLK, 256, 0, stream>>>(edge_index, bcur, pairs2, E);
    bucket_scatter_kernel<<<NBUCK, 256, 0, stream>>>(bbase, pairs2, csr_src,
                                                     row_ptr, rend, dinv, N);

    // ---- layer 1: h1*dinv (bf16) ----
    mm1_kernel<<<(N + 3) / 4, 256, 0, stream>>>(emb, W1, dinv, hbs1, N);

    // ---- fused gather(L1) + mm2 -> hbs2 ----
    gather_mm2_kernel<<<(N + 3) / 4, 256, 0, stream>>>(row_ptr, rend, csr_src, dinv,
                                                       hbs1, W2, b1, hbs2, N);

    // ---- gather(L2) -> xb (b2 folded) ----
    gather_out_kernel<<<(N + 3) / 4, 256, 0, stream>>>(row_ptr, rend, csr_src, dinv,
                                                       hbs2, b2, xb, N);

    // ---- pair MLP head (MFMA) ----
    final_mfma_kernel<<<2048, 256, 0, stream>>>(edge_pairs, pf, xb, wfrag,
                                                bf1, Wf2, bf2, out, P);
}

// Round 12
// 423.569 us; speedup vs baseline: 6.7495x; 1.1384x over previous
//
#include <hip/hip_runtime.h>
#include <hip/hip_bf16.h>
#include <math.h>

#define EMB 32
#define HID 64
#define PAT 8

#define BSH   9                 // nodes per bucket = 512
#define NBMAX 256               // max buckets supported (N <= 131072; src fits 17 bits)
#define CHUNK 4096              // edges per partition block

typedef __attribute__((ext_vector_type(8))) short short8v;   // 8 bf16 = 4 VGPRs
typedef __attribute__((ext_vector_type(16))) float f32x16;   // MFMA 32x32 accumulator

union Frag {
    short8v s8;
    uint4 u4;
    __hip_bfloat162 h2[4];
    __hip_bfloat16 h[8];
    unsigned short us[8];
};

// ---------------- pass 0: per-block LDS bucket histogram ----------------
__global__ __launch_bounds__(256) void bucket_hist_kernel(
    const int* __restrict__ dst, int* __restrict__ btot, int e) {
    __shared__ int cnt[NBMAX];
    int t = threadIdx.x;
    for (int k = t; k < NBMAX; k += 256) cnt[k] = 0;
    __syncthreads();
    int e0 = blockIdx.x * CHUNK;
    int ec = min(CHUNK, e - e0);
    for (int k = t; k < ec; k += 256)
        atomicAdd(&cnt[dst[e0 + k] >> BSH], 1);
    __syncthreads();
    for (int k = t; k < NBMAX; k += 256)
        if (cnt[k]) atomicAdd(&btot[k], cnt[k]);
}

// one block: exclusive scan of bucket totals -> bbase (197 entries), bcur
__global__ void scan_buckets_kernel(const int* __restrict__ btot, int* __restrict__ bbase,
                                    int* __restrict__ bcur, int nbuck, int e) {
    __shared__ int s[256];
    int t = threadIdx.x;
    int v = (t < nbuck) ? btot[t] : 0;
    s[t] = v;
    __syncthreads();
    for (int off = 1; off < 256; off <<= 1) {
        int u = (t >= off) ? s[t - off] : 0;
        __syncthreads();
        s[t] += u;
        __syncthreads();
    }
    if (t < nbuck) {
        int ex = s[t] - v;
        bbase[t] = ex;
        bcur[t]  = ex;
    }
    if (t == 0) bbase[nbuck] = e;
}

// ---------------- pass A: LDS-staged partition; output packed (dlocal<<17 | src) ----------------
__global__ __launch_bounds__(256) void partition_kernel(
    const int* __restrict__ ei, int* __restrict__ bcur,
    unsigned* __restrict__ pairs, int e) {
    __shared__ int cnt[NBMAX];
    __shared__ int scn[NBMAX];
    __shared__ int loff[NBMAX];
    __shared__ int base[NBMAX];
    __shared__ int2 stg[CHUNK];
    int t = threadIdx.x;
    int e0 = blockIdx.x * CHUNK;
    int ecnt = min(CHUNK, e - e0);

    for (int k = t; k < NBMAX; k += 256) cnt[k] = 0;
    __syncthreads();
    for (int k = t; k < ecnt; k += 256)
        atomicAdd(&cnt[ei[e + e0 + k] >> BSH], 1);
    __syncthreads();
    int c = cnt[t];
    scn[t] = c;
    __syncthreads();
    for (int off = 1; off < 256; off <<= 1) {
        int u = (t >= off) ? scn[t - off] : 0;
        __syncthreads();
        scn[t] += u;
        __syncthreads();
    }
    int ex = scn[t] - c;
    __syncthreads();
    scn[t] = ex;
    loff[t] = ex;
    base[t] = c ? atomicAdd(&bcur[t], c) : 0;
    __syncthreads();
    for (int k = t; k < ecnt; k += 256) {
        int s = ei[e0 + k];
        int d = ei[e + e0 + k];
        int pos = atomicAdd(&loff[d >> BSH], 1);
        stg[pos] = make_int2(s, d);
    }
    __syncthreads();
    for (int k = t; k < ecnt; k += 256) {
        int2 pr = stg[k];
        int b = pr.y >> BSH;
        unsigned pk = ((unsigned)(pr.y & ((1 << BSH) - 1)) << 17) | (unsigned)pr.x;
        pairs[base[b] + (k - scn[b])] = pk;
    }
}

// ---------------- pass B: per-bucket count+scan+scatter; emits row_ptr/rend/dinv/csr_src ----------------
__global__ __launch_bounds__(256) void bucket_scatter_kernel(
    const int* __restrict__ bbase, const unsigned* __restrict__ pairs,
    int* __restrict__ csr_src, int* __restrict__ row_ptr, int* __restrict__ rend,
    float* __restrict__ dinv, int n) {
    __shared__ int cnt[1 << BSH];
    __shared__ int scn[256];
    __shared__ int cur[1 << BSH];
    int b = blockIdx.x;
    int n0 = b << BSH;
    int nn = min(1 << BSH, n - n0);
    int t = threadIdx.x;
    cnt[t] = 0; cnt[t + 256] = 0;
    __syncthreads();
    int p0 = bbase[b], p1 = bbase[b + 1];
    for (int k = p0 + t; k < p1; k += 256)
        atomicAdd(&cnt[pairs[k] >> 17], 1);
    __syncthreads();
    int ca = cnt[2 * t], cb = cnt[2 * t + 1];
    int c2 = ca + cb;
    scn[t] = c2;
    __syncthreads();
    for (int off = 1; off < 256; off <<= 1) {
        int u = (t >= off) ? scn[t - off] : 0;
        __syncthreads();
        scn[t] += u;
        __syncthreads();
    }
    int ex2 = scn[t] - c2;
    int ea = p0 + ex2;
    int eb = ea + ca;
    if (2 * t < nn) {
        row_ptr[n0 + 2 * t] = ea;
        rend[n0 + 2 * t]    = ea + ca;
        dinv[n0 + 2 * t]    = rsqrtf(1.0f + (float)ca);
        cur[2 * t] = ea;
    }
    if (2 * t + 1 < nn) {
        row_ptr[n0 + 2 * t + 1] = eb;
        rend[n0 + 2 * t + 1]    = eb + cb;
        dinv[n0 + 2 * t + 1]    = rsqrtf(1.0f + (float)cb);
        cur[2 * t + 1] = eb;
    }
    __syncthreads();
    for (int k = p0 + t; k < p1; k += 256) {
        unsigned v = pairs[k];
        int pos = atomicAdd(&cur[v >> 17], 1);
        csr_src[pos] = (int)(v & 0x1FFFFu);
    }
}

// ---------------- pack Wf1 into MFMA B-fragment order (bf16) ----------------
__global__ void prep_wf1_kernel(const float* __restrict__ Wf1, __hip_bfloat16* __restrict__ wfrag) {
    int gid = blockIdx.x * blockDim.x + threadIdx.x;
    if (gid >= 10 * 512) return;
    int f = gid >> 9;
    int rem = gid & 511;
    int l = rem >> 3;
    int e = rem & 7;
    int c = f >> 1;
    int t = f & 1;
    int k = c * 16 + ((l >> 5) << 3) + e;
    int n = (l & 31) + (t << 5);
    float v = (k < HID + PAT) ? Wf1[k * 64 + n] : 0.0f;
    wfrag[gid] = __float2bfloat16(v);
}

// ---------------- pack W2 into MFMA B-fragment order (bf16): 8 frags (4 k-chunks x 2 n-tiles) ----------------
__global__ void prep_w2_kernel(const float* __restrict__ W2, __hip_bfloat16* __restrict__ w2frag) {
    int gid = blockIdx.x * blockDim.x + threadIdx.x;
    if (gid >= 8 * 512) return;
    int f = gid >> 9;
    int rem = gid & 511;
    int l = rem >> 3;
    int e = rem & 7;
    int c = f >> 1;
    int t = f & 1;
    int k = c * 16 + ((l >> 5) << 3) + e;
    int n = (l & 31) + (t << 5);
    w2frag[gid] = __float2bfloat16(W2[k * 64 + n]);
}

// ---------------- layer-1 matmul: hbs1 = bf16((emb @ W1) * dinv) ----------------
__global__ __launch_bounds__(256) void mm1_kernel(
    const float* __restrict__ emb, const float* __restrict__ W1,
    const float* __restrict__ dinv,
    __hip_bfloat16* __restrict__ hbs, int n) {
    __shared__ float w[EMB * HID];  // 8 KB
    int t = threadIdx.x;
    for (int k = t; k < EMB * HID; k += 256) w[k] = W1[k];
    __syncthreads();
    int wave = t >> 6, lane = t & 63;
    int i = blockIdx.x * 4 + wave;
    if (i >= n) return;
    float e = (lane < EMB) ? emb[i * EMB + lane] : 0.0f;
    float acc = 0.0f;
#pragma unroll
    for (int k = 0; k < EMB; ++k) {
        float ek = __shfl(e, k, 64);
        acc += ek * w[k * HID + lane];
    }
    hbs[(size_t)i * HID + lane] = __float2bfloat16(acc * dinv[i]);
}

// ---------------- fused gather(L1) + MFMA mm2: 32 rows/block ----------------
// gather phase: 4 waves x 8 rows -> x1 = relu(dv*sum+b1) into LDS (bf16, XOR-swizzled 16B blocks)
// mm2 phase: waves 0,1 each compute one 32-col n-tile via 4x mfma_32x32x16; scale by dinv, store.
__global__ __launch_bounds__(256) void gather_mm2_kernel(
    const int* __restrict__ row_ptr, const int* __restrict__ rend,
    const int* __restrict__ csr_src, const float* __restrict__ dinv,
    const __hip_bfloat16* __restrict__ hbs1, const __hip_bfloat16* __restrict__ w2frag,
    const float* __restrict__ b1, __hip_bfloat16* __restrict__ hbs2, int n) {
    __shared__ __attribute__((aligned(16))) unsigned short x1s[32 * 64];  // 4 KB
    int t = threadIdx.x;
    int lane = t & 63;
    int wv = t >> 6;
    int n0 = blockIdx.x << 5;
    float b1v = b1[lane];

    for (int rr = 0; rr < 8; ++rr) {
        int row = wv * 8 + rr;
        int i = n0 + row;
        float x = 0.0f;
        if (i < n) {
            int e = row_ptr[i], end = rend[i];
            float sum = __bfloat162float(hbs1[(size_t)i * HID + lane]);  // self-loop
            for (; e + 8 <= end; e += 8) {
                int s0 = csr_src[e],     s1 = csr_src[e + 1], s2 = csr_src[e + 2], s3 = csr_src[e + 3];
                int s4 = csr_src[e + 4], s5 = csr_src[e + 5], s6 = csr_src[e + 6], s7 = csr_src[e + 7];
                float h0 = __bfloat162float(hbs1[(size_t)s0 * HID + lane]);
                float h1 = __bfloat162float(hbs1[(size_t)s1 * HID + lane]);
                float h2 = __bfloat162float(hbs1[(size_t)s2 * HID + lane]);
                float h3 = __bfloat162float(hbs1[(size_t)s3 * HID + lane]);
                float h4 = __bfloat162float(hbs1[(size_t)s4 * HID + lane]);
                float h5 = __bfloat162float(hbs1[(size_t)s5 * HID + lane]);
                float h6 = __bfloat162float(hbs1[(size_t)s6 * HID + lane]);
                float h7 = __bfloat162float(hbs1[(size_t)s7 * HID + lane]);
                sum += ((h0 + h1) + (h2 + h3)) + ((h4 + h5) + (h6 + h7));
            }
            for (; e < end; ++e)
                sum += __bfloat162float(hbs1[(size_t)csr_src[e] * HID + lane]);
            x = fmaxf(fmaf(dinv[i], sum, b1v), 0.0f);
        }
        __hip_bfloat16 hv = __float2bfloat16(x);
        // swizzle: 16B block index (lane>>3) XOR (row&7)
        x1s[row * 64 + ((((lane >> 3) ^ (row & 7)) << 3) | (lane & 7))] =
            *reinterpret_cast<unsigned short*>(&hv);
    }
    __syncthreads();

    if (wv < 2) {   // wv = n-tile index
        int half = lane >> 5;
        int lp   = lane & 31;
        const uint4* wf = (const uint4*)w2frag;
        f32x16 acc;
#pragma unroll
        for (int r = 0; r < 16; ++r) acc[r] = 0.0f;
#pragma unroll
        for (int c = 0; c < 4; ++c) {
            Frag fa, fb;
            int blk = (c * 2 + half) ^ (lp & 7);
            fa.u4 = *(const uint4*)&x1s[lp * 64 + (blk << 3)];
            fb.u4 = wf[(c * 2 + wv) * 64 + lane];
            acc = __builtin_amdgcn_mfma_f32_32x32x16_bf16(fa.s8, fb.s8, acc, 0, 0, 0);
        }
#pragma unroll
        for (int r = 0; r < 16; ++r) {
            int m = (r & 3) + 8 * (r >> 2) + 4 * half;
            int i = n0 + m;
            if (i < n)
                hbs2[(size_t)i * HID + lp + 32 * wv] = __float2bfloat16(acc[r] * dinv[i]);
        }
    }
}

// ---------------- gather(layer2): xb = bf16(dv*sum + b2) ----------------
__global__ __launch_bounds__(256) void gather_out_kernel(
    const int* __restrict__ row_ptr, const int* __restrict__ rend,
    const int* __restrict__ csr_src, const float* __restrict__ dinv,
    const __hip_bfloat16* __restrict__ hbs2, const float* __restrict__ b2,
    __hip_bfloat16* __restrict__ xb, int n) {
    int t = threadIdx.x;
    int lane = t & 63;
    int i = blockIdx.x * 4 + (t >> 6);
    if (i >= n) return;
    int e   = row_ptr[i];
    int end = rend[i];
    float sum = __bfloat162float(hbs2[(size_t)i * HID + lane]);  // self-loop
    for (; e + 8 <= end; e += 8) {
        int s0 = csr_src[e],     s1 = csr_src[e + 1], s2 = csr_src[e + 2], s3 = csr_src[e + 3];
        int s4 = csr_src[e + 4], s5 = csr_src[e + 5], s6 = csr_src[e + 6], s7 = csr_src[e + 7];
        float h0 = __bfloat162float(hbs2[(size_t)s0 * HID + lane]);
        float h1 = __bfloat162float(hbs2[(size_t)s1 * HID + lane]);
        float h2 = __bfloat162float(hbs2[(size_t)s2 * HID + lane]);
        float h3 = __bfloat162float(hbs2[(size_t)s3 * HID + lane]);
        float h4 = __bfloat162float(hbs2[(size_t)s4 * HID + lane]);
        float h5 = __bfloat162float(hbs2[(size_t)s5 * HID + lane]);
        float h6 = __bfloat162float(hbs2[(size_t)s6 * HID + lane]);
        float h7 = __bfloat162float(hbs2[(size_t)s7 * HID + lane]);
        sum += ((h0 + h1) + (h2 + h3)) + ((h4 + h5) + (h6 + h7));
    }
    for (; e < end; ++e)
        sum += __bfloat162float(hbs2[(size_t)csr_src[e] * HID + lane]);
    xb[(size_t)i * HID + lane] = __float2bfloat16(fmaf(dinv[i], sum, b2[lane]));
}

// ---------------- pair MLP head via MFMA (C/D layout HW-verified) ----------------
__global__ __launch_bounds__(256) void final_mfma_kernel(
    const int* __restrict__ pairs, const float* __restrict__ pf,
    const __hip_bfloat16* __restrict__ xb, const __hip_bfloat16* __restrict__ wfrag,
    const float* __restrict__ bf1, const float* __restrict__ Wf2,
    const float* __restrict__ bf2, float* __restrict__ out, int p) {
    int lane = threadIdx.x & 63;
    int wid  = threadIdx.x >> 6;
    int half = lane >> 5;
    int lp   = lane & 31;

    float bf1a = bf1[lp];
    float bf1b = bf1[32 + lp];
    float w2a  = Wf2[lp];
    float w2b  = Wf2[32 + lp];
    float bf2r = bf2[0];

    const uint4* wf = (const uint4*)wfrag;

    int ngroups = (p + 31) >> 5;
    int nw = gridDim.x * 4;
    for (int g = blockIdx.x * 4 + wid; g < ngroups; g += nw) {
        int p32 = g << 5;
        int pi = p32 + lp; if (pi >= p) pi = p - 1;
        int2 pr = ((const int2*)pairs)[pi];
        const uint4* drow = (const uint4*)(xb + (size_t)pr.x * HID);
        const uint4* arow = (const uint4*)(xb + (size_t)pr.y * HID);

        f32x16 acc0, acc1;
#pragma unroll
        for (int r = 0; r < 16; ++r) { acc0[r] = 0.0f; acc1[r] = 0.0f; }

#pragma unroll
        for (int c = 0; c < 4; ++c) {
            Frag fd, fx, fa, fb0, fb1;
            fd.u4 = drow[c * 2 + half];
            fx.u4 = arow[c * 2 + half];
#pragma unroll
            for (int q = 0; q < 4; ++q) fa.h2[q] = __hmul2(fd.h2[q], fx.h2[q]);
            fb0.u4 = wf[(c * 2 + 0) * 64 + lane];
            fb1.u4 = wf[(c * 2 + 1) * 64 + lane];
            acc0 = __builtin_amdgcn_mfma_f32_32x32x16_bf16(fa.s8, fb0.s8, acc0, 0, 0, 0);
            acc1 = __builtin_amdgcn_mfma_f32_32x32x16_bf16(fa.s8, fb1.s8, acc1, 0, 0, 0);
        }
        {   // chunk 4: patient features (k=64..71 real, 72..79 zero-pad)
            Frag fa, fb0, fb1;
            if (half == 0) {
                float4 lo = ((const float4*)pf)[pi * 2];
                float4 hi = ((const float4*)pf)[pi * 2 + 1];
                fa.h[0] = __float2bfloat16(lo.x); fa.h[1] = __float2bfloat16(lo.y);
                fa.h[2] = __float2bfloat16(lo.z); fa.h[3] = __float2bfloat16(lo.w);
                fa.h[4] = __float2bfloat16(hi.x); fa.h[5] = __float2bfloat16(hi.y);
                fa.h[6] = __float2bfloat16(hi.z); fa.h[7] = __float2bfloat16(hi.w);
            } else {
#pragma unroll
                for (int e = 0; e < 8; ++e) fa.us[e] = 0;
            }
            fb0.u4 = wf[8 * 64 + lane];
            fb1.u4 = wf[9 * 64 + lane];
            acc0 = __builtin_amdgcn_mfma_f32_32x32x16_bf16(fa.s8, fb0.s8, acc0, 0, 0, 0);
            acc1 = __builtin_amdgcn_mfma_f32_32x32x16_bf16(fa.s8, fb1.s8, acc1, 0, 0, 0);
        }

        float t[16];
#pragma unroll
        for (int r = 0; r < 16; ++r)
            t[r] = fmaxf(acc0[r] + bf1a, 0.0f) * w2a + fmaxf(acc1[r] + bf1b, 0.0f) * w2b;

#pragma unroll
        for (int off = 1; off < 32; off <<= 1) {
#pragma unroll
            for (int r = 0; r < 16; ++r) t[r] += __shfl_xor(t[r], off, 64);
        }

        if (lp < 16) {
            int j = lp;
            float u[8];
#pragma unroll
            for (int r = 0; r < 8; ++r) u[r] = (j & 1) ? t[2 * r + 1] : t[2 * r];
            float v4[4];
#pragma unroll
            for (int r = 0; r < 4; ++r) v4[r] = (j & 2) ? u[2 * r + 1] : u[2 * r];
            float w2v[2];
#pragma unroll
            for (int r = 0; r < 2; ++r) w2v[r] = (j & 4) ? v4[2 * r + 1] : v4[2 * r];
            float z = (j & 8) ? w2v[1] : w2v[0];
            int m = (j & 3) + ((j >> 2) << 3) + (half << 2);
            int po = p32 + m;
            if (po < p) out[po] = 1.0f / (1.0f + expf(-(z + bf2r)));
        }
    }
}

extern "C" void kernel_launch(void* const* d_in, const int* in_sizes, int n_in,
                              void* d_out, int out_size, void* d_ws, size_t ws_size,
                              hipStream_t stream) {
    const int*   edge_index = (const int*)d_in[0];
    const int*   edge_pairs = (const int*)d_in[1];
    const float* pf         = (const float*)d_in[2];
    const float* emb        = (const float*)d_in[3];
    const float* W1         = (const float*)d_in[4];
    const float* b1         = (const float*)d_in[5];
    const float* W2         = (const float*)d_in[6];
    const float* b2         = (const float*)d_in[7];
    const float* Wf1        = (const float*)d_in[8];
    const float* bf1        = (const float*)d_in[9];
    const float* Wf2        = (const float*)d_in[10];
    const float* bf2        = (const float*)d_in[11];
    float*       out        = (float*)d_out;

    const int E = in_sizes[0] / 2;
    const int P = in_sizes[1] / 2;
    const int N = in_sizes[3] / EMB;
    const int NBUCK = (N + (1 << BSH) - 1) >> BSH;   // 196 for N=100k (<=NBMAX)

    char* ws = (char*)d_ws;
    size_t off = 0;
    float*          dinv    = (float*)(ws + off);          off += ((size_t)N * 4 + 255) & ~255ULL;
    __hip_bfloat16* hbs1    = (__hip_bfloat16*)(ws + off); off += ((size_t)N * HID * 2 + 255) & ~255ULL;
    __hip_bfloat16* hbs2    = (__hip_bfloat16*)(ws + off); off += ((size_t)N * HID * 2 + 255) & ~255ULL;
    __hip_bfloat16* xb      = (__hip_bfloat16*)(ws + off); off += ((size_t)N * HID * 2 + 255) & ~255ULL;
    __hip_bfloat16* wfrag   = (__hip_bfloat16*)(ws + off); off += ((size_t)10 * 512 * 2 + 255) & ~255ULL;
    __hip_bfloat16* w2frag  = (__hip_bfloat16*)(ws + off); off += ((size_t)8 * 512 * 2 + 255) & ~255ULL;
    int*            row_ptr = (int*)(ws + off);            off += ((size_t)N * 4 + 255) & ~255ULL;
    int*            rend    = (int*)(ws + off);            off += ((size_t)N * 4 + 255) & ~255ULL;
    int*            btot    = (int*)(ws + off);            off += ((size_t)NBMAX * 4 + 255) & ~255ULL;
    int*            bbase   = (int*)(ws + off);            off += ((size_t)(NBMAX + 1) * 4 + 255) & ~255ULL;
    int*            bcur    = (int*)(ws + off);            off += ((size_t)NBMAX * 4 + 255) & ~255ULL;
    int*            csr_src = (int*)(ws + off);            off += ((size_t)E * 4 + 255) & ~255ULL;
    unsigned*       pairs2  = (unsigned*)(ws + off);       off += ((size_t)E * 4 + 255) & ~255ULL;
    (void)ws_size;

    const int EBLK = (E + CHUNK - 1) / CHUNK;

    // ---- CSR build (bucket hist -> scan -> partition -> bucket scatter) ----
    hipMemsetAsync(btot, 0, (size_t)NBMAX * 4, stream);
    bucket_hist_kernel<<<EBLK, 256, 0, stream>>>(edge_index + E, btot, E);
    prep_wf1_kernel<<<20, 256, 0, stream>>>(Wf1, wfrag);
    prep_w2_kernel<<<16, 256, 0, stream>>>(W2, w2frag);
    scan_buckets_kernel<<<1, 256, 0, stream>>>(btot, bbase, bcur, NBUCK, E);
    partition_kernel<<<EBLK, 256, 0, stream>>>(edge_index, bcur, pairs2, E);
    bucket_scatter_kernel<<<NBUCK, 256, 0, stream>>>(bbase, pairs2, csr_src,
                                                     row_ptr, rend, dinv, N);

    // ---- layer 1: h1*dinv (bf16) ----
    mm1_kernel<<<(N + 3) / 4, 256, 0, stream>>>(emb, W1, dinv, hbs1, N);

    // ---- fused gather(L1) + MFMA mm2 -> hbs2 ----
    gather_mm2_kernel<<<(N + 31) / 32, 256, 0, stream>>>(row_ptr, rend, csr_src, dinv,
                                                         hbs1, w2frag, b1, hbs2, N);

    // ---- gather(L2) -> xb (b2 folded) ----
    gather_out_kernel<<<(N + 3) / 4, 256, 0, stream>>>(row_ptr, rend, csr_src, dinv,
                                                       hbs2, b2, xb, N);

    // ---- pair MLP head (MFMA) ----
    final_mfma_kernel<<<2048, 256, 0, stream>>>(edge_pairs, pf, xb, wfrag,
                                                bf1, Wf2, bf2, out, P);
}

// Round 13
// 383.940 us; speedup vs baseline: 7.4461x; 1.1032x over previous
//
#include <hip/hip_runtime.h>
#include <hip/hip_bf16.h>
#include <math.h>

#define EMB 32
#define HID 64
#define PAT 8

#define BSH   9                 // nodes per bucket = 512
#define NBMAX 256               // max buckets supported (N <= 131072; src fits 17 bits)
#define CHUNK 4096              // edges per partition block

typedef __attribute__((ext_vector_type(8))) short short8v;   // 8 bf16 = 4 VGPRs
typedef __attribute__((ext_vector_type(16))) float f32x16;   // MFMA 32x32 accumulator

union Frag {
    short8v s8;
    uint4 u4;
    __hip_bfloat162 h2[4];
    __hip_bfloat16 h[8];
    unsigned short us[8];
};

__device__ __forceinline__ float bf_lo(unsigned v) { return __uint_as_float(v << 16); }
__device__ __forceinline__ float bf_hi(unsigned v) { return __uint_as_float(v & 0xFFFF0000u); }
__device__ __forceinline__ unsigned pack_bf2(float a, float b) {
    __hip_bfloat16 ba = __float2bfloat16(a), bb = __float2bfloat16(b);
    return ((unsigned)*(unsigned short*)&bb << 16) | *(unsigned short*)&ba;
}

// ---------------- pass 0: per-block LDS bucket histogram ----------------
__global__ __launch_bounds__(256) void bucket_hist_kernel(
    const int* __restrict__ dst, int* __restrict__ btot, int e) {
    __shared__ int cnt[NBMAX];
    int t = threadIdx.x;
    for (int k = t; k < NBMAX; k += 256) cnt[k] = 0;
    __syncthreads();
    int e0 = blockIdx.x * CHUNK;
    int ec = min(CHUNK, e - e0);
    for (int k = t; k < ec; k += 256)
        atomicAdd(&cnt[dst[e0 + k] >> BSH], 1);
    __syncthreads();
    for (int k = t; k < NBMAX; k += 256)
        if (cnt[k]) atomicAdd(&btot[k], cnt[k]);
}

// one block: exclusive scan of bucket totals -> bbase (197 entries), bcur
__global__ void scan_buckets_kernel(const int* __restrict__ btot, int* __restrict__ bbase,
                                    int* __restrict__ bcur, int nbuck, int e) {
    __shared__ int s[256];
    int t = threadIdx.x;
    int v = (t < nbuck) ? btot[t] : 0;
    s[t] = v;
    __syncthreads();
    for (int off = 1; off < 256; off <<= 1) {
        int u = (t >= off) ? s[t - off] : 0;
        __syncthreads();
        s[t] += u;
        __syncthreads();
    }
    if (t < nbuck) {
        int ex = s[t] - v;
        bbase[t] = ex;
        bcur[t]  = ex;
    }
    if (t == 0) bbase[nbuck] = e;
}

// ---------------- pass A: LDS-staged partition; output packed (dlocal<<17 | src) ----------------
__global__ __launch_bounds__(256) void partition_kernel(
    const int* __restrict__ ei, int* __restrict__ bcur,
    unsigned* __restrict__ pairs, int e) {
    __shared__ int cnt[NBMAX];
    __shared__ int scn[NBMAX];
    __shared__ int loff[NBMAX];
    __shared__ int base[NBMAX];
    __shared__ int2 stg[CHUNK];
    int t = threadIdx.x;
    int e0 = blockIdx.x * CHUNK;
    int ecnt = min(CHUNK, e - e0);

    for (int k = t; k < NBMAX; k += 256) cnt[k] = 0;
    __syncthreads();
    for (int k = t; k < ecnt; k += 256)
        atomicAdd(&cnt[ei[e + e0 + k] >> BSH], 1);
    __syncthreads();
    int c = cnt[t];
    scn[t] = c;
    __syncthreads();
    for (int off = 1; off < 256; off <<= 1) {
        int u = (t >= off) ? scn[t - off] : 0;
        __syncthreads();
        scn[t] += u;
        __syncthreads();
    }
    int ex = scn[t] - c;
    __syncthreads();
    scn[t] = ex;
    loff[t] = ex;
    base[t] = c ? atomicAdd(&bcur[t], c) : 0;
    __syncthreads();
    for (int k = t; k < ecnt; k += 256) {
        int s = ei[e0 + k];
        int d = ei[e + e0 + k];
        int pos = atomicAdd(&loff[d >> BSH], 1);
        stg[pos] = make_int2(s, d);
    }
    __syncthreads();
    for (int k = t; k < ecnt; k += 256) {
        int2 pr = stg[k];
        int b = pr.y >> BSH;
        unsigned pk = ((unsigned)(pr.y & ((1 << BSH) - 1)) << 17) | (unsigned)pr.x;
        pairs[base[b] + (k - scn[b])] = pk;
    }
}

// ---------------- pass B: per-bucket count+scan+scatter; emits row_ptr/rend/dinv/csr_src ----------------
__global__ __launch_bounds__(256) void bucket_scatter_kernel(
    const int* __restrict__ bbase, const unsigned* __restrict__ pairs,
    int* __restrict__ csr_src, int* __restrict__ row_ptr, int* __restrict__ rend,
    float* __restrict__ dinv, int n) {
    __shared__ int cnt[1 << BSH];
    __shared__ int scn[256];
    __shared__ int cur[1 << BSH];
    int b = blockIdx.x;
    int n0 = b << BSH;
    int nn = min(1 << BSH, n - n0);
    int t = threadIdx.x;
    cnt[t] = 0; cnt[t + 256] = 0;
    __syncthreads();
    int p0 = bbase[b], p1 = bbase[b + 1];
    for (int k = p0 + t; k < p1; k += 256)
        atomicAdd(&cnt[pairs[k] >> 17], 1);
    __syncthreads();
    int ca = cnt[2 * t], cb = cnt[2 * t + 1];
    int c2 = ca + cb;
    scn[t] = c2;
    __syncthreads();
    for (int off = 1; off < 256; off <<= 1) {
        int u = (t >= off) ? scn[t - off] : 0;
        __syncthreads();
        scn[t] += u;
        __syncthreads();
    }
    int ex2 = scn[t] - c2;
    int ea = p0 + ex2;
    int eb = ea + ca;
    if (2 * t < nn) {
        row_ptr[n0 + 2 * t] = ea;
        rend[n0 + 2 * t]    = ea + ca;
        dinv[n0 + 2 * t]    = rsqrtf(1.0f + (float)ca);
        cur[2 * t] = ea;
    }
    if (2 * t + 1 < nn) {
        row_ptr[n0 + 2 * t + 1] = eb;
        rend[n0 + 2 * t + 1]    = eb + cb;
        dinv[n0 + 2 * t + 1]    = rsqrtf(1.0f + (float)cb);
        cur[2 * t + 1] = eb;
    }
    __syncthreads();
    for (int k = p0 + t; k < p1; k += 256) {
        unsigned v = pairs[k];
        int pos = atomicAdd(&cur[v >> 17], 1);
        csr_src[pos] = (int)(v & 0x1FFFFu);
    }
}

// ---------------- pack Wf1 into MFMA B-fragment order (bf16) ----------------
__global__ void prep_wf1_kernel(const float* __restrict__ Wf1, __hip_bfloat16* __restrict__ wfrag) {
    int gid = blockIdx.x * blockDim.x + threadIdx.x;
    if (gid >= 10 * 512) return;
    int f = gid >> 9;
    int rem = gid & 511;
    int l = rem >> 3;
    int e = rem & 7;
    int c = f >> 1;
    int t = f & 1;
    int k = c * 16 + ((l >> 5) << 3) + e;
    int n = (l & 31) + (t << 5);
    float v = (k < HID + PAT) ? Wf1[k * 64 + n] : 0.0f;
    wfrag[gid] = __float2bfloat16(v);
}

// ---------------- pack W2 into MFMA B-fragment order (bf16): 8 frags ----------------
__global__ void prep_w2_kernel(const float* __restrict__ W2, __hip_bfloat16* __restrict__ w2frag) {
    int gid = blockIdx.x * blockDim.x + threadIdx.x;
    if (gid >= 8 * 512) return;
    int f = gid >> 9;
    int rem = gid & 511;
    int l = rem >> 3;
    int e = rem & 7;
    int c = f >> 1;
    int t = f & 1;
    int k = c * 16 + ((l >> 5) << 3) + e;
    int n = (l & 31) + (t << 5);
    w2frag[gid] = __float2bfloat16(W2[k * 64 + n]);
}

// ---------------- layer-1 matmul: hbs1 = bf16((emb @ W1) * dinv) ----------------
__global__ __launch_bounds__(256) void mm1_kernel(
    const float* __restrict__ emb, const float* __restrict__ W1,
    const float* __restrict__ dinv,
    __hip_bfloat16* __restrict__ hbs, int n) {
    __shared__ float w[EMB * HID];  // 8 KB
    int t = threadIdx.x;
    for (int k = t; k < EMB * HID; k += 256) w[k] = W1[k];
    __syncthreads();
    int wave = t >> 6, lane = t & 63;
    int i = blockIdx.x * 4 + wave;
    if (i >= n) return;
    float e = (lane < EMB) ? emb[i * EMB + lane] : 0.0f;
    float acc = 0.0f;
#pragma unroll
    for (int k = 0; k < EMB; ++k) {
        float ek = __shfl(e, k, 64);
        acc += ek * w[k * HID + lane];
    }
    hbs[(size_t)i * HID + lane] = __float2bfloat16(acc * dinv[i]);
}

// ======== 2-edges-per-instruction gather core ========
// lane l: columns 2*(l&31), 2*(l&31)+1; lanes<32 even edges, lanes>=32 odd edges.
// Returns combined (s0,s1) INCLUDING self-loop row i.
__device__ __forceinline__ float2 gather_row2(
    const int* __restrict__ csr_src, const __hip_bfloat16* __restrict__ hb,
    int i, int e, int end, int halfe, int lp2) {
    float s0 = 0.0f, s1 = 0.0f;
    int k = e + halfe;
    for (; k + 14 < end; k += 16) {
        int a0 = csr_src[k],      a1 = csr_src[k + 2],  a2 = csr_src[k + 4],  a3 = csr_src[k + 6];
        int a4 = csr_src[k + 8],  a5 = csr_src[k + 10], a6 = csr_src[k + 12], a7 = csr_src[k + 14];
        unsigned r0 = *(const unsigned*)&hb[(size_t)a0 * HID + lp2];
        unsigned r1 = *(const unsigned*)&hb[(size_t)a1 * HID + lp2];
        unsigned r2 = *(const unsigned*)&hb[(size_t)a2 * HID + lp2];
        unsigned r3 = *(const unsigned*)&hb[(size_t)a3 * HID + lp2];
        unsigned r4 = *(const unsigned*)&hb[(size_t)a4 * HID + lp2];
        unsigned r5 = *(const unsigned*)&hb[(size_t)a5 * HID + lp2];
        unsigned r6 = *(const unsigned*)&hb[(size_t)a6 * HID + lp2];
        unsigned r7 = *(const unsigned*)&hb[(size_t)a7 * HID + lp2];
        s0 += ((bf_lo(r0) + bf_lo(r1)) + (bf_lo(r2) + bf_lo(r3))) +
              ((bf_lo(r4) + bf_lo(r5)) + (bf_lo(r6) + bf_lo(r7)));
        s1 += ((bf_hi(r0) + bf_hi(r1)) + (bf_hi(r2) + bf_hi(r3))) +
              ((bf_hi(r4) + bf_hi(r5)) + (bf_hi(r6) + bf_hi(r7)));
    }
    for (; k + 6 < end; k += 8) {
        int a0 = csr_src[k], a1 = csr_src[k + 2], a2 = csr_src[k + 4], a3 = csr_src[k + 6];
        unsigned r0 = *(const unsigned*)&hb[(size_t)a0 * HID + lp2];
        unsigned r1 = *(const unsigned*)&hb[(size_t)a1 * HID + lp2];
        unsigned r2 = *(const unsigned*)&hb[(size_t)a2 * HID + lp2];
        unsigned r3 = *(const unsigned*)&hb[(size_t)a3 * HID + lp2];
        s0 += (bf_lo(r0) + bf_lo(r1)) + (bf_lo(r2) + bf_lo(r3));
        s1 += (bf_hi(r0) + bf_hi(r1)) + (bf_hi(r2) + bf_hi(r3));
    }
    for (; k < end; k += 2) {
        unsigned r0 = *(const unsigned*)&hb[(size_t)csr_src[k] * HID + lp2];
        s0 += bf_lo(r0);
        s1 += bf_hi(r0);
    }
    // merge parity halves
    s0 += __shfl_xor(s0, 32, 64);
    s1 += __shfl_xor(s1, 32, 64);
    // self-loop
    unsigned sv = *(const unsigned*)&hb[(size_t)i * HID + lp2];
    s0 += bf_lo(sv);
    s1 += bf_hi(sv);
    return make_float2(s0, s1);
}

// ---------------- fused gather(L1) + MFMA mm2: 32 rows/block ----------------
__global__ __launch_bounds__(256) void gather_mm2_kernel(
    const int* __restrict__ row_ptr, const int* __restrict__ rend,
    const int* __restrict__ csr_src, const float* __restrict__ dinv,
    const __hip_bfloat16* __restrict__ hbs1, const __hip_bfloat16* __restrict__ w2frag,
    const float* __restrict__ b1, __hip_bfloat16* __restrict__ hbs2, int n) {
    __shared__ __attribute__((aligned(16))) unsigned short x1s[32 * 64];  // 4 KB
    int t = threadIdx.x;
    int lane = t & 63;
    int wv = t >> 6;
    int halfe = lane >> 5;
    int lp = lane & 31;
    int lp2 = lp * 2;
    int n0 = blockIdx.x << 5;
    float2 b1v = *(const float2*)&b1[lp2];

    for (int rr = 0; rr < 8; ++rr) {
        int row = wv * 8 + rr;
        int i = n0 + row;
        unsigned pk = 0;
        if (i < n) {
            float2 s = gather_row2(csr_src, hbs1, i, row_ptr[i], rend[i], halfe, lp2);
            float dv = dinv[i];
            pk = pack_bf2(fmaxf(fmaf(dv, s.x, b1v.x), 0.0f),
                          fmaxf(fmaf(dv, s.y, b1v.y), 0.0f));
        }
        if (lane < 32) {
            int blk = (lp >> 2) ^ (row & 7);   // 16B-block XOR swizzle (bank-conflict-free)
            *(unsigned*)&x1s[row * 64 + (blk << 3) + (lp2 & 7)] = pk;
        }
    }
    __syncthreads();

    if (wv < 2) {   // wv = n-tile index
        int half = lane >> 5;
        const uint4* wf = (const uint4*)w2frag;
        f32x16 acc;
#pragma unroll
        for (int r = 0; r < 16; ++r) acc[r] = 0.0f;
#pragma unroll
        for (int c = 0; c < 4; ++c) {
            Frag fa, fb;
            int blk = (c * 2 + half) ^ (lp & 7);
            fa.u4 = *(const uint4*)&x1s[lp * 64 + (blk << 3)];
            fb.u4 = wf[(c * 2 + wv) * 64 + lane];
            acc = __builtin_amdgcn_mfma_f32_32x32x16_bf16(fa.s8, fb.s8, acc, 0, 0, 0);
        }
#pragma unroll
        for (int r = 0; r < 16; ++r) {
            int m = (r & 3) + 8 * (r >> 2) + 4 * half;
            int i = n0 + m;
            if (i < n)
                hbs2[(size_t)i * HID + lp + 32 * wv] = __float2bfloat16(acc[r] * dinv[i]);
        }
    }
}

// ---------------- gather(layer2): xb = bf16(dv*sum + b2) ----------------
__global__ __launch_bounds__(256) void gather_out_kernel(
    const int* __restrict__ row_ptr, const int* __restrict__ rend,
    const int* __restrict__ csr_src, const float* __restrict__ dinv,
    const __hip_bfloat16* __restrict__ hbs2, const float* __restrict__ b2,
    __hip_bfloat16* __restrict__ xb, int n) {
    int t = threadIdx.x;
    int lane = t & 63;
    int halfe = lane >> 5;
    int lp = lane & 31;
    int lp2 = lp * 2;
    int i = blockIdx.x * 4 + (t >> 6);
    if (i >= n) return;
    float2 s = gather_row2(csr_src, hbs2, i, row_ptr[i], rend[i], halfe, lp2);
    if (lane < 32) {
        float dv = dinv[i];
        float2 b2v = *(const float2*)&b2[lp2];
        *(unsigned*)&xb[(size_t)i * HID + lp2] =
            pack_bf2(fmaf(dv, s.x, b2v.x), fmaf(dv, s.y, b2v.y));
    }
}

// ---------------- pair MLP head via MFMA (C/D layout HW-verified) ----------------
__global__ __launch_bounds__(256) void final_mfma_kernel(
    const int* __restrict__ pairs, const float* __restrict__ pf,
    const __hip_bfloat16* __restrict__ xb, const __hip_bfloat16* __restrict__ wfrag,
    const float* __restrict__ bf1, const float* __restrict__ Wf2,
    const float* __restrict__ bf2, float* __restrict__ out, int p) {
    int lane = threadIdx.x & 63;
    int wid  = threadIdx.x >> 6;
    int half = lane >> 5;
    int lp   = lane & 31;

    float bf1a = bf1[lp];
    float bf1b = bf1[32 + lp];
    float w2a  = Wf2[lp];
    float w2b  = Wf2[32 + lp];
    float bf2r = bf2[0];

    const uint4* wf = (const uint4*)wfrag;

    int ngroups = (p + 31) >> 5;
    int nw = gridDim.x * 4;
    for (int g = blockIdx.x * 4 + wid; g < ngroups; g += nw) {
        int p32 = g << 5;
        int pi = p32 + lp; if (pi >= p) pi = p - 1;
        int2 pr = ((const int2*)pairs)[pi];
        const uint4* drow = (const uint4*)(xb + (size_t)pr.x * HID);
        const uint4* arow = (const uint4*)(xb + (size_t)pr.y * HID);

        f32x16 acc0, acc1;
#pragma unroll
        for (int r = 0; r < 16; ++r) { acc0[r] = 0.0f; acc1[r] = 0.0f; }

#pragma unroll
        for (int c = 0; c < 4; ++c) {
            Frag fd, fx, fa, fb0, fb1;
            fd.u4 = drow[c * 2 + half];
            fx.u4 = arow[c * 2 + half];
#pragma unroll
            for (int q = 0; q < 4; ++q) fa.h2[q] = __hmul2(fd.h2[q], fx.h2[q]);
            fb0.u4 = wf[(c * 2 + 0) * 64 + lane];
            fb1.u4 = wf[(c * 2 + 1) * 64 + lane];
            acc0 = __builtin_amdgcn_mfma_f32_32x32x16_bf16(fa.s8, fb0.s8, acc0, 0, 0, 0);
            acc1 = __builtin_amdgcn_mfma_f32_32x32x16_bf16(fa.s8, fb1.s8, acc1, 0, 0, 0);
        }
        {   // chunk 4: patient features (k=64..71 real, 72..79 zero-pad)
            Frag fa, fb0, fb1;
            if (half == 0) {
                float4 lo = ((const float4*)pf)[pi * 2];
                float4 hi = ((const float4*)pf)[pi * 2 + 1];
                fa.h[0] = __float2bfloat16(lo.x); fa.h[1] = __float2bfloat16(lo.y);
                fa.h[2] = __float2bfloat16(lo.z); fa.h[3] = __float2bfloat16(lo.w);
                fa.h[4] = __float2bfloat16(hi.x); fa.h[5] = __float2bfloat16(hi.y);
                fa.h[6] = __float2bfloat16(hi.z); fa.h[7] = __float2bfloat16(hi.w);
            } else {
#pragma unroll
                for (int e = 0; e < 8; ++e) fa.us[e] = 0;
            }
            fb0.u4 = wf[8 * 64 + lane];
            fb1.u4 = wf[9 * 64 + lane];
            acc0 = __builtin_amdgcn_mfma_f32_32x32x16_bf16(fa.s8, fb0.s8, acc0, 0, 0, 0);
            acc1 = __builtin_amdgcn_mfma_f32_32x32x16_bf16(fa.s8, fb1.s8, acc1, 0, 0, 0);
        }

        float t[16];
#pragma unroll
        for (int r = 0; r < 16; ++r)
            t[r] = fmaxf(acc0[r] + bf1a, 0.0f) * w2a + fmaxf(acc1[r] + bf1b, 0.0f) * w2b;

#pragma unroll
        for (int off = 1; off < 32; off <<= 1) {
#pragma unroll
            for (int r = 0; r < 16; ++r) t[r] += __shfl_xor(t[r], off, 64);
        }

        if (lp < 16) {
            int j = lp;
            float u[8];
#pragma unroll
            for (int r = 0; r < 8; ++r) u[r] = (j & 1) ? t[2 * r + 1] : t[2 * r];
            float v4[4];
#pragma unroll
            for (int r = 0; r < 4; ++r) v4[r] = (j & 2) ? u[2 * r + 1] : u[2 * r];
            float w2v[2];
#pragma unroll
            for (int r = 0; r < 2; ++r) w2v[r] = (j & 4) ? v4[2 * r + 1] : v4[2 * r];
            float z = (j & 8) ? w2v[1] : w2v[0];
            int m = (j & 3) + ((j >> 2) << 3) + (half << 2);
            int po = p32 + m;
            if (po < p) out[po] = 1.0f / (1.0f + expf(-(z + bf2r)));
        }
    }
}

extern "C" void kernel_launch(void* const* d_in, const int* in_sizes, int n_in,
                              void* d_out, int out_size, void* d_ws, size_t ws_size,
                              hipStream_t stream) {
    const int*   edge_index = (const int*)d_in[0];
    const int*   edge_pairs = (const int*)d_in[1];
    const float* pf         = (const float*)d_in[2];
    const float* emb        = (const float*)d_in[3];
    const float* W1         = (const float*)d_in[4];
    const float* b1         = (const float*)d_in[5];
    const float* W2         = (const float*)d_in[6];
    const float* b2         = (const float*)d_in[7];
    const float* Wf1        = (const float*)d_in[8];
    const float* bf1        = (const float*)d_in[9];
    const float* Wf2        = (const float*)d_in[10];
    const float* bf2        = (const float*)d_in[11];
    float*       out        = (float*)d_out;

    const int E = in_sizes[0] / 2;
    const int P = in_sizes[1] / 2;
    const int N = in_sizes[3] / EMB;
    const int NBUCK = (N + (1 << BSH) - 1) >> BSH;   // 196 for N=100k (<=NBMAX)

    char* ws = (char*)d_ws;
    size_t off = 0;
    float*          dinv    = (float*)(ws + off);          off += ((size_t)N * 4 + 255) & ~255ULL;
    __hip_bfloat16* hbs1    = (__hip_bfloat16*)(ws + off); off += ((size_t)N * HID * 2 + 255) & ~255ULL;
    __hip_bfloat16* hbs2    = (__hip_bfloat16*)(ws + off); off += ((size_t)N * HID * 2 + 255) & ~255ULL;
    __hip_bfloat16* xb      = (__hip_bfloat16*)(ws + off); off += ((size_t)N * HID * 2 + 255) & ~255ULL;
    __hip_bfloat16* wfrag   = (__hip_bfloat16*)(ws + off); off += ((size_t)10 * 512 * 2 + 255) & ~255ULL;
    __hip_bfloat16* w2frag  = (__hip_bfloat16*)(ws + off); off += ((size_t)8 * 512 * 2 + 255) & ~255ULL;
    int*            row_ptr = (int*)(ws + off);            off += ((size_t)N * 4 + 255) & ~255ULL;
    int*            rend    = (int*)(ws + off);            off += ((size_t)N * 4 + 255) & ~255ULL;
    int*            btot    = (int*)(ws + off);            off += ((size_t)NBMAX * 4 + 255) & ~255ULL;
    int*            bbase   = (int*)(ws + off);            off += ((size_t)(NBMAX + 1) * 4 + 255) & ~255ULL;
    int*            bcur    = (int*)(ws + off);            off += ((size_t)NBMAX * 4 + 255) & ~255ULL;
    int*            csr_src = (int*)(ws + off);            off += ((size_t)E * 4 + 255) & ~255ULL;
    unsigned*       pairs2  = (unsigned*)(ws + off);       off += ((size_t)E * 4 + 255) & ~255ULL;
    (void)ws_size;

    const int EBLK = (E + CHUNK - 1) / CHUNK;

    // ---- CSR build (bucket hist -> scan -> partition -> bucket scatter) ----
    hipMemsetAsync(btot, 0, (size_t)NBMAX * 4, stream);
    bucket_hist_kernel<<<EBLK, 256, 0, stream>>>(edge_index + E, btot, E);
    prep_wf1_kernel<<<20, 256, 0, stream>>>(Wf1, wfrag);
    prep_w2_kernel<<<16, 256, 0, stream>>>(W2, w2frag);
    scan_buckets_kernel<<<1, 256, 0, stream>>>(btot, bbase, bcur, NBUCK, E);
    partition_kernel<<<EBLK, 256, 0, stream>>>(edge_index, bcur, pairs2, E);
    bucket_scatter_kernel<<<NBUCK, 256, 0, stream>>>(bbase, pairs2, csr_src,
                                                     row_ptr, rend, dinv, N);

    // ---- layer 1: h1*dinv (bf16) ----
    mm1_kernel<<<(N + 3) / 4, 256, 0, stream>>>(emb, W1, dinv, hbs1, N);

    // ---- fused gather(L1) + MFMA mm2 -> hbs2 ----
    gather_mm2_kernel<<<(N + 31) / 32, 256, 0, stream>>>(row_ptr, rend, csr_src, dinv,
                                                         hbs1, w2frag, b1, hbs2, N);

    // ---- gather(L2) -> xb (b2 folded) ----
    gather_out_kernel<<<(N + 3) / 4, 256, 0, stream>>>(row_ptr, rend, csr_src, dinv,
                                                       hbs2, b2, xb, N);

    // ---- pair MLP head (MFMA) ----
    final_mfma_kernel<<<2048, 256, 0, stream>>>(edge_pairs, pf, xb, wfrag,
                                                bf1, Wf2, bf2, out, P);
}

// Round 14
// 368.259 us; speedup vs baseline: 7.7632x; 1.0426x over previous
//
#include <hip/hip_runtime.h>
#include <hip/hip_bf16.h>
#include <math.h>

#define EMB 32
#define HID 64
#define PAT 8

#define BSH   9                 // nodes per bucket = 512
#define NBMAX 256               // max buckets supported (N <= 131072; src fits 17 bits)
#define CHUNK 4096              // edges per partition block

typedef __attribute__((ext_vector_type(8))) short short8v;   // 8 bf16 = 4 VGPRs
typedef __attribute__((ext_vector_type(16))) float f32x16;   // MFMA 32x32 accumulator

union Frag {
    short8v s8;
    uint4 u4;
    __hip_bfloat162 h2[4];
    __hip_bfloat16 h[8];
    unsigned short us[8];
};

__device__ __forceinline__ float bf_lo(unsigned v) { return __uint_as_float(v << 16); }
__device__ __forceinline__ float bf_hi(unsigned v) { return __uint_as_float(v & 0xFFFF0000u); }
__device__ __forceinline__ unsigned pack_bf2(float a, float b) {
    __hip_bfloat16 ba = __float2bfloat16(a), bb = __float2bfloat16(b);
    return ((unsigned)*(unsigned short*)&bb << 16) | *(unsigned short*)&ba;
}

// ---------------- pass 0: per-block LDS bucket histogram ----------------
__global__ __launch_bounds__(256) void bucket_hist_kernel(
    const int* __restrict__ dst, int* __restrict__ btot, int e) {
    __shared__ int cnt[NBMAX];
    int t = threadIdx.x;
    for (int k = t; k < NBMAX; k += 256) cnt[k] = 0;
    __syncthreads();
    int e0 = blockIdx.x * CHUNK;
    int ec = min(CHUNK, e - e0);
    for (int k = t; k < ec; k += 256)
        atomicAdd(&cnt[dst[e0 + k] >> BSH], 1);
    __syncthreads();
    for (int k = t; k < NBMAX; k += 256)
        if (cnt[k]) atomicAdd(&btot[k], cnt[k]);
}

// one block: exclusive scan of bucket totals -> bbase (197 entries), bcur
__global__ void scan_buckets_kernel(const int* __restrict__ btot, int* __restrict__ bbase,
                                    int* __restrict__ bcur, int nbuck, int e) {
    __shared__ int s[256];
    int t = threadIdx.x;
    int v = (t < nbuck) ? btot[t] : 0;
    s[t] = v;
    __syncthreads();
    for (int off = 1; off < 256; off <<= 1) {
        int u = (t >= off) ? s[t - off] : 0;
        __syncthreads();
        s[t] += u;
        __syncthreads();
    }
    if (t < nbuck) {
        int ex = s[t] - v;
        bbase[t] = ex;
        bcur[t]  = ex;
    }
    if (t == 0) bbase[nbuck] = e;
}

// ---------------- pass A: LDS-staged partition; output packed (dlocal<<17 | src) ----------------
__global__ __launch_bounds__(256) void partition_kernel(
    const int* __restrict__ ei, int* __restrict__ bcur,
    unsigned* __restrict__ pairs, int e) {
    __shared__ int cnt[NBMAX];
    __shared__ int scn[NBMAX];
    __shared__ int loff[NBMAX];
    __shared__ int base[NBMAX];
    __shared__ int2 stg[CHUNK];
    int t = threadIdx.x;
    int e0 = blockIdx.x * CHUNK;
    int ecnt = min(CHUNK, e - e0);

    for (int k = t; k < NBMAX; k += 256) cnt[k] = 0;
    __syncthreads();
    for (int k = t; k < ecnt; k += 256)
        atomicAdd(&cnt[ei[e + e0 + k] >> BSH], 1);
    __syncthreads();
    int c = cnt[t];
    scn[t] = c;
    __syncthreads();
    for (int off = 1; off < 256; off <<= 1) {
        int u = (t >= off) ? scn[t - off] : 0;
        __syncthreads();
        scn[t] += u;
        __syncthreads();
    }
    int ex = scn[t] - c;
    __syncthreads();
    scn[t] = ex;
    loff[t] = ex;
    base[t] = c ? atomicAdd(&bcur[t], c) : 0;
    __syncthreads();
    for (int k = t; k < ecnt; k += 256) {
        int s = ei[e0 + k];
        int d = ei[e + e0 + k];
        int pos = atomicAdd(&loff[d >> BSH], 1);
        stg[pos] = make_int2(s, d);
    }
    __syncthreads();
    for (int k = t; k < ecnt; k += 256) {
        int2 pr = stg[k];
        int b = pr.y >> BSH;
        unsigned pk = ((unsigned)(pr.y & ((1 << BSH) - 1)) << 17) | (unsigned)pr.x;
        pairs[base[b] + (k - scn[b])] = pk;
    }
}

// ---------------- pass B: per-bucket count+scan+scatter; emits row_ptr/rend/dinv/csr_src ----------------
__global__ __launch_bounds__(256) void bucket_scatter_kernel(
    const int* __restrict__ bbase, const unsigned* __restrict__ pairs,
    int* __restrict__ csr_src, int* __restrict__ row_ptr, int* __restrict__ rend,
    float* __restrict__ dinv, int n) {
    __shared__ int cnt[1 << BSH];
    __shared__ int scn[256];
    __shared__ int cur[1 << BSH];
    int b = blockIdx.x;
    int n0 = b << BSH;
    int nn = min(1 << BSH, n - n0);
    int t = threadIdx.x;
    cnt[t] = 0; cnt[t + 256] = 0;
    __syncthreads();
    int p0 = bbase[b], p1 = bbase[b + 1];
    for (int k = p0 + t; k < p1; k += 256)
        atomicAdd(&cnt[pairs[k] >> 17], 1);
    __syncthreads();
    int ca = cnt[2 * t], cb = cnt[2 * t + 1];
    int c2 = ca + cb;
    scn[t] = c2;
    __syncthreads();
    for (int off = 1; off < 256; off <<= 1) {
        int u = (t >= off) ? scn[t - off] : 0;
        __syncthreads();
        scn[t] += u;
        __syncthreads();
    }
    int ex2 = scn[t] - c2;
    int ea = p0 + ex2;
    int eb = ea + ca;
    if (2 * t < nn) {
        row_ptr[n0 + 2 * t] = ea;
        rend[n0 + 2 * t]    = ea + ca;
        dinv[n0 + 2 * t]    = rsqrtf(1.0f + (float)ca);
        cur[2 * t] = ea;
    }
    if (2 * t + 1 < nn) {
        row_ptr[n0 + 2 * t + 1] = eb;
        rend[n0 + 2 * t + 1]    = eb + cb;
        dinv[n0 + 2 * t + 1]    = rsqrtf(1.0f + (float)cb);
        cur[2 * t + 1] = eb;
    }
    __syncthreads();
    for (int k = p0 + t; k < p1; k += 256) {
        unsigned v = pairs[k];
        int pos = atomicAdd(&cur[v >> 17], 1);
        csr_src[pos] = (int)(v & 0x1FFFFu);
    }
}

// ---------------- pack Wf1 into MFMA fragment order (bf16) ----------------
// Used as the A-operand (m=channel): lane l holds ch=(l&31)+32t, k=c*16+(l>>5)*8+e.
__global__ void prep_wf1_kernel(const float* __restrict__ Wf1, __hip_bfloat16* __restrict__ wfrag) {
    int gid = blockIdx.x * blockDim.x + threadIdx.x;
    if (gid >= 10 * 512) return;
    int f = gid >> 9;
    int rem = gid & 511;
    int l = rem >> 3;
    int e = rem & 7;
    int c = f >> 1;
    int t = f & 1;
    int k = c * 16 + ((l >> 5) << 3) + e;
    int n = (l & 31) + (t << 5);
    float v = (k < HID + PAT) ? Wf1[k * 64 + n] : 0.0f;
    wfrag[gid] = __float2bfloat16(v);
}

// ---------------- pack W2 into MFMA B-fragment order (bf16): 8 frags ----------------
__global__ void prep_w2_kernel(const float* __restrict__ W2, __hip_bfloat16* __restrict__ w2frag) {
    int gid = blockIdx.x * blockDim.x + threadIdx.x;
    if (gid >= 8 * 512) return;
    int f = gid >> 9;
    int rem = gid & 511;
    int l = rem >> 3;
    int e = rem & 7;
    int c = f >> 1;
    int t = f & 1;
    int k = c * 16 + ((l >> 5) << 3) + e;
    int n = (l & 31) + (t << 5);
    w2frag[gid] = __float2bfloat16(W2[k * 64 + n]);
}

// ---------------- pack epilogue weights: wepi[r*2+half] = {bf1[ch], w2[ch], bf1[ch+32], w2[ch+32]} ----------------
// ch = (r&3)+8*(r>>2)+4*half  (the 32x32 MFMA C/D row mapping)
__global__ void prep_epi_kernel(const float* __restrict__ bf1, const float* __restrict__ Wf2,
                                float4* __restrict__ wepi) {
    int t = threadIdx.x;
    if (t >= 32) return;
    int r = t >> 1, half = t & 1;
    int ch = (r & 3) + 8 * (r >> 2) + 4 * half;
    wepi[t] = make_float4(bf1[ch], Wf2[ch], bf1[ch + 32], Wf2[ch + 32]);
}

// ---------------- layer-1 matmul: hbs1 = bf16((emb @ W1) * dinv) ----------------
__global__ __launch_bounds__(256) void mm1_kernel(
    const float* __restrict__ emb, const float* __restrict__ W1,
    const float* __restrict__ dinv,
    __hip_bfloat16* __restrict__ hbs, int n) {
    __shared__ float w[EMB * HID];  // 8 KB
    int t = threadIdx.x;
    for (int k = t; k < EMB * HID; k += 256) w[k] = W1[k];
    __syncthreads();
    int wave = t >> 6, lane = t & 63;
    int i = blockIdx.x * 4 + wave;
    if (i >= n) return;
    float e = (lane < EMB) ? emb[i * EMB + lane] : 0.0f;
    float acc = 0.0f;
#pragma unroll
    for (int k = 0; k < EMB; ++k) {
        float ek = __shfl(e, k, 64);
        acc += ek * w[k * HID + lane];
    }
    hbs[(size_t)i * HID + lane] = __float2bfloat16(acc * dinv[i]);
}

// ======== 2-edges-per-instruction gather core ========
__device__ __forceinline__ float2 gather_row2(
    const int* __restrict__ csr_src, const __hip_bfloat16* __restrict__ hb,
    int i, int e, int end, int halfe, int lp2) {
    float s0 = 0.0f, s1 = 0.0f;
    int k = e + halfe;
    for (; k + 14 < end; k += 16) {
        int a0 = csr_src[k],      a1 = csr_src[k + 2],  a2 = csr_src[k + 4],  a3 = csr_src[k + 6];
        int a4 = csr_src[k + 8],  a5 = csr_src[k + 10], a6 = csr_src[k + 12], a7 = csr_src[k + 14];
        unsigned r0 = *(const unsigned*)&hb[(size_t)a0 * HID + lp2];
        unsigned r1 = *(const unsigned*)&hb[(size_t)a1 * HID + lp2];
        unsigned r2 = *(const unsigned*)&hb[(size_t)a2 * HID + lp2];
        unsigned r3 = *(const unsigned*)&hb[(size_t)a3 * HID + lp2];
        unsigned r4 = *(const unsigned*)&hb[(size_t)a4 * HID + lp2];
        unsigned r5 = *(const unsigned*)&hb[(size_t)a5 * HID + lp2];
        unsigned r6 = *(const unsigned*)&hb[(size_t)a6 * HID + lp2];
        unsigned r7 = *(const unsigned*)&hb[(size_t)a7 * HID + lp2];
        s0 += ((bf_lo(r0) + bf_lo(r1)) + (bf_lo(r2) + bf_lo(r3))) +
              ((bf_lo(r4) + bf_lo(r5)) + (bf_lo(r6) + bf_lo(r7)));
        s1 += ((bf_hi(r0) + bf_hi(r1)) + (bf_hi(r2) + bf_hi(r3))) +
              ((bf_hi(r4) + bf_hi(r5)) + (bf_hi(r6) + bf_hi(r7)));
    }
    for (; k + 6 < end; k += 8) {
        int a0 = csr_src[k], a1 = csr_src[k + 2], a2 = csr_src[k + 4], a3 = csr_src[k + 6];
        unsigned r0 = *(const unsigned*)&hb[(size_t)a0 * HID + lp2];
        unsigned r1 = *(const unsigned*)&hb[(size_t)a1 * HID + lp2];
        unsigned r2 = *(const unsigned*)&hb[(size_t)a2 * HID + lp2];
        unsigned r3 = *(const unsigned*)&hb[(size_t)a3 * HID + lp2];
        s0 += (bf_lo(r0) + bf_lo(r1)) + (bf_lo(r2) + bf_lo(r3));
        s1 += (bf_hi(r0) + bf_hi(r1)) + (bf_hi(r2) + bf_hi(r3));
    }
    for (; k < end; k += 2) {
        unsigned r0 = *(const unsigned*)&hb[(size_t)csr_src[k] * HID + lp2];
        s0 += bf_lo(r0);
        s1 += bf_hi(r0);
    }
    s0 += __shfl_xor(s0, 32, 64);
    s1 += __shfl_xor(s1, 32, 64);
    unsigned sv = *(const unsigned*)&hb[(size_t)i * HID + lp2];
    s0 += bf_lo(sv);
    s1 += bf_hi(sv);
    return make_float2(s0, s1);
}

// ---------------- fused gather(L1) + MFMA mm2: 32 rows/block ----------------
__global__ __launch_bounds__(256) void gather_mm2_kernel(
    const int* __restrict__ row_ptr, const int* __restrict__ rend,
    const int* __restrict__ csr_src, const float* __restrict__ dinv,
    const __hip_bfloat16* __restrict__ hbs1, const __hip_bfloat16* __restrict__ w2frag,
    const float* __restrict__ b1, __hip_bfloat16* __restrict__ hbs2, int n) {
    __shared__ __attribute__((aligned(16))) unsigned short x1s[32 * 64];  // 4 KB
    int t = threadIdx.x;
    int lane = t & 63;
    int wv = t >> 6;
    int halfe = lane >> 5;
    int lp = lane & 31;
    int lp2 = lp * 2;
    int n0 = blockIdx.x << 5;
    float2 b1v = *(const float2*)&b1[lp2];

    for (int rr = 0; rr < 8; ++rr) {
        int row = wv * 8 + rr;
        int i = n0 + row;
        unsigned pk = 0;
        if (i < n) {
            float2 s = gather_row2(csr_src, hbs1, i, row_ptr[i], rend[i], halfe, lp2);
            float dv = dinv[i];
            pk = pack_bf2(fmaxf(fmaf(dv, s.x, b1v.x), 0.0f),
                          fmaxf(fmaf(dv, s.y, b1v.y), 0.0f));
        }
        if (lane < 32) {
            int blk = (lp >> 2) ^ (row & 7);   // 16B-block XOR swizzle (bank-conflict-free)
            *(unsigned*)&x1s[row * 64 + (blk << 3) + (lp2 & 7)] = pk;
        }
    }
    __syncthreads();

    if (wv < 2) {   // wv = n-tile index
        int half = lane >> 5;
        const uint4* wf = (const uint4*)w2frag;
        f32x16 acc;
#pragma unroll
        for (int r = 0; r < 16; ++r) acc[r] = 0.0f;
#pragma unroll
        for (int c = 0; c < 4; ++c) {
            Frag fa, fb;
            int blk = (c * 2 + half) ^ (lp & 7);
            fa.u4 = *(const uint4*)&x1s[lp * 64 + (blk << 3)];
            fb.u4 = wf[(c * 2 + wv) * 64 + lane];
            acc = __builtin_amdgcn_mfma_f32_32x32x16_bf16(fa.s8, fb.s8, acc, 0, 0, 0);
        }
#pragma unroll
        for (int r = 0; r < 16; ++r) {
            int m = (r & 3) + 8 * (r >> 2) + 4 * half;
            int i = n0 + m;
            if (i < n)
                hbs2[(size_t)i * HID + lp + 32 * wv] = __float2bfloat16(acc[r] * dinv[i]);
        }
    }
}

// ---------------- gather(layer2): xb = bf16(dv*sum + b2) ----------------
__global__ __launch_bounds__(256) void gather_out_kernel(
    const int* __restrict__ row_ptr, const int* __restrict__ rend,
    const int* __restrict__ csr_src, const float* __restrict__ dinv,
    const __hip_bfloat16* __restrict__ hbs2, const float* __restrict__ b2,
    __hip_bfloat16* __restrict__ xb, int n) {
    int t = threadIdx.x;
    int lane = t & 63;
    int halfe = lane >> 5;
    int lp = lane & 31;
    int lp2 = lp * 2;
    int i = blockIdx.x * 4 + (t >> 6);
    if (i >= n) return;
    float2 s = gather_row2(csr_src, hbs2, i, row_ptr[i], rend[i], halfe, lp2);
    if (lane < 32) {
        float dv = dinv[i];
        float2 b2v = *(const float2*)&b2[lp2];
        *(unsigned*)&xb[(size_t)i * HID + lp2] =
            pack_bf2(fmaf(dv, s.x, b2v.x), fmaf(dv, s.y, b2v.y));
    }
}

// ---------------- pair MLP head via MFMA, SWAPPED operands ----------------
// D' = Wf1_frag (A, m=channel) x combined_frag (B, n=pair): lane holds col=pair,
// channels in regs -> layer-2 reduce is per-lane FMA over 32 regs + ONE shfl_xor(32).
// A/B fragment symmetry means fa/wfrag are byte-identical to the old version.
__global__ __launch_bounds__(256) void final_mfma_kernel(
    const int* __restrict__ pairs, const float* __restrict__ pf,
    const __hip_bfloat16* __restrict__ xb, const __hip_bfloat16* __restrict__ wfrag,
    const float4* __restrict__ wepi, const float* __restrict__ bf2,
    float* __restrict__ out, int p) {
    int lane = threadIdx.x & 63;
    int wid  = threadIdx.x >> 6;
    int half = lane >> 5;
    int lp   = lane & 31;

    float bf2r = bf2[0];
    const uint4* wf = (const uint4*)wfrag;

    int ngroups = (p + 31) >> 5;
    int nw = gridDim.x * 4;
    for (int g = blockIdx.x * 4 + wid; g < ngroups; g += nw) {
        int p32 = g << 5;
        int pi = p32 + lp; if (pi >= p) pi = p - 1;
        int2 pr = ((const int2*)pairs)[pi];
        const uint4* drow = (const uint4*)(xb + (size_t)pr.x * HID);
        const uint4* arow = (const uint4*)(xb + (size_t)pr.y * HID);

        f32x16 acc0, acc1;
#pragma unroll
        for (int r = 0; r < 16; ++r) { acc0[r] = 0.0f; acc1[r] = 0.0f; }

#pragma unroll
        for (int c = 0; c < 4; ++c) {
            Frag fd, fx, fa, fb0, fb1;
            fd.u4 = drow[c * 2 + half];
            fx.u4 = arow[c * 2 + half];
#pragma unroll
            for (int q = 0; q < 4; ++q) fa.h2[q] = __hmul2(fd.h2[q], fx.h2[q]);
            fb0.u4 = wf[(c * 2 + 0) * 64 + lane];
            fb1.u4 = wf[(c * 2 + 1) * 64 + lane];
            acc0 = __builtin_amdgcn_mfma_f32_32x32x16_bf16(fb0.s8, fa.s8, acc0, 0, 0, 0);
            acc1 = __builtin_amdgcn_mfma_f32_32x32x16_bf16(fb1.s8, fa.s8, acc1, 0, 0, 0);
        }
        {   // chunk 4: patient features (k=64..71 real, 72..79 zero-pad)
            Frag fa, fb0, fb1;
            if (half == 0) {
                float4 lo = ((const float4*)pf)[pi * 2];
                float4 hi = ((const float4*)pf)[pi * 2 + 1];
                fa.h[0] = __float2bfloat16(lo.x); fa.h[1] = __float2bfloat16(lo.y);
                fa.h[2] = __float2bfloat16(lo.z); fa.h[3] = __float2bfloat16(lo.w);
                fa.h[4] = __float2bfloat16(hi.x); fa.h[5] = __float2bfloat16(hi.y);
                fa.h[6] = __float2bfloat16(hi.z); fa.h[7] = __float2bfloat16(hi.w);
            } else {
#pragma unroll
                for (int e = 0; e < 8; ++e) fa.us[e] = 0;
            }
            fb0.u4 = wf[8 * 64 + lane];
            fb1.u4 = wf[9 * 64 + lane];
            acc0 = __builtin_amdgcn_mfma_f32_32x32x16_bf16(fb0.s8, fa.s8, acc0, 0, 0, 0);
            acc1 = __builtin_amdgcn_mfma_f32_32x32x16_bf16(fb1.s8, fa.s8, acc1, 0, 0, 0);
        }

        // layer 2: per-lane over 32 register-resident channels, then one lane-swap
        float s = 0.0f;
#pragma unroll
        for (int r = 0; r < 16; ++r) {
            float4 wv = wepi[r * 2 + half];
            s += fmaxf(acc0[r] + wv.x, 0.0f) * wv.y
               + fmaxf(acc1[r] + wv.z, 0.0f) * wv.w;
        }
        s += __shfl_xor(s, 32, 64);
        if (lane < 32) {
            int po = p32 + lp;
            if (po < p) out[po] = 1.0f / (1.0f + expf(-(s + bf2r)));
        }
    }
}

extern "C" void kernel_launch(void* const* d_in, const int* in_sizes, int n_in,
                              void* d_out, int out_size, void* d_ws, size_t ws_size,
                              hipStream_t stream) {
    const int*   edge_index = (const int*)d_in[0];
    const int*   edge_pairs = (const int*)d_in[1];
    const float* pf         = (const float*)d_in[2];
    const float* emb        = (const float*)d_in[3];
    const float* W1         = (const float*)d_in[4];
    const float* b1         = (const float*)d_in[5];
    const float* W2         = (const float*)d_in[6];
    const float* b2         = (const float*)d_in[7];
    const float* Wf1        = (const float*)d_in[8];
    const float* bf1        = (const float*)d_in[9];
    const float* Wf2        = (const float*)d_in[10];
    const float* bf2        = (const float*)d_in[11];
    float*       out        = (float*)d_out;

    const int E = in_sizes[0] / 2;
    const int P = in_sizes[1] / 2;
    const int N = in_sizes[3] / EMB;
    const int NBUCK = (N + (1 << BSH) - 1) >> BSH;   // 196 for N=100k (<=NBMAX)

    char* ws = (char*)d_ws;
    size_t off = 0;
    float*          dinv    = (float*)(ws + off);          off += ((size_t)N * 4 + 255) & ~255ULL;
    __hip_bfloat16* hbs1    = (__hip_bfloat16*)(ws + off); off += ((size_t)N * HID * 2 + 255) & ~255ULL;
    __hip_bfloat16* hbs2    = (__hip_bfloat16*)(ws + off); off += ((size_t)N * HID * 2 + 255) & ~255ULL;
    __hip_bfloat16* xb      = (__hip_bfloat16*)(ws + off); off += ((size_t)N * HID * 2 + 255) & ~255ULL;
    __hip_bfloat16* wfrag   = (__hip_bfloat16*)(ws + off); off += ((size_t)10 * 512 * 2 + 255) & ~255ULL;
    __hip_bfloat16* w2frag  = (__hip_bfloat16*)(ws + off); off += ((size_t)8 * 512 * 2 + 255) & ~255ULL;
    float4*         wepi    = (float4*)(ws + off);         off += ((size_t)32 * 16 + 255) & ~255ULL;
    int*            row_ptr = (int*)(ws + off);            off += ((size_t)N * 4 + 255) & ~255ULL;
    int*            rend    = (int*)(ws + off);            off += ((size_t)N * 4 + 255) & ~255ULL;
    int*            btot    = (int*)(ws + off);            off += ((size_t)NBMAX * 4 + 255) & ~255ULL;
    int*            bbase   = (int*)(ws + off);            off += ((size_t)(NBMAX + 1) * 4 + 255) & ~255ULL;
    int*            bcur    = (int*)(ws + off);            off += ((size_t)NBMAX * 4 + 255) & ~255ULL;
    int*            csr_src = (int*)(ws + off);            off += ((size_t)E * 4 + 255) & ~255ULL;
    unsigned*       pairs2  = (unsigned*)(ws + off);       off += ((size_t)E * 4 + 255) & ~255ULL;
    (void)ws_size;

    const int EBLK = (E + CHUNK - 1) / CHUNK;

    // ---- CSR build (bucket hist -> scan -> partition -> bucket scatter) ----
    hipMemsetAsync(btot, 0, (size_t)NBMAX * 4, stream);
    bucket_hist_kernel<<<EBLK, 256, 0, stream>>>(edge_index + E, btot, E);
    prep_wf1_kernel<<<20, 256, 0, stream>>>(Wf1, wfrag);
    prep_w2_kernel<<<16, 256, 0, stream>>>(W2, w2frag);
    prep_epi_kernel<<<1, 32, 0, stream>>>(bf1, Wf2, wepi);
    scan_buckets_kernel<<<1, 256, 0, stream>>>(btot, bbase, bcur, NBUCK, E);
    partition_kernel<<<EBLK, 256, 0, stream>>>(edge_index, bcur, pairs2, E);
    bucket_scatter_kernel<<<NBUCK, 256, 0, stream>>>(bbase, pairs2, csr_src,
                                                     row_ptr, rend, dinv, N);

    // ---- layer 1: h1*dinv (bf16) ----
    mm1_kernel<<<(N + 3) / 4, 256, 0, stream>>>(emb, W1, dinv, hbs1, N);

    // ---- fused gather(L1) + MFMA mm2 -> hbs2 ----
    gather_mm2_kernel<<<(N + 31) / 32, 256, 0, stream>>>(row_ptr, rend, csr_src, dinv,
                                                         hbs1, w2frag, b1, hbs2, N);

    // ---- gather(L2) -> xb (b2 folded) ----
    gather_out_kernel<<<(N + 3) / 4, 256, 0, stream>>>(row_ptr, rend, csr_src, dinv,
                                                       hbs2, b2, xb, N);

    // ---- pair MLP head (MFMA, swapped operands) ----
    final_mfma_kernel<<<2048, 256, 0, stream>>>(edge_pairs, pf, xb, wfrag,
                                                wepi, bf2, out, P);
}

// Round 15
// 363.765 us; speedup vs baseline: 7.8591x; 1.0124x over previous
//
#include <hip/hip_runtime.h>
#include <hip/hip_bf16.h>
#include <math.h>

#define EMB 32
#define HID 64
#define PAT 8

#define BSH   9                 // nodes per bucket = 512
#define NBMAX 256               // max buckets supported (N <= 131072; src fits 17 bits)
#define CHUNK 4096              // edges per partition block

typedef __attribute__((ext_vector_type(8))) short short8v;   // 8 bf16 = 4 VGPRs
typedef __attribute__((ext_vector_type(16))) float f32x16;   // MFMA 32x32 accumulator

union Frag {
    short8v s8;
    uint4 u4;
    __hip_bfloat162 h2[4];
    __hip_bfloat16 h[8];
    unsigned short us[8];
};

__device__ __forceinline__ float bf_lo(unsigned v) { return __uint_as_float(v << 16); }
__device__ __forceinline__ float bf_hi(unsigned v) { return __uint_as_float(v & 0xFFFF0000u); }
__device__ __forceinline__ unsigned pack_bf2(float a, float b) {
    __hip_bfloat16 ba = __float2bfloat16(a), bb = __float2bfloat16(b);
    return ((unsigned)*(unsigned short*)&bb << 16) | *(unsigned short*)&ba;
}

// ---------------- pass 0: per-block LDS bucket histogram ----------------
__global__ __launch_bounds__(256) void bucket_hist_kernel(
    const int* __restrict__ dst, int* __restrict__ btot, int e) {
    __shared__ int cnt[NBMAX];
    int t = threadIdx.x;
    for (int k = t; k < NBMAX; k += 256) cnt[k] = 0;
    __syncthreads();
    int e0 = blockIdx.x * CHUNK;
    int ec = min(CHUNK, e - e0);
    for (int k = t; k < ec; k += 256)
        atomicAdd(&cnt[dst[e0 + k] >> BSH], 1);
    __syncthreads();
    for (int k = t; k < NBMAX; k += 256)
        if (cnt[k]) atomicAdd(&btot[k], cnt[k]);
}

// one block: exclusive scan of bucket totals -> bbase (197 entries), bcur
__global__ void scan_buckets_kernel(const int* __restrict__ btot, int* __restrict__ bbase,
                                    int* __restrict__ bcur, int nbuck, int e) {
    __shared__ int s[256];
    int t = threadIdx.x;
    int v = (t < nbuck) ? btot[t] : 0;
    s[t] = v;
    __syncthreads();
    for (int off = 1; off < 256; off <<= 1) {
        int u = (t >= off) ? s[t - off] : 0;
        __syncthreads();
        s[t] += u;
        __syncthreads();
    }
    if (t < nbuck) {
        int ex = s[t] - v;
        bbase[t] = ex;
        bcur[t]  = ex;
    }
    if (t == 0) bbase[nbuck] = e;
}

// ---------------- pass A: LDS-staged partition; output packed (dlocal<<17 | src) ----------------
// Edges register-staged (read ei ONCE instead of twice).
__global__ __launch_bounds__(256) void partition_kernel(
    const int* __restrict__ ei, int* __restrict__ bcur,
    unsigned* __restrict__ pairs, int e) {
    __shared__ int cnt[NBMAX];
    __shared__ int scn[NBMAX];
    __shared__ int loff[NBMAX];
    __shared__ int base[NBMAX];
    __shared__ int2 stg[CHUNK];
    int t = threadIdx.x;
    int e0 = blockIdx.x * CHUNK;
    int ecnt = min(CHUNK, e - e0);

    int2 ed[CHUNK / 256];
#pragma unroll
    for (int j = 0; j < CHUNK / 256; ++j) {
        int k = t + j * 256;
        if (k < ecnt) { ed[j].x = ei[e0 + k]; ed[j].y = ei[e + e0 + k]; }
    }

    for (int k = t; k < NBMAX; k += 256) cnt[k] = 0;
    __syncthreads();
#pragma unroll
    for (int j = 0; j < CHUNK / 256; ++j)
        if (t + j * 256 < ecnt) atomicAdd(&cnt[ed[j].y >> BSH], 1);
    __syncthreads();
    int c = cnt[t];
    scn[t] = c;
    __syncthreads();
    for (int off = 1; off < 256; off <<= 1) {
        int u = (t >= off) ? scn[t - off] : 0;
        __syncthreads();
        scn[t] += u;
        __syncthreads();
    }
    int ex = scn[t] - c;
    __syncthreads();
    scn[t] = ex;
    loff[t] = ex;
    base[t] = c ? atomicAdd(&bcur[t], c) : 0;
    __syncthreads();
#pragma unroll
    for (int j = 0; j < CHUNK / 256; ++j)
        if (t + j * 256 < ecnt) {
            int pos = atomicAdd(&loff[ed[j].y >> BSH], 1);
            stg[pos] = ed[j];
        }
    __syncthreads();
    for (int k = t; k < ecnt; k += 256) {
        int2 pr = stg[k];
        int b = pr.y >> BSH;
        unsigned pk = ((unsigned)(pr.y & ((1 << BSH) - 1)) << 17) | (unsigned)pr.x;
        pairs[base[b] + (k - scn[b])] = pk;
    }
}

// ---------------- pass B: per-bucket count+scan+scatter; emits row_ptr/rend/dinv/csr_src ----------------
__global__ __launch_bounds__(256) void bucket_scatter_kernel(
    const int* __restrict__ bbase, const unsigned* __restrict__ pairs,
    int* __restrict__ csr_src, int* __restrict__ row_ptr, int* __restrict__ rend,
    float* __restrict__ dinv, int n) {
    __shared__ int cnt[1 << BSH];
    __shared__ int scn[256];
    __shared__ int cur[1 << BSH];
    int b = blockIdx.x;
    int n0 = b << BSH;
    int nn = min(1 << BSH, n - n0);
    int t = threadIdx.x;
    cnt[t] = 0; cnt[t + 256] = 0;
    __syncthreads();
    int p0 = bbase[b], p1 = bbase[b + 1];
    for (int k = p0 + t; k < p1; k += 256)
        atomicAdd(&cnt[pairs[k] >> 17], 1);
    __syncthreads();
    int ca = cnt[2 * t], cb = cnt[2 * t + 1];
    int c2 = ca + cb;
    scn[t] = c2;
    __syncthreads();
    for (int off = 1; off < 256; off <<= 1) {
        int u = (t >= off) ? scn[t - off] : 0;
        __syncthreads();
        scn[t] += u;
        __syncthreads();
    }
    int ex2 = scn[t] - c2;
    int ea = p0 + ex2;
    int eb = ea + ca;
    if (2 * t < nn) {
        row_ptr[n0 + 2 * t] = ea;
        rend[n0 + 2 * t]    = ea + ca;
        dinv[n0 + 2 * t]    = rsqrtf(1.0f + (float)ca);
        cur[2 * t] = ea;
    }
    if (2 * t + 1 < nn) {
        row_ptr[n0 + 2 * t + 1] = eb;
        rend[n0 + 2 * t + 1]    = eb + cb;
        dinv[n0 + 2 * t + 1]    = rsqrtf(1.0f + (float)cb);
        cur[2 * t + 1] = eb;
    }
    __syncthreads();
    for (int k = p0 + t; k < p1; k += 256) {
        unsigned v = pairs[k];
        int pos = atomicAdd(&cur[v >> 17], 1);
        csr_src[pos] = (int)(v & 0x1FFFFu);
    }
}

// ---------------- pack Wf1 into MFMA fragment order (bf16) ----------------
__global__ void prep_wf1_kernel(const float* __restrict__ Wf1, __hip_bfloat16* __restrict__ wfrag) {
    int gid = blockIdx.x * blockDim.x + threadIdx.x;
    if (gid >= 10 * 512) return;
    int f = gid >> 9;
    int rem = gid & 511;
    int l = rem >> 3;
    int e = rem & 7;
    int c = f >> 1;
    int t = f & 1;
    int k = c * 16 + ((l >> 5) << 3) + e;
    int n = (l & 31) + (t << 5);
    float v = (k < HID + PAT) ? Wf1[k * 64 + n] : 0.0f;
    wfrag[gid] = __float2bfloat16(v);
}

// ---------------- pack W2 into MFMA B-fragment order (bf16): 8 frags ----------------
__global__ void prep_w2_kernel(const float* __restrict__ W2, __hip_bfloat16* __restrict__ w2frag) {
    int gid = blockIdx.x * blockDim.x + threadIdx.x;
    if (gid >= 8 * 512) return;
    int f = gid >> 9;
    int rem = gid & 511;
    int l = rem >> 3;
    int e = rem & 7;
    int c = f >> 1;
    int t = f & 1;
    int k = c * 16 + ((l >> 5) << 3) + e;
    int n = (l & 31) + (t << 5);
    w2frag[gid] = __float2bfloat16(W2[k * 64 + n]);
}

// ---------------- pack epilogue weights ----------------
__global__ void prep_epi_kernel(const float* __restrict__ bf1, const float* __restrict__ Wf2,
                                float4* __restrict__ wepi) {
    int t = threadIdx.x;
    if (t >= 32) return;
    int r = t >> 1, half = t & 1;
    int ch = (r & 3) + 8 * (r >> 2) + 4 * half;
    wepi[t] = make_float4(bf1[ch], Wf2[ch], bf1[ch + 32], Wf2[ch + 32]);
}

// ---------------- layer-1 matmul: hbs1 = bf16((emb @ W1) * dinv) ----------------
__global__ __launch_bounds__(256) void mm1_kernel(
    const float* __restrict__ emb, const float* __restrict__ W1,
    const float* __restrict__ dinv,
    __hip_bfloat16* __restrict__ hbs, int n) {
    __shared__ float w[EMB * HID];  // 8 KB
    int t = threadIdx.x;
    for (int k = t; k < EMB * HID; k += 256) w[k] = W1[k];
    __syncthreads();
    int wave = t >> 6, lane = t & 63;
    int i = blockIdx.x * 4 + wave;
    if (i >= n) return;
    float e = (lane < EMB) ? emb[i * EMB + lane] : 0.0f;
    float acc = 0.0f;
#pragma unroll
    for (int k = 0; k < EMB; ++k) {
        float ek = __shfl(e, k, 64);
        acc += ek * w[k * HID + lane];
    }
    hbs[(size_t)i * HID + lane] = __float2bfloat16(acc * dinv[i]);
}

// ======== 2-edges-per-instruction gather core, deep-MLP (32/16/8/2 cascade) ========
#define GSTEP(NE)                                                               \
    for (; k + 2 * NE - 2 < end; k += 2 * NE) {                                 \
        int aa[NE]; unsigned rr[NE];                                            \
        _Pragma("unroll") for (int j = 0; j < NE; ++j) aa[j] = csr_src[k + 2 * j]; \
        _Pragma("unroll") for (int j = 0; j < NE; ++j)                          \
            rr[j] = *(const unsigned*)&hb[(size_t)aa[j] * HID + lp2];           \
        _Pragma("unroll") for (int j = 0; j < NE; ++j) { s0 += bf_lo(rr[j]); s1 += bf_hi(rr[j]); } \
    }

__device__ __forceinline__ float2 gather_row2(
    const int* __restrict__ csr_src, const __hip_bfloat16* __restrict__ hb,
    int i, int e, int end, int halfe, int lp2) {
    float s0 = 0.0f, s1 = 0.0f;
    int k = e + halfe;
    GSTEP(16)   // 32 edges per wave-iteration: 16 row-loads in flight per lane
    GSTEP(8)
    GSTEP(4)
    for (; k < end; k += 2) {
        unsigned r0 = *(const unsigned*)&hb[(size_t)csr_src[k] * HID + lp2];
        s0 += bf_lo(r0);
        s1 += bf_hi(r0);
    }
    s0 += __shfl_xor(s0, 32, 64);
    s1 += __shfl_xor(s1, 32, 64);
    unsigned sv = *(const unsigned*)&hb[(size_t)i * HID + lp2];
    s0 += bf_lo(sv);
    s1 += bf_hi(sv);
    return make_float2(s0, s1);
}
#undef GSTEP

// ---------------- fused gather(L1) + MFMA mm2: 32 rows/block ----------------
__global__ __launch_bounds__(256) void gather_mm2_kernel(
    const int* __restrict__ row_ptr, const int* __restrict__ rend,
    const int* __restrict__ csr_src, const float* __restrict__ dinv,
    const __hip_bfloat16* __restrict__ hbs1, const __hip_bfloat16* __restrict__ w2frag,
    const float* __restrict__ b1, __hip_bfloat16* __restrict__ hbs2, int n) {
    __shared__ __attribute__((aligned(16))) unsigned short x1s[32 * 64];  // 4 KB
    int t = threadIdx.x;
    int lane = t & 63;
    int wv = t >> 6;
    int halfe = lane >> 5;
    int lp = lane & 31;
    int lp2 = lp * 2;
    int n0 = blockIdx.x << 5;
    float2 b1v = *(const float2*)&b1[lp2];

    for (int rr = 0; rr < 8; ++rr) {
        int row = wv * 8 + rr;
        int i = n0 + row;
        unsigned pk = 0;
        if (i < n) {
            float2 s = gather_row2(csr_src, hbs1, i, row_ptr[i], rend[i], halfe, lp2);
            float dv = dinv[i];
            pk = pack_bf2(fmaxf(fmaf(dv, s.x, b1v.x), 0.0f),
                          fmaxf(fmaf(dv, s.y, b1v.y), 0.0f));
        }
        if (lane < 32) {
            int blk = (lp >> 2) ^ (row & 7);   // 16B-block XOR swizzle (bank-conflict-free)
            *(unsigned*)&x1s[row * 64 + (blk << 3) + (lp2 & 7)] = pk;
        }
    }
    __syncthreads();

    if (wv < 2) {   // wv = n-tile index
        int half = lane >> 5;
        const uint4* wf = (const uint4*)w2frag;
        f32x16 acc;
#pragma unroll
        for (int r = 0; r < 16; ++r) acc[r] = 0.0f;
#pragma unroll
        for (int c = 0; c < 4; ++c) {
            Frag fa, fb;
            int blk = (c * 2 + half) ^ (lp & 7);
            fa.u4 = *(const uint4*)&x1s[lp * 64 + (blk << 3)];
            fb.u4 = wf[(c * 2 + wv) * 64 + lane];
            acc = __builtin_amdgcn_mfma_f32_32x32x16_bf16(fa.s8, fb.s8, acc, 0, 0, 0);
        }
#pragma unroll
        for (int r = 0; r < 16; ++r) {
            int m = (r & 3) + 8 * (r >> 2) + 4 * half;
            int i = n0 + m;
            if (i < n)
                hbs2[(size_t)i * HID + lp + 32 * wv] = __float2bfloat16(acc[r] * dinv[i]);
        }
    }
}

// ---------------- gather(layer2): xb = bf16(dv*sum + b2) ----------------
__global__ __launch_bounds__(256) void gather_out_kernel(
    const int* __restrict__ row_ptr, const int* __restrict__ rend,
    const int* __restrict__ csr_src, const float* __restrict__ dinv,
    const __hip_bfloat16* __restrict__ hbs2, const float* __restrict__ b2,
    __hip_bfloat16* __restrict__ xb, int n) {
    int t = threadIdx.x;
    int lane = t & 63;
    int halfe = lane >> 5;
    int lp = lane & 31;
    int lp2 = lp * 2;
    int i = blockIdx.x * 4 + (t >> 6);
    if (i >= n) return;
    float2 s = gather_row2(csr_src, hbs2, i, row_ptr[i], rend[i], halfe, lp2);
    if (lane < 32) {
        float dv = dinv[i];
        float2 b2v = *(const float2*)&b2[lp2];
        *(unsigned*)&xb[(size_t)i * HID + lp2] =
            pack_bf2(fmaf(dv, s.x, b2v.x), fmaf(dv, s.y, b2v.y));
    }
}

// ---------------- pair MLP head via MFMA, swapped operands + hoisted fragment loads ----------------
__global__ __launch_bounds__(256) void final_mfma_kernel(
    const int* __restrict__ pairs, const float* __restrict__ pf,
    const __hip_bfloat16* __restrict__ xb, const __hip_bfloat16* __restrict__ wfrag,
    const float4* __restrict__ wepi, const float* __restrict__ bf2,
    float* __restrict__ out, int p) {
    int lane = threadIdx.x & 63;
    int wid  = threadIdx.x >> 6;
    int half = lane >> 5;
    int lp   = lane & 31;

    float bf2r = bf2[0];
    const uint4* wf = (const uint4*)wfrag;

    int ngroups = (p + 31) >> 5;
    int nw = gridDim.x * 4;
    for (int g = blockIdx.x * 4 + wid; g < ngroups; g += nw) {
        int p32 = g << 5;
        int pi = p32 + lp; if (pi >= p) pi = p - 1;
        int2 pr = ((const int2*)pairs)[pi];
        const uint4* drow = (const uint4*)(xb + (size_t)pr.x * HID);
        const uint4* arow = (const uint4*)(xb + (size_t)pr.y * HID);

        // hoist ALL random row loads (8 per lane) so they are all in flight at once
        uint4 du[4], au[4];
        float4 pflo, pfhi;
#pragma unroll
        for (int c = 0; c < 4; ++c) { du[c] = drow[c * 2 + half]; au[c] = arow[c * 2 + half]; }
        if (half == 0) {
            pflo = ((const float4*)pf)[pi * 2];
            pfhi = ((const float4*)pf)[pi * 2 + 1];
        }

        f32x16 acc0, acc1;
#pragma unroll
        for (int r = 0; r < 16; ++r) { acc0[r] = 0.0f; acc1[r] = 0.0f; }

#pragma unroll
        for (int c = 0; c < 4; ++c) {
            Frag fd, fx, fa, fb0, fb1;
            fd.u4 = du[c];
            fx.u4 = au[c];
#pragma unroll
            for (int q = 0; q < 4; ++q) fa.h2[q] = __hmul2(fd.h2[q], fx.h2[q]);
            fb0.u4 = wf[(c * 2 + 0) * 64 + lane];
            fb1.u4 = wf[(c * 2 + 1) * 64 + lane];
            acc0 = __builtin_amdgcn_mfma_f32_32x32x16_bf16(fb0.s8, fa.s8, acc0, 0, 0, 0);
            acc1 = __builtin_amdgcn_mfma_f32_32x32x16_bf16(fb1.s8, fa.s8, acc1, 0, 0, 0);
        }
        {   // chunk 4: patient features (k=64..71 real, 72..79 zero-pad)
            Frag fa, fb0, fb1;
            if (half == 0) {
                fa.h[0] = __float2bfloat16(pflo.x); fa.h[1] = __float2bfloat16(pflo.y);
                fa.h[2] = __float2bfloat16(pflo.z); fa.h[3] = __float2bfloat16(pflo.w);
                fa.h[4] = __float2bfloat16(pfhi.x); fa.h[5] = __float2bfloat16(pfhi.y);
                fa.h[6] = __float2bfloat16(pfhi.z); fa.h[7] = __float2bfloat16(pfhi.w);
            } else {
#pragma unroll
                for (int e = 0; e < 8; ++e) fa.us[e] = 0;
            }
            fb0.u4 = wf[8 * 64 + lane];
            fb1.u4 = wf[9 * 64 + lane];
            acc0 = __builtin_amdgcn_mfma_f32_32x32x16_bf16(fb0.s8, fa.s8, acc0, 0, 0, 0);
            acc1 = __builtin_amdgcn_mfma_f32_32x32x16_bf16(fb1.s8, fa.s8, acc1, 0, 0, 0);
        }

        // layer 2: per-lane over 32 register-resident channels, then one lane-swap
        float s = 0.0f;
#pragma unroll
        for (int r = 0; r < 16; ++r) {
            float4 wv = wepi[r * 2 + half];
            s += fmaxf(acc0[r] + wv.x, 0.0f) * wv.y
               + fmaxf(acc1[r] + wv.z, 0.0f) * wv.w;
        }
        s += __shfl_xor(s, 32, 64);
        if (lane < 32) {
            int po = p32 + lp;
            if (po < p) out[po] = 1.0f / (1.0f + expf(-(s + bf2r)));
        }
    }
}

extern "C" void kernel_launch(void* const* d_in, const int* in_sizes, int n_in,
                              void* d_out, int out_size, void* d_ws, size_t ws_size,
                              hipStream_t stream) {
    const int*   edge_index = (const int*)d_in[0];
    const int*   edge_pairs = (const int*)d_in[1];
    const float* pf         = (const float*)d_in[2];
    const float* emb        = (const float*)d_in[3];
    const float* W1         = (const float*)d_in[4];
    const float* b1         = (const float*)d_in[5];
    const float* W2         = (const float*)d_in[6];
    const float* b2         = (const float*)d_in[7];
    const float* Wf1        = (const float*)d_in[8];
    const float* bf1        = (const float*)d_in[9];
    const float* Wf2        = (const float*)d_in[10];
    const float* bf2        = (const float*)d_in[11];
    float*       out        = (float*)d_out;

    const int E = in_sizes[0] / 2;
    const int P = in_sizes[1] / 2;
    const int N = in_sizes[3] / EMB;
    const int NBUCK = (N + (1 << BSH) - 1) >> BSH;   // 196 for N=100k (<=NBMAX)

    char* ws = (char*)d_ws;
    size_t off = 0;
    float*          dinv    = (float*)(ws + off);          off += ((size_t)N * 4 + 255) & ~255ULL;
    __hip_bfloat16* hbs1    = (__hip_bfloat16*)(ws + off); off += ((size_t)N * HID * 2 + 255) & ~255ULL;
    __hip_bfloat16* hbs2    = (__hip_bfloat16*)(ws + off); off += ((size_t)N * HID * 2 + 255) & ~255ULL;
    __hip_bfloat16* xb      = (__hip_bfloat16*)(ws + off); off += ((size_t)N * HID * 2 + 255) & ~255ULL;
    __hip_bfloat16* wfrag   = (__hip_bfloat16*)(ws + off); off += ((size_t)10 * 512 * 2 + 255) & ~255ULL;
    __hip_bfloat16* w2frag  = (__hip_bfloat16*)(ws + off); off += ((size_t)8 * 512 * 2 + 255) & ~255ULL;
    float4*         wepi    = (float4*)(ws + off);         off += ((size_t)32 * 16 + 255) & ~255ULL;
    int*            row_ptr = (int*)(ws + off);            off += ((size_t)N * 4 + 255) & ~255ULL;
    int*            rend    = (int*)(ws + off);            off += ((size_t)N * 4 + 255) & ~255ULL;
    int*            btot    = (int*)(ws + off);            off += ((size_t)NBMAX * 4 + 255) & ~255ULL;
    int*            bbase   = (int*)(ws + off);            off += ((size_t)(NBMAX + 1) * 4 + 255) & ~255ULL;
    int*            bcur    = (int*)(ws + off);            off += ((size_t)NBMAX * 4 + 255) & ~255ULL;
    int*            csr_src = (int*)(ws + off);            off += ((size_t)E * 4 + 255) & ~255ULL;
    unsigned*       pairs2  = (unsigned*)(ws + off);       off += ((size_t)E * 4 + 255) & ~255ULL;
    (void)ws_size;

    const int EBLK = (E + CHUNK - 1) / CHUNK;

    // ---- CSR build (bucket hist -> scan -> partition -> bucket scatter) ----
    hipMemsetAsync(btot, 0, (size_t)NBMAX * 4, stream);
    bucket_hist_kernel<<<EBLK, 256, 0, stream>>>(edge_index + E, btot, E);
    prep_wf1_kernel<<<20, 256, 0, stream>>>(Wf1, wfrag);
    prep_w2_kernel<<<16, 256, 0, stream>>>(W2, w2frag);
    prep_epi_kernel<<<1, 32, 0, stream>>>(bf1, Wf2, wepi);
    scan_buckets_kernel<<<1, 256, 0, stream>>>(btot, bbase, bcur, NBUCK, E);
    partition_kernel<<<EBLK, 256, 0, stream>>>(edge_index, bcur, pairs2, E);
    bucket_scatter_kernel<<<NBUCK, 256, 0, stream>>>(bbase, pairs2, csr_src,
                                                     row_ptr, rend, dinv, N);

    // ---- layer 1: h1*dinv (bf16) ----
    mm1_kernel<<<(N + 3) / 4, 256, 0, stream>>>(emb, W1, dinv, hbs1, N);

    // ---- fused gather(L1) + MFMA mm2 -> hbs2 ----
    gather_mm2_kernel<<<(N + 31) / 32, 256, 0, stream>>>(row_ptr, rend, csr_src, dinv,
                                                         hbs1, w2frag, b1, hbs2, N);

    // ---- gather(L2) -> xb (b2 folded) ----
    gather_out_kernel<<<(N + 3) / 4, 256, 0, stream>>>(row_ptr, rend, csr_src, dinv,
                                                       hbs2, b2, xb, N);

    // ---- pair MLP head (MFMA, swapped operands) ----
    final_mfma_kernel<<<2048, 256, 0, stream>>>(edge_pairs, pf, xb, wfrag,
                                                wepi, bf2, out, P);
}